// Round 1
// baseline (290.886 us; speedup 1.0000x reference)
//
#include <hip/hip_runtime.h>
#include <hip/hip_fp16.h>

// GCN 3-layer, CSR-gather, low-rank L1 + fused L2/L3 transform.
//   deg+rank histogram now via PER-XCD L2-LOCAL atomics (workgroup scope, no sc1):
//     each XCD x owns cnt[x][*] (in) and cnt[8+x][*] (out); rank packs (xcc<<24)|local.
//     scan reconstructs totals + per-XCD absolute offsets off8[x][v].
//   (agent-scope atomics executed memory-side at ~1.1/cyc/XCD = the old 78us floor;
//    WRITE_SIZE 52.9MB showed 32B/atomic memory-side RMW traffic)
//   scan -> fill: ONE int2 (8B) scatter/edge: {src|label<<16, out_norm}
//   L1 fused: h1s(fp16) = relu(in_norm*sum w_e*T1[lbl_e] + b1)*out_norm (linear stream)
//   L2 agg:  agg(fp32) = in_norm * gather(h1s fp16, 192B rows)
//   L2+L3 fused GEMM (W2/W3 in LDS — global-W was 2.5x slower, R12),
//     t = h2@W3 stored FP16, row stride 64 halfs = 128B = exactly 1 cacheline
//   out = in_norm*gather(t fp16) + b3      [fp32 accumulate everywhere]
#define N_NODES 50000
#define N_EDGES 800000
#define EMB     64
#define HID     96
#define NLAB    50
#define NB_SCAN ((N_NODES + 255) / 256)    // 196
#define TSTRIDE 64                         // t row stride (halfs): 128B line-aligned
#define TC      13                         // gather chunks over t (cols 0..51)
#define EDGEB   ((N_EDGES + 255) / 256)    // 3125
#define T1B     ((NLAB * HID + 255) / 256) // 19
#define NXCD    8

__device__ __forceinline__ float2 h2f(unsigned u) {
    __half2 h = *reinterpret_cast<__half2*>(&u);
    return __half22float2(h);
}
__device__ __forceinline__ unsigned f2h(float a, float b) {
    __half2 h = __floats2half2_rn(a, b);
    return *reinterpret_cast<unsigned*>(&h);
}
__device__ __forceinline__ unsigned xcc_id() {
    unsigned x;
    asm volatile("s_getreg_b32 %0, hwreg(HW_REG_XCC_ID)" : "=s"(x));
    return x & 7u;
}

// Histogram both degrees into the XCD-local copy with workgroup-scope (L2-local,
// no sc1) atomics; rank[i] = (xcc<<24) | local rank within (dst, xcc). Tail
// blocks (VALU idle here) compute T1 = emb@W1.
__global__ void deg_rank_t1_kernel(const int* __restrict__ src, const int* __restrict__ dst,
                                   int* __restrict__ cnt,   // [16][N]: 0..7 in-copies, 8..15 out-copies
                                   int* __restrict__ rank,
                                   const float* __restrict__ emb, const float* __restrict__ W1,
                                   float* __restrict__ T1) {
    int b = blockIdx.x;
    if (b < EDGEB) {
        unsigned xcc = xcc_id();
        int* cin  = cnt + (size_t)xcc * N_NODES;
        int* cout = cnt + (size_t)(NXCD + xcc) * N_NODES;
        int i = b * 256 + threadIdx.x;
        if (i < N_EDGES) {
            __hip_atomic_fetch_add(&cout[src[i]], 1, __ATOMIC_RELAXED,
                                   __HIP_MEMORY_SCOPE_WORKGROUP);
            int r = __hip_atomic_fetch_add(&cin[dst[i]], 1, __ATOMIC_RELAXED,
                                           __HIP_MEMORY_SCOPE_WORKGROUP);
            rank[i] = (int)((xcc << 24) | (unsigned)r);   // r < N_EDGES < 2^24
        }
    } else {
        int i = (b - EDGEB) * 256 + threadIdx.x;
        if (i < NLAB * HID) {
            int l = i / HID, j = i - l * HID;
            float sum = 0.0f;
#pragma unroll
            for (int k = 0; k < EMB; ++k) sum += emb[l * EMB + k] * W1[k * HID + j];
            T1[i] = sum;
        }
    }
}

// --- block sums of total in-degree (sum of the 8 XCD copies) ---
__global__ void scan1_kernel(const int* __restrict__ cnt, int* __restrict__ deg_in_total,
                             int* __restrict__ bsum) {
    __shared__ int s[256];
    int t = threadIdx.x, i = blockIdx.x * 256 + t;
    int v = 0;
    if (i < N_NODES) {
#pragma unroll
        for (int x = 0; x < NXCD; ++x) v += cnt[(size_t)x * N_NODES + i];
        deg_in_total[i] = v;
    }
    s[t] = v;
    for (int off = 128; off > 0; off >>= 1) {
        __syncthreads();
        if (t < off) s[t] += s[t + off];
    }
    if (t == 0) bsum[blockIdx.x] = s[0];
}

// Merged scan2+scan3: each block derives its prefix from bsum, scans its chunk,
// emits norms + node_info, and the per-XCD absolute CSR offsets off8[x][v].
__global__ void scan23_kernel(const int* __restrict__ deg_in_total, const int* __restrict__ bsum,
                              const int* __restrict__ cnt, const int* __restrict__ labels,
                              int* __restrict__ row_off, int* __restrict__ off8,
                              float* __restrict__ out_norm, float* __restrict__ in_norm,
                              int2* __restrict__ node_info) {
    __shared__ int pb[256];
    __shared__ int s[256];
    int t = threadIdx.x, i = blockIdx.x * 256 + t;
    pb[t] = (t < (int)blockIdx.x) ? bsum[t] : 0;
    int own = (i < N_NODES) ? deg_in_total[i] : 0;
    s[t] = own;
    __syncthreads();
    for (int off = 128; off > 0; off >>= 1) {
        if (t < off) pb[t] += pb[t + off];
        __syncthreads();
    }
    int base = pb[0];
    for (int off = 1; off < 256; off <<= 1) {
        int v = s[t];
        if (t >= off) v += s[t - off];
        __syncthreads();
        s[t] = v;
        __syncthreads();
    }
    if (i < N_NODES) {
        int ro = base + s[t] - own;
        row_off[i] = ro;
        int dout = 0;
#pragma unroll
        for (int x = 0; x < NXCD; ++x) dout += cnt[(size_t)(NXCD + x) * N_NODES + i];
        float on = rsqrtf(fmaxf((float)dout, 1.0f));
        out_norm[i] = on;
        in_norm[i]  = rsqrtf(fmaxf((float)own, 1.0f));
        node_info[i] = make_int2(labels[i] << 16, __float_as_int(on));
        int run = ro;
#pragma unroll
        for (int x = 0; x < NXCD; ++x) {
            off8[(size_t)x * N_NODES + i] = run;
            run += cnt[(size_t)x * N_NODES + i];
        }
    }
}

// Atomic-free CSR fill: ONE 8B scatter per edge. rec = {src|label<<16, out_norm}
// pos = off8[xcc][dst] + local_rank.
__global__ void fill_kernel(const int* __restrict__ src, const int* __restrict__ dst,
                            const int* __restrict__ off8, const int* __restrict__ rank,
                            const int2* __restrict__ node_info,
                            int2* __restrict__ edge_rec) {
    int i = blockIdx.x * blockDim.x + threadIdx.x;
    if (i < N_EDGES) {
        int s = src[i];
        int2 ni = node_info[s];
        unsigned rp = (unsigned)rank[i];
        int pos = off8[(size_t)(rp >> 24) * N_NODES + dst[i]] + (int)(rp & 0xFFFFFFu >> 8 ? rp & 0xFFFFFF : rp & 0xFFFFFF);
        edge_rec[pos] = make_int2(s | ni.x, ni.y);
    }
}

// Fused layer 1: 2 float4 chunks per thread, unroll-4 edges; edge_rec read linearly.
// h1s (FP16) = relu(in_norm*sum w_e*T1[lbl_e] + b1) * out_norm
__global__ void gather1t_kernel(const int2* __restrict__ edge_rec, const float* __restrict__ T1,
                                const int* __restrict__ row_off, const int* __restrict__ deg,
                                const float* __restrict__ in_norm,
                                const float* __restrict__ out_norm, const float* __restrict__ b1,
                                __half* __restrict__ h1s) {
    constexpr int C = HID / 8;   // 12 chunk-pairs per node
    int i = blockIdx.x * blockDim.x + threadIdx.x;
    if (i >= N_NODES * C) return;
    int n = i / C;
    int c = i - n * C;
    const float* t1a = T1 + c * 4;
    const float* t1b = T1 + (c + C) * 4;
    int k = row_off[n];
    int e = k + deg[n];
    float ax = 0.f, ay = 0.f, az = 0.f, aw = 0.f;
    float bx = 0.f, by = 0.f, bz = 0.f, bw = 0.f;
    for (; k + 3 < e; k += 4) {
        int2 i0 = edge_rec[k];
        int2 i1 = edge_rec[k + 1];
        int2 i2 = edge_rec[k + 2];
        int2 i3 = edge_rec[k + 3];
        int r0 = ((unsigned)i0.x >> 16) * HID, r1 = ((unsigned)i1.x >> 16) * HID;
        int r2 = ((unsigned)i2.x >> 16) * HID, r3 = ((unsigned)i3.x >> 16) * HID;
        float4 aA = *(const float4*)(t1a + r0); float4 bA = *(const float4*)(t1b + r0);
        float4 aB = *(const float4*)(t1a + r1); float4 bB = *(const float4*)(t1b + r1);
        float4 aC = *(const float4*)(t1a + r2); float4 bC = *(const float4*)(t1b + r2);
        float4 aD = *(const float4*)(t1a + r3); float4 bD = *(const float4*)(t1b + r3);
        float w0 = __int_as_float(i0.y), w1 = __int_as_float(i1.y);
        float w2 = __int_as_float(i2.y), w3 = __int_as_float(i3.y);
        ax += aA.x * w0 + aB.x * w1 + aC.x * w2 + aD.x * w3;
        ay += aA.y * w0 + aB.y * w1 + aC.y * w2 + aD.y * w3;
        az += aA.z * w0 + aB.z * w1 + aC.z * w2 + aD.z * w3;
        aw += aA.w * w0 + aB.w * w1 + aC.w * w2 + aD.w * w3;
        bx += bA.x * w0 + bB.x * w1 + bC.x * w2 + bD.x * w3;
        by += bA.y * w0 + bB.y * w1 + bC.y * w2 + bD.y * w3;
        bz += bA.z * w0 + bB.z * w1 + bC.z * w2 + bD.z * w3;
        bw += bA.w * w0 + bB.w * w1 + bC.w * w2 + bD.w * w3;
    }
    for (; k < e; ++k) {
        int2 i0 = edge_rec[k];
        int r0 = ((unsigned)i0.x >> 16) * HID;
        float4 aA = *(const float4*)(t1a + r0); float4 bA = *(const float4*)(t1b + r0);
        float w0 = __int_as_float(i0.y);
        ax += aA.x * w0; ay += aA.y * w0; az += aA.z * w0; aw += aA.w * w0;
        bx += bA.x * w0; by += bA.y * w0; bz += bA.z * w0; bw += bA.w * w0;
    }
    float nn = in_norm[n];
    float on = out_norm[n];
    float4 b1a = *(const float4*)(b1 + c * 4);
    float4 b1b = *(const float4*)(b1 + (c + C) * 4);
    uint2 rA, rB;
    rA.x = f2h(fmaxf(ax * nn + b1a.x, 0.f) * on, fmaxf(ay * nn + b1a.y, 0.f) * on);
    rA.y = f2h(fmaxf(az * nn + b1a.z, 0.f) * on, fmaxf(aw * nn + b1a.w, 0.f) * on);
    rB.x = f2h(fmaxf(bx * nn + b1b.x, 0.f) * on, fmaxf(by * nn + b1b.y, 0.f) * on);
    rB.y = f2h(fmaxf(bz * nn + b1b.z, 0.f) * on, fmaxf(bw * nn + b1b.w, 0.f) * on);
    __half* op = h1s + (size_t)n * HID;
    *(uint2*)(op + c * 4) = rA;
    *(uint2*)(op + (c + C) * 4) = rB;
}

// Layer-2 aggregate from FP16 rows (192B): src = edge_rec[k].x & 0xFFFF.
__global__ void gather4x2_kernel(const __half* __restrict__ hs, const int* __restrict__ row_off,
                                 const int* __restrict__ deg, const int2* __restrict__ erec,
                                 const float* __restrict__ in_norm, float* __restrict__ out) {
    constexpr int C = HID / 8;   // 12
    int i = blockIdx.x * blockDim.x + threadIdx.x;
    if (i >= N_NODES * C) return;
    int n = i / C;
    int c = i - n * C;
    const __half* p0 = hs + c * 4;
    const __half* p1 = hs + (c + C) * 4;
    int k = row_off[n];
    int e = k + deg[n];
    float ax = 0.f, ay = 0.f, az = 0.f, aw = 0.f;
    float bx = 0.f, by = 0.f, bz = 0.f, bw = 0.f;
    for (; k + 3 < e; k += 4) {
        size_t r0 = (size_t)(erec[k].x & 0xFFFF) * HID;
        size_t r1 = (size_t)(erec[k + 1].x & 0xFFFF) * HID;
        size_t r2 = (size_t)(erec[k + 2].x & 0xFFFF) * HID;
        size_t r3 = (size_t)(erec[k + 3].x & 0xFFFF) * HID;
        uint2 aA = *(const uint2*)(p0 + r0); uint2 bA = *(const uint2*)(p1 + r0);
        uint2 aB = *(const uint2*)(p0 + r1); uint2 bB = *(const uint2*)(p1 + r1);
        uint2 aC = *(const uint2*)(p0 + r2); uint2 bC = *(const uint2*)(p1 + r2);
        uint2 aD = *(const uint2*)(p0 + r3); uint2 bD = *(const uint2*)(p1 + r3);
        float2 f;
        f = h2f(aA.x); ax += f.x; ay += f.y;  f = h2f(aA.y); az += f.x; aw += f.y;
        f = h2f(aB.x); ax += f.x; ay += f.y;  f = h2f(aB.y); az += f.x; aw += f.y;
        f = h2f(aC.x); ax += f.x; ay += f.y;  f = h2f(aC.y); az += f.x; aw += f.y;
        f = h2f(aD.x); ax += f.x; ay += f.y;  f = h2f(aD.y); az += f.x; aw += f.y;
        f = h2f(bA.x); bx += f.x; by += f.y;  f = h2f(bA.y); bz += f.x; bw += f.y;
        f = h2f(bB.x); bx += f.x; by += f.y;  f = h2f(bB.y); bz += f.x; bw += f.y;
        f = h2f(bC.x); bx += f.x; by += f.y;  f = h2f(bC.y); bz += f.x; bw += f.y;
        f = h2f(bD.x); bx += f.x; by += f.y;  f = h2f(bD.y); bz += f.x; bw += f.y;
    }
    for (; k < e; ++k) {
        size_t r0 = (size_t)(erec[k].x & 0xFFFF) * HID;
        uint2 aA = *(const uint2*)(p0 + r0); uint2 bA = *(const uint2*)(p1 + r0);
        float2 f;
        f = h2f(aA.x); ax += f.x; ay += f.y;  f = h2f(aA.y); az += f.x; aw += f.y;
        f = h2f(bA.x); bx += f.x; by += f.y;  f = h2f(bA.y); bz += f.x; bw += f.y;
    }
    float nn = in_norm[n];
    float4 rA, rB;
    rA.x = ax * nn; rA.y = ay * nn; rA.z = az * nn; rA.w = aw * nn;
    rB.x = bx * nn; rB.y = by * nn; rB.z = bz * nn; rB.w = bw * nn;
    float* op = out + (size_t)n * HID;
    *(float4*)(op + c * 4) = rA;
    *(float4*)(op + (c + C) * 4) = rB;
}

// Fused layers 2+3 (LDS-W form): h2 = relu(agg@W2+b2)*out_norm in LDS,
// t = h2@W3 stored FP16 at row stride 64 halfs (128B line-aligned; cols 0..51 used).
__global__ __launch_bounds__(256) void linear23_kernel(
        const float* __restrict__ agg, const float* __restrict__ W2,
        const float* __restrict__ b2, const float* __restrict__ out_norm,
        const float* __restrict__ W3, __half* __restrict__ t) {
    constexpr int INP = 100;
    __shared__ float in_s[64][INP];      // 25.6 KB
    __shared__ float W_s[HID * HID];     // 36.9 KB ([k][j]; phase 2: 96x64)
    __shared__ float bs[HID];
    const int tid = threadIdx.x;
    const int n0 = blockIdx.x * 64;

    for (int idx = tid; idx < 64 * (HID / 4); idx += 256) {
        int m = idx / (HID / 4), c = idx - m * (HID / 4);
        int n = n0 + m;
        float4 v = (n < N_NODES) ? *(const float4*)(agg + (size_t)n * HID + c * 4)
                                 : make_float4(0.f, 0.f, 0.f, 0.f);
        *(float4*)(&in_s[m][c * 4]) = v;
    }
    for (int idx = tid; idx < HID * HID / 4; idx += 256)
        *(float4*)(&W_s[idx * 4]) = *(const float4*)(W2 + idx * 4);
    if (tid < HID) bs[tid] = b2[tid];
    __syncthreads();

    const int tx = tid & 15, ty = tid >> 4;
    const int j0 = tx * 6, m0 = ty * 4;

    // GEMM1: 64x96 @ 96x96
    float acc[4][6];
#pragma unroll
    for (int i = 0; i < 4; ++i)
#pragma unroll
        for (int jj = 0; jj < 6; ++jj) acc[i][jj] = 0.0f;
#pragma unroll 4
    for (int k = 0; k < HID; ++k) {
        float a[4], w[6];
#pragma unroll
        for (int i = 0; i < 4; ++i) a[i] = in_s[m0 + i][k];
#pragma unroll
        for (int jj = 0; jj < 6; ++jj) w[jj] = W_s[k * HID + j0 + jj];
#pragma unroll
        for (int i = 0; i < 4; ++i)
#pragma unroll
            for (int jj = 0; jj < 6; ++jj) acc[i][jj] += a[i] * w[jj];
    }
    __syncthreads();

    // h2 tile -> in_s (in place); W3 (zero-padded to 64 cols) -> W_s
#pragma unroll
    for (int i = 0; i < 4; ++i) {
        int n = n0 + m0 + i;
        float on = (n < N_NODES) ? out_norm[n] : 0.0f;
#pragma unroll
        for (int jj = 0; jj < 6; ++jj)
            in_s[m0 + i][j0 + jj] = fmaxf(acc[i][jj] + bs[j0 + jj], 0.0f) * on;
    }
    for (int idx = tid; idx < HID * 64; idx += 256) {
        int k = idx >> 6, j = idx & 63;
        W_s[idx] = (j < NLAB) ? W3[k * NLAB + j] : 0.0f;
    }
    __syncthreads();

    // GEMM2: 64x96 @ 96x64 (cols >= 50 zero)
    const int j20 = tx * 4;
    float acc2[4][4];
#pragma unroll
    for (int i = 0; i < 4; ++i)
#pragma unroll
        for (int jj = 0; jj < 4; ++jj) acc2[i][jj] = 0.0f;
#pragma unroll 4
    for (int k = 0; k < HID; ++k) {
        float a[4], w[4];
#pragma unroll
        for (int i = 0; i < 4; ++i) a[i] = in_s[m0 + i][k];
#pragma unroll
        for (int jj = 0; jj < 4; ++jj) w[jj] = W_s[k * 64 + j20 + jj];
#pragma unroll
        for (int i = 0; i < 4; ++i)
#pragma unroll
            for (int jj = 0; jj < 4; ++jj) acc2[i][jj] += a[i] * w[jj];
    }
    if (j20 < 4 * TC) {   // tx <= 12: cols 0..51 (52..63 never read)
#pragma unroll
        for (int i = 0; i < 4; ++i) {
            int n = n0 + m0 + i;
            if (n >= N_NODES) break;
            uint2 raw;
            raw.x = f2h(acc2[i][0], acc2[i][1]);
            raw.y = f2h(acc2[i][2], acc2[i][3]);
            *(uint2*)(t + (size_t)n * TSTRIDE + j20) = raw;
        }
    }
}

// Final gather over FP16 t (128B-aligned rows, 1 line each).
__global__ void gather_out_kernel(const __half* __restrict__ t, const int* __restrict__ row_off,
                                  const int* __restrict__ deg, const int2* __restrict__ erec,
                                  const float* __restrict__ in_norm, const float* __restrict__ bias,
                                  float* __restrict__ out) {
    int i = blockIdx.x * blockDim.x + threadIdx.x;
    if (i >= N_NODES * TC) return;
    int n = i / TC;
    int c = i - n * TC;
    const __half* p0 = t + c * 4;
    int k = row_off[n];
    int e = k + deg[n];
    float ax = 0.f, ay = 0.f, az = 0.f, aw = 0.f;
    for (; k + 3 < e; k += 4) {
        size_t r0 = (size_t)(erec[k].x & 0xFFFF) * TSTRIDE;
        size_t r1 = (size_t)(erec[k + 1].x & 0xFFFF) * TSTRIDE;
        size_t r2 = (size_t)(erec[k + 2].x & 0xFFFF) * TSTRIDE;
        size_t r3 = (size_t)(erec[k + 3].x & 0xFFFF) * TSTRIDE;
        uint2 v0 = *(const uint2*)(p0 + r0);
        uint2 v1 = *(const uint2*)(p0 + r1);
        uint2 v2 = *(const uint2*)(p0 + r2);
        uint2 v3 = *(const uint2*)(p0 + r3);
        float2 f;
        f = h2f(v0.x); ax += f.x; ay += f.y;  f = h2f(v0.y); az += f.x; aw += f.y;
        f = h2f(v1.x); ax += f.x; ay += f.y;  f = h2f(v1.y); az += f.x; aw += f.y;
        f = h2f(v2.x); ax += f.x; ay += f.y;  f = h2f(v2.y); az += f.x; aw += f.y;
        f = h2f(v3.x); ax += f.x; ay += f.y;  f = h2f(v3.y); az += f.x; aw += f.y;
    }
    for (; k < e; ++k) {
        size_t r0 = (size_t)(erec[k].x & 0xFFFF) * TSTRIDE;
        uint2 v0 = *(const uint2*)(p0 + r0);
        float2 f;
        f = h2f(v0.x); ax += f.x; ay += f.y;  f = h2f(v0.y); az += f.x; aw += f.y;
    }
    float nn = in_norm[n];
    int j = c * 4;
    float* op = out + (size_t)n * NLAB + j;   // rows 8B-aligned only -> float2 stores
    float2 lo; lo.x = ax * nn + bias[j];     lo.y = ay * nn + bias[j + 1];
    *(float2*)op = lo;
    if (j + 2 < NLAB) {
        float2 hi; hi.x = az * nn + bias[j + 2]; hi.y = aw * nn + bias[j + 3];
        *(float2*)(op + 2) = hi;
    }
}

static inline int cdiv(long a, int b) { return (int)((a + b - 1) / b); }

extern "C" void kernel_launch(void* const* d_in, const int* in_sizes, int n_in,
                              void* d_out, int out_size, void* d_ws, size_t ws_size,
                              hipStream_t stream) {
    const int*   dep_labels = (const int*)d_in[0];
    const int*   src        = (const int*)d_in[1];
    const int*   dst        = (const int*)d_in[2];
    const float* emb        = (const float*)d_in[3];
    const float* W1 = (const float*)d_in[4]; const float* b1 = (const float*)d_in[5];
    const float* W2 = (const float*)d_in[6]; const float* b2 = (const float*)d_in[7];
    const float* W3 = (const float*)d_in[8]; const float* b3 = (const float*)d_in[9];
    float* out = (float*)d_out;

    // ---- workspace layout ----
    int* wsp           = (int*)d_ws;
    int* row_off       = wsp;                 wsp += N_NODES;
    int* deg_in_total  = wsp;                 wsp += N_NODES;
    int* rank          = wsp;                 wsp += N_EDGES;
    int* bsum          = wsp;                 wsp += 256;
    float* out_norm    = (float*)wsp;         wsp += N_NODES;
    float* in_norm     = (float*)wsp;         wsp += N_NODES;
    int2* node_info    = (int2*)wsp;          wsp += 2 * N_NODES;
    float* T1          = (float*)wsp;         wsp += NLAB * HID + 16;  // pad
    int2* edge_rec     = (int2*)wsp;          wsp += 2 * N_EDGES;      // 6.4 MB
    float* bufA        = (float*)wsp;         wsp += (size_t)N_NODES * HID;   // agg (fp32)
    __half* bufH       = (__half*)wsp;        // h1s (fp16), then t (fp16, stride 64)
    // cnt/off8 alias into bufA: dead before gather4x2 first writes bufA.
    int* cnt  = (int*)bufA;                       // [16][N] = 3.2 MB
    int* off8 = (int*)bufA + 2 * NXCD * N_NODES;  // [8][N]  = 1.6 MB

    const int B = 256;
    const int NLIN = cdiv(N_NODES, 64);    // 782

    hipMemsetAsync(cnt, 0, (size_t)2 * NXCD * N_NODES * sizeof(int), stream);
    deg_rank_t1_kernel<<<EDGEB + T1B, B, 0, stream>>>(src, dst, cnt, rank, emb, W1, T1);

    scan1_kernel<<<NB_SCAN, 256, 0, stream>>>(cnt, deg_in_total, bsum);
    scan23_kernel<<<NB_SCAN, 256, 0, stream>>>(deg_in_total, bsum, cnt, dep_labels,
                                               row_off, off8, out_norm, in_norm, node_info);
    fill_kernel<<<EDGEB, B, 0, stream>>>(src, dst, off8, rank, node_info, edge_rec);

    // Layer 1 fused: linear edge_rec stream, T1 L1-resident -> h1s (fp16)
    gather1t_kernel<<<cdiv((long)N_NODES * (HID / 8), B), B, 0, stream>>>(
        edge_rec, T1, row_off, deg_in_total, in_norm, out_norm, b1, bufH);

    // Layer 2 aggregate (fp16 rows -> fp32 agg)  [clobbers cnt/off8 aliases]
    gather4x2_kernel<<<cdiv((long)N_NODES * (HID / 8), B), B, 0, stream>>>(
        bufH, row_off, deg_in_total, edge_rec, in_norm, bufA);

    // Layers 2+3 fused transform: agg -> t (fp16 stride 64; h2 stays in LDS)
    linear23_kernel<<<NLIN, 256, 0, stream>>>(bufA, W2, b2, out_norm, W3, bufH);

    // Final gather + bias (fp16 t -> fp32 out)
    gather_out_kernel<<<cdiv((long)N_NODES * TC, B), B, 0, stream>>>(
        bufH, row_off, deg_in_total, edge_rec, in_norm, b3, out);
}

// Round 2
// 250.901 us; speedup vs baseline: 1.1594x; 1.1594x over previous
//
#include <hip/hip_runtime.h>
#include <hip/hip_fp16.h>

// GCN 3-layer, CSR-gather, low-rank L1 + fused L2/L3 transform.
//   CSR build is now GLOBAL-ATOMIC-FREE (gfx950 global atomics write through
//   32B/op to HBM at ~700GB/s -> 78us floor for 1.6M RMWs; scope bits don't
//   change it). Two-level counting sort keyed on dst>>8 (196 buckets x 256
//   nodes), LDS atomics only:
//     coarse_hist (per-block 256-bucket LDS hists of dst>>8 and src>>8, + T1 tail)
//     coarse_scan (per-bucket scan over blocks + bucket bases)
//     partition   (LDS cursors -> dstp: src|(dst&255)<<16, srcp: src&255)
//     fine_hist   (per-bucket LDS hist -> deg_in/deg_out, non-atomic stores)
//     scan1/scan23 -> row_off, norms, node_info
//     fine_scatter (per-node LDS rank cursors -> edge_rec directly; absorbs fill)
//   L1 fused: h1s(fp16) = relu(in_norm*sum w_e*T1[lbl_e] + b1)*out_norm (linear stream)
//   L2 agg:  agg(fp32) = in_norm * gather(h1s fp16, 192B rows)
//   L2+L3 fused GEMM (W2/W3 in LDS), t = h2@W3 stored FP16, row stride 64 halfs
//   out = in_norm*gather(t fp16) + b3      [fp32 accumulate everywhere]
#define N_NODES 50000
#define N_EDGES 800000
#define EMB     64
#define HID     96
#define NLAB    50
#define NB_SCAN ((N_NODES + 255) / 256)    // 196
#define TSTRIDE 64                         // t row stride (halfs): 128B line-aligned
#define TC      13                         // gather chunks over t (cols 0..51)
#define T1B     ((NLAB * HID + 255) / 256) // 19
#define NBP     256                        // partition blocks
#define EPB     ((N_EDGES + NBP - 1) / NBP)  // 3125 edges per block
#define NBUCK   196                        // node buckets of 256 (covers 50176)

__device__ __forceinline__ float2 h2f(unsigned u) {
    __half2 h = *reinterpret_cast<__half2*>(&u);
    return __half22float2(h);
}
__device__ __forceinline__ unsigned f2h(float a, float b) {
    __half2 h = __floats2half2_rn(a, b);
    return *reinterpret_cast<unsigned*>(&h);
}

// Per-block coarse histograms (dst>>8, src>>8) via LDS atomics. Tail blocks
// compute T1 = emb@W1.
__global__ void coarse_hist_kernel(const int* __restrict__ src, const int* __restrict__ dst,
                                   int* __restrict__ histd, int* __restrict__ hists,
                                   const float* __restrict__ emb, const float* __restrict__ W1,
                                   float* __restrict__ T1) {
    int b = blockIdx.x, t = threadIdx.x;
    if (b < NBP) {
        __shared__ int hd[256], hs[256];
        hd[t] = 0; hs[t] = 0;
        __syncthreads();
        int hi = min(b * EPB + EPB, N_EDGES);
        for (int i = b * EPB + t; i < hi; i += 256) {
            atomicAdd(&hd[((unsigned)dst[i]) >> 8], 1);
            atomicAdd(&hs[((unsigned)src[i]) >> 8], 1);
        }
        __syncthreads();
        histd[b * 256 + t] = hd[t];
        hists[b * 256 + t] = hs[t];
    } else {
        int i = (b - NBP) * 256 + t;
        if (i < NLAB * HID) {
            int l = i / HID, j = i - l * HID;
            float sum = 0.0f;
#pragma unroll
            for (int k = 0; k < EMB; ++k) sum += emb[l * EMB + k] * W1[k * HID + j];
            T1[i] = sum;
        }
    }
}

// Block 0: dst side; block 1: src side. Thread t owns bucket t.
// blkrel[b][t] = exclusive prefix of hist[.][t] over blocks; bbase[t] =
// exclusive prefix of bucket totals.
__global__ void coarse_scan_kernel(const int* __restrict__ histd, const int* __restrict__ hists,
                                   int* __restrict__ blkrel_d, int* __restrict__ blkrel_s,
                                   int* __restrict__ bbase_d, int* __restrict__ bbase_s) {
    __shared__ int sh[256];
    int t = threadIdx.x;
    const int* hist = blockIdx.x ? hists : histd;
    int* blkrel     = blockIdx.x ? blkrel_s : blkrel_d;
    int* bbase      = blockIdx.x ? bbase_s : bbase_d;
    int run = 0;
#pragma unroll 4
    for (int b = 0; b < NBP; ++b) {
        blkrel[b * 256 + t] = run;
        run += hist[b * 256 + t];
    }
    sh[t] = run;
    __syncthreads();
    for (int off = 1; off < 256; off <<= 1) {
        int v = sh[t];
        if (t >= off) v += sh[t - off];
        __syncthreads();
        sh[t] = v;
        __syncthreads();
    }
    bbase[t] = sh[t] - run;   // exclusive bucket base
}

// Scatter edges into bucket-partitioned arrays via LDS cursors (no global RMW).
// dstp rec = src | (dst&255)<<16 ; srcp rec = src&255.
__global__ void partition_kernel(const int* __restrict__ src, const int* __restrict__ dst,
                                 const int* __restrict__ blkrel_d, const int* __restrict__ blkrel_s,
                                 const int* __restrict__ bbase_d, const int* __restrict__ bbase_s,
                                 int* __restrict__ dstp, int* __restrict__ srcp) {
    __shared__ int curd[256], curs[256];
    int b = blockIdx.x, t = threadIdx.x;
    curd[t] = bbase_d[t] + blkrel_d[b * 256 + t];
    curs[t] = bbase_s[t] + blkrel_s[b * 256 + t];
    __syncthreads();
    int hi = min(b * EPB + EPB, N_EDGES);
    for (int i = b * EPB + t; i < hi; i += 256) {
        int d = dst[i], s = src[i];
        int pd = atomicAdd(&curd[((unsigned)d) >> 8], 1);
        dstp[pd] = s | ((d & 0xFF) << 16);
        int ps = atomicAdd(&curs[((unsigned)s) >> 8], 1);
        srcp[ps] = s & 0xFF;
    }
}

// Per-bucket fine histogram -> degree arrays (each node in exactly one bucket:
// plain stores, no atomics). Blocks 0..NBUCK-1: dst side; NBUCK..2*NBUCK-1: src.
__global__ void fine_hist_kernel(const int* __restrict__ dstp, const int* __restrict__ srcp,
                                 const int* __restrict__ bbase_d, const int* __restrict__ bbase_s,
                                 int* __restrict__ deg_in, int* __restrict__ deg_out) {
    __shared__ int cnt[256];
    int b = blockIdx.x, t = threadIdx.x;
    cnt[t] = 0;
    __syncthreads();
    if (b < NBUCK) {
        int lo = bbase_d[b], hi = bbase_d[b + 1];
        for (int i = lo + t; i < hi; i += 256)
            atomicAdd(&cnt[(dstp[i] >> 16) & 0xFF], 1);
        __syncthreads();
        int node = b * 256 + t;
        if (node < N_NODES) deg_in[node] = cnt[t];
    } else {
        int bb = b - NBUCK;
        int lo = bbase_s[bb], hi = bbase_s[bb + 1];
        for (int i = lo + t; i < hi; i += 256)
            atomicAdd(&cnt[srcp[i]], 1);
        __syncthreads();
        int node = bb * 256 + t;
        if (node < N_NODES) deg_out[node] = cnt[t];
    }
}

// --- block sums of deg_in ---
__global__ void scan1_kernel(const int* __restrict__ deg, int* __restrict__ bsum) {
    __shared__ int s[256];
    int t = threadIdx.x, i = blockIdx.x * 256 + t;
    s[t] = (i < N_NODES) ? deg[i] : 0;
    for (int off = 128; off > 0; off >>= 1) {
        __syncthreads();
        if (t < off) s[t] += s[t + off];
    }
    if (t == 0) bsum[blockIdx.x] = s[0];
}

// Merged scan2+scan3: each block derives its prefix from bsum, scans its chunk,
// and emits norms + node_info (label<<16 in .x, out_norm bits in .y).
__global__ void scan23_kernel(const int* __restrict__ deg_in, const int* __restrict__ bsum,
                              const int* __restrict__ deg_out, const int* __restrict__ labels,
                              int* __restrict__ row_off,
                              float* __restrict__ out_norm, float* __restrict__ in_norm,
                              int2* __restrict__ node_info) {
    __shared__ int pb[256];
    __shared__ int s[256];
    int t = threadIdx.x, i = blockIdx.x * 256 + t;
    pb[t] = (t < (int)blockIdx.x) ? bsum[t] : 0;
    int own = (i < N_NODES) ? deg_in[i] : 0;
    s[t] = own;
    __syncthreads();
    for (int off = 128; off > 0; off >>= 1) {
        if (t < off) pb[t] += pb[t + off];
        __syncthreads();
    }
    int base = pb[0];
    for (int off = 1; off < 256; off <<= 1) {
        int v = s[t];
        if (t >= off) v += s[t - off];
        __syncthreads();
        s[t] = v;
        __syncthreads();
    }
    if (i < N_NODES) {
        row_off[i] = base + s[t] - own;
        float on = rsqrtf(fmaxf((float)deg_out[i], 1.0f));
        out_norm[i] = on;
        in_norm[i]  = rsqrtf(fmaxf((float)own, 1.0f));
        node_info[i] = make_int2(labels[i] << 16, __float_as_int(on));
    }
}

// One block per dst-bucket: LDS per-node rank cursors -> final edge_rec write
// (absorbs the old fill kernel). rec = {src|label<<16, out_norm}.
__global__ void fine_scatter_kernel(const int* __restrict__ dstp, const int* __restrict__ bbase_d,
                                    const int* __restrict__ row_off,
                                    const int2* __restrict__ node_info,
                                    int2* __restrict__ edge_rec) {
    __shared__ int cur[256];
    __shared__ int ro[256];
    int b = blockIdx.x, t = threadIdx.x;
    int node = b * 256 + t;
    ro[t] = (node < N_NODES) ? row_off[node] : 0;
    cur[t] = 0;
    __syncthreads();
    int lo = bbase_d[b], hi = bbase_d[b + 1];
    for (int i = lo + t; i < hi; i += 256) {
        int rec = dstp[i];
        int s = rec & 0xFFFF;
        int nl = (rec >> 16) & 0xFF;
        int r = atomicAdd(&cur[nl], 1);
        int2 ni = node_info[s];
        edge_rec[ro[nl] + r] = make_int2(s | ni.x, ni.y);
    }
}

// Fused layer 1: 2 float4 chunks per thread, unroll-4 edges; edge_rec read linearly.
// h1s (FP16) = relu(in_norm*sum w_e*T1[lbl_e] + b1) * out_norm
__global__ void gather1t_kernel(const int2* __restrict__ edge_rec, const float* __restrict__ T1,
                                const int* __restrict__ row_off, const int* __restrict__ deg,
                                const float* __restrict__ in_norm,
                                const float* __restrict__ out_norm, const float* __restrict__ b1,
                                __half* __restrict__ h1s) {
    constexpr int C = HID / 8;   // 12 chunk-pairs per node
    int i = blockIdx.x * blockDim.x + threadIdx.x;
    if (i >= N_NODES * C) return;
    int n = i / C;
    int c = i - n * C;
    const float* t1a = T1 + c * 4;
    const float* t1b = T1 + (c + C) * 4;
    int k = row_off[n];
    int e = k + deg[n];
    float ax = 0.f, ay = 0.f, az = 0.f, aw = 0.f;
    float bx = 0.f, by = 0.f, bz = 0.f, bw = 0.f;
    for (; k + 3 < e; k += 4) {
        int2 i0 = edge_rec[k];
        int2 i1 = edge_rec[k + 1];
        int2 i2 = edge_rec[k + 2];
        int2 i3 = edge_rec[k + 3];
        int r0 = ((unsigned)i0.x >> 16) * HID, r1 = ((unsigned)i1.x >> 16) * HID;
        int r2 = ((unsigned)i2.x >> 16) * HID, r3 = ((unsigned)i3.x >> 16) * HID;
        float4 aA = *(const float4*)(t1a + r0); float4 bA = *(const float4*)(t1b + r0);
        float4 aB = *(const float4*)(t1a + r1); float4 bB = *(const float4*)(t1b + r1);
        float4 aC = *(const float4*)(t1a + r2); float4 bC = *(const float4*)(t1b + r2);
        float4 aD = *(const float4*)(t1a + r3); float4 bD = *(const float4*)(t1b + r3);
        float w0 = __int_as_float(i0.y), w1 = __int_as_float(i1.y);
        float w2 = __int_as_float(i2.y), w3 = __int_as_float(i3.y);
        ax += aA.x * w0 + aB.x * w1 + aC.x * w2 + aD.x * w3;
        ay += aA.y * w0 + aB.y * w1 + aC.y * w2 + aD.y * w3;
        az += aA.z * w0 + aB.z * w1 + aC.z * w2 + aD.z * w3;
        aw += aA.w * w0 + aB.w * w1 + aC.w * w2 + aD.w * w3;
        bx += bA.x * w0 + bB.x * w1 + bC.x * w2 + bD.x * w3;
        by += bA.y * w0 + bB.y * w1 + bC.y * w2 + bD.y * w3;
        bz += bA.z * w0 + bB.z * w1 + bC.z * w2 + bD.z * w3;
        bw += bA.w * w0 + bB.w * w1 + bC.w * w2 + bD.w * w3;
    }
    for (; k < e; ++k) {
        int2 i0 = edge_rec[k];
        int r0 = ((unsigned)i0.x >> 16) * HID;
        float4 aA = *(const float4*)(t1a + r0); float4 bA = *(const float4*)(t1b + r0);
        float w0 = __int_as_float(i0.y);
        ax += aA.x * w0; ay += aA.y * w0; az += aA.z * w0; aw += aA.w * w0;
        bx += bA.x * w0; by += bA.y * w0; bz += bA.z * w0; bw += bA.w * w0;
    }
    float nn = in_norm[n];
    float on = out_norm[n];
    float4 b1a = *(const float4*)(b1 + c * 4);
    float4 b1b = *(const float4*)(b1 + (c + C) * 4);
    uint2 rA, rB;
    rA.x = f2h(fmaxf(ax * nn + b1a.x, 0.f) * on, fmaxf(ay * nn + b1a.y, 0.f) * on);
    rA.y = f2h(fmaxf(az * nn + b1a.z, 0.f) * on, fmaxf(aw * nn + b1a.w, 0.f) * on);
    rB.x = f2h(fmaxf(bx * nn + b1b.x, 0.f) * on, fmaxf(by * nn + b1b.y, 0.f) * on);
    rB.y = f2h(fmaxf(bz * nn + b1b.z, 0.f) * on, fmaxf(bw * nn + b1b.w, 0.f) * on);
    __half* op = h1s + (size_t)n * HID;
    *(uint2*)(op + c * 4) = rA;
    *(uint2*)(op + (c + C) * 4) = rB;
}

// Layer-2 aggregate from FP16 rows (192B): src = edge_rec[k].x & 0xFFFF.
__global__ void gather4x2_kernel(const __half* __restrict__ hs, const int* __restrict__ row_off,
                                 const int* __restrict__ deg, const int2* __restrict__ erec,
                                 const float* __restrict__ in_norm, float* __restrict__ out) {
    constexpr int C = HID / 8;   // 12
    int i = blockIdx.x * blockDim.x + threadIdx.x;
    if (i >= N_NODES * C) return;
    int n = i / C;
    int c = i - n * C;
    const __half* p0 = hs + c * 4;
    const __half* p1 = hs + (c + C) * 4;
    int k = row_off[n];
    int e = k + deg[n];
    float ax = 0.f, ay = 0.f, az = 0.f, aw = 0.f;
    float bx = 0.f, by = 0.f, bz = 0.f, bw = 0.f;
    for (; k + 3 < e; k += 4) {
        size_t r0 = (size_t)(erec[k].x & 0xFFFF) * HID;
        size_t r1 = (size_t)(erec[k + 1].x & 0xFFFF) * HID;
        size_t r2 = (size_t)(erec[k + 2].x & 0xFFFF) * HID;
        size_t r3 = (size_t)(erec[k + 3].x & 0xFFFF) * HID;
        uint2 aA = *(const uint2*)(p0 + r0); uint2 bA = *(const uint2*)(p1 + r0);
        uint2 aB = *(const uint2*)(p0 + r1); uint2 bB = *(const uint2*)(p1 + r1);
        uint2 aC = *(const uint2*)(p0 + r2); uint2 bC = *(const uint2*)(p1 + r2);
        uint2 aD = *(const uint2*)(p0 + r3); uint2 bD = *(const uint2*)(p1 + r3);
        float2 f;
        f = h2f(aA.x); ax += f.x; ay += f.y;  f = h2f(aA.y); az += f.x; aw += f.y;
        f = h2f(aB.x); ax += f.x; ay += f.y;  f = h2f(aB.y); az += f.x; aw += f.y;
        f = h2f(aC.x); ax += f.x; ay += f.y;  f = h2f(aC.y); az += f.x; aw += f.y;
        f = h2f(aD.x); ax += f.x; ay += f.y;  f = h2f(aD.y); az += f.x; aw += f.y;
        f = h2f(bA.x); bx += f.x; by += f.y;  f = h2f(bA.y); bz += f.x; bw += f.y;
        f = h2f(bB.x); bx += f.x; by += f.y;  f = h2f(bB.y); bz += f.x; bw += f.y;
        f = h2f(bC.x); bx += f.x; by += f.y;  f = h2f(bC.y); bz += f.x; bw += f.y;
        f = h2f(bD.x); bx += f.x; by += f.y;  f = h2f(bD.y); bz += f.x; bw += f.y;
    }
    for (; k < e; ++k) {
        size_t r0 = (size_t)(erec[k].x & 0xFFFF) * HID;
        uint2 aA = *(const uint2*)(p0 + r0); uint2 bA = *(const uint2*)(p1 + r0);
        float2 f;
        f = h2f(aA.x); ax += f.x; ay += f.y;  f = h2f(aA.y); az += f.x; aw += f.y;
        f = h2f(bA.x); bx += f.x; by += f.y;  f = h2f(bA.y); bz += f.x; bw += f.y;
    }
    float nn = in_norm[n];
    float4 rA, rB;
    rA.x = ax * nn; rA.y = ay * nn; rA.z = az * nn; rA.w = aw * nn;
    rB.x = bx * nn; rB.y = by * nn; rB.z = bz * nn; rB.w = bw * nn;
    float* op = out + (size_t)n * HID;
    *(float4*)(op + c * 4) = rA;
    *(float4*)(op + (c + C) * 4) = rB;
}

// Fused layers 2+3 (LDS-W form): h2 = relu(agg@W2+b2)*out_norm in LDS,
// t = h2@W3 stored FP16 at row stride 64 halfs (128B line-aligned; cols 0..51 used).
__global__ __launch_bounds__(256) void linear23_kernel(
        const float* __restrict__ agg, const float* __restrict__ W2,
        const float* __restrict__ b2, const float* __restrict__ out_norm,
        const float* __restrict__ W3, __half* __restrict__ t) {
    constexpr int INP = 100;
    __shared__ float in_s[64][INP];      // 25.6 KB
    __shared__ float W_s[HID * HID];     // 36.9 KB ([k][j]; phase 2: 96x64)
    __shared__ float bs[HID];
    const int tid = threadIdx.x;
    const int n0 = blockIdx.x * 64;

    for (int idx = tid; idx < 64 * (HID / 4); idx += 256) {
        int m = idx / (HID / 4), c = idx - m * (HID / 4);
        int n = n0 + m;
        float4 v = (n < N_NODES) ? *(const float4*)(agg + (size_t)n * HID + c * 4)
                                 : make_float4(0.f, 0.f, 0.f, 0.f);
        *(float4*)(&in_s[m][c * 4]) = v;
    }
    for (int idx = tid; idx < HID * HID / 4; idx += 256)
        *(float4*)(&W_s[idx * 4]) = *(const float4*)(W2 + idx * 4);
    if (tid < HID) bs[tid] = b2[tid];
    __syncthreads();

    const int tx = tid & 15, ty = tid >> 4;
    const int j0 = tx * 6, m0 = ty * 4;

    // GEMM1: 64x96 @ 96x96
    float acc[4][6];
#pragma unroll
    for (int i = 0; i < 4; ++i)
#pragma unroll
        for (int jj = 0; jj < 6; ++jj) acc[i][jj] = 0.0f;
#pragma unroll 4
    for (int k = 0; k < HID; ++k) {
        float a[4], w[6];
#pragma unroll
        for (int i = 0; i < 4; ++i) a[i] = in_s[m0 + i][k];
#pragma unroll
        for (int jj = 0; jj < 6; ++jj) w[jj] = W_s[k * HID + j0 + jj];
#pragma unroll
        for (int i = 0; i < 4; ++i)
#pragma unroll
            for (int jj = 0; jj < 6; ++jj) acc[i][jj] += a[i] * w[jj];
    }
    __syncthreads();

    // h2 tile -> in_s (in place); W3 (zero-padded to 64 cols) -> W_s
#pragma unroll
    for (int i = 0; i < 4; ++i) {
        int n = n0 + m0 + i;
        float on = (n < N_NODES) ? out_norm[n] : 0.0f;
#pragma unroll
        for (int jj = 0; jj < 6; ++jj)
            in_s[m0 + i][j0 + jj] = fmaxf(acc[i][jj] + bs[j0 + jj], 0.0f) * on;
    }
    for (int idx = tid; idx < HID * 64; idx += 256) {
        int k = idx >> 6, j = idx & 63;
        W_s[idx] = (j < NLAB) ? W3[k * NLAB + j] : 0.0f;
    }
    __syncthreads();

    // GEMM2: 64x96 @ 96x64 (cols >= 50 zero)
    const int j20 = tx * 4;
    float acc2[4][4];
#pragma unroll
    for (int i = 0; i < 4; ++i)
#pragma unroll
        for (int jj = 0; jj < 4; ++jj) acc2[i][jj] = 0.0f;
#pragma unroll 4
    for (int k = 0; k < HID; ++k) {
        float a[4], w[4];
#pragma unroll
        for (int i = 0; i < 4; ++i) a[i] = in_s[m0 + i][k];
#pragma unroll
        for (int jj = 0; jj < 4; ++jj) w[jj] = W_s[k * 64 + j20 + jj];
#pragma unroll
        for (int i = 0; i < 4; ++i)
#pragma unroll
            for (int jj = 0; jj < 4; ++jj) acc2[i][jj] += a[i] * w[jj];
    }
    if (j20 < 4 * TC) {   // tx <= 12: cols 0..51 (52..63 never read)
#pragma unroll
        for (int i = 0; i < 4; ++i) {
            int n = n0 + m0 + i;
            if (n >= N_NODES) break;
            uint2 raw;
            raw.x = f2h(acc2[i][0], acc2[i][1]);
            raw.y = f2h(acc2[i][2], acc2[i][3]);
            *(uint2*)(t + (size_t)n * TSTRIDE + j20) = raw;
        }
    }
}

// Final gather over FP16 t (128B-aligned rows, 1 line each).
__global__ void gather_out_kernel(const __half* __restrict__ t, const int* __restrict__ row_off,
                                  const int* __restrict__ deg, const int2* __restrict__ erec,
                                  const float* __restrict__ in_norm, const float* __restrict__ bias,
                                  float* __restrict__ out) {
    int i = blockIdx.x * blockDim.x + threadIdx.x;
    if (i >= N_NODES * TC) return;
    int n = i / TC;
    int c = i - n * TC;
    const __half* p0 = t + c * 4;
    int k = row_off[n];
    int e = k + deg[n];
    float ax = 0.f, ay = 0.f, az = 0.f, aw = 0.f;
    for (; k + 3 < e; k += 4) {
        size_t r0 = (size_t)(erec[k].x & 0xFFFF) * TSTRIDE;
        size_t r1 = (size_t)(erec[k + 1].x & 0xFFFF) * TSTRIDE;
        size_t r2 = (size_t)(erec[k + 2].x & 0xFFFF) * TSTRIDE;
        size_t r3 = (size_t)(erec[k + 3].x & 0xFFFF) * TSTRIDE;
        uint2 v0 = *(const uint2*)(p0 + r0);
        uint2 v1 = *(const uint2*)(p0 + r1);
        uint2 v2 = *(const uint2*)(p0 + r2);
        uint2 v3 = *(const uint2*)(p0 + r3);
        float2 f;
        f = h2f(v0.x); ax += f.x; ay += f.y;  f = h2f(v0.y); az += f.x; aw += f.y;
        f = h2f(v1.x); ax += f.x; ay += f.y;  f = h2f(v1.y); az += f.x; aw += f.y;
        f = h2f(v2.x); ax += f.x; ay += f.y;  f = h2f(v2.y); az += f.x; aw += f.y;
        f = h2f(v3.x); ax += f.x; ay += f.y;  f = h2f(v3.y); az += f.x; aw += f.y;
    }
    for (; k < e; ++k) {
        size_t r0 = (size_t)(erec[k].x & 0xFFFF) * TSTRIDE;
        uint2 v0 = *(const uint2*)(p0 + r0);
        float2 f;
        f = h2f(v0.x); ax += f.x; ay += f.y;  f = h2f(v0.y); az += f.x; aw += f.y;
    }
    float nn = in_norm[n];
    int j = c * 4;
    float* op = out + (size_t)n * NLAB + j;   // rows 8B-aligned only -> float2 stores
    float2 lo; lo.x = ax * nn + bias[j];     lo.y = ay * nn + bias[j + 1];
    *(float2*)op = lo;
    if (j + 2 < NLAB) {
        float2 hi; hi.x = az * nn + bias[j + 2]; hi.y = aw * nn + bias[j + 3];
        *(float2*)(op + 2) = hi;
    }
}

static inline int cdiv(long a, int b) { return (int)((a + b - 1) / b); }

extern "C" void kernel_launch(void* const* d_in, const int* in_sizes, int n_in,
                              void* d_out, int out_size, void* d_ws, size_t ws_size,
                              hipStream_t stream) {
    const int*   dep_labels = (const int*)d_in[0];
    const int*   src        = (const int*)d_in[1];
    const int*   dst        = (const int*)d_in[2];
    const float* emb        = (const float*)d_in[3];
    const float* W1 = (const float*)d_in[4]; const float* b1 = (const float*)d_in[5];
    const float* W2 = (const float*)d_in[6]; const float* b2 = (const float*)d_in[7];
    const float* W3 = (const float*)d_in[8]; const float* b3 = (const float*)d_in[9];
    float* out = (float*)d_out;

    // ---- workspace layout ----
    int* wsp           = (int*)d_ws;
    int* row_off       = wsp;                 wsp += N_NODES;
    int* deg_in        = wsp;                 wsp += N_NODES;
    int* deg_out_a     = wsp;                 wsp += N_NODES;
    int* bsum          = wsp;                 wsp += 256;
    float* out_norm    = (float*)wsp;         wsp += N_NODES;
    float* in_norm     = (float*)wsp;         wsp += N_NODES;
    int2* node_info    = (int2*)wsp;          wsp += 2 * N_NODES;
    float* T1          = (float*)wsp;         wsp += NLAB * HID + 16;  // pad
    int2* edge_rec     = (int2*)wsp;          wsp += 2 * N_EDGES;      // 6.4 MB
    float* bufA        = (float*)wsp;         wsp += (size_t)N_NODES * HID;   // agg (fp32)
    __half* bufH       = (__half*)wsp;        // h1s (fp16), then t (fp16, stride 64)
    // CSR-build temporaries alias into bufA (dead before gather4x2 writes it):
    int* histd    = (int*)bufA;               // [NBP][256]
    int* hists    = histd + NBP * 256;        // [NBP][256]
    int* blkrel_d = hists + NBP * 256;        // [NBP][256]
    int* blkrel_s = blkrel_d + NBP * 256;     // [NBP][256]
    int* bbase_d  = blkrel_s + NBP * 256;     // [256]
    int* bbase_s  = bbase_d + 256;            // [256]
    int* dstp     = bbase_s + 256;            // [N_EDGES]
    int* srcp     = dstp + N_EDGES;           // [N_EDGES]

    const int B = 256;
    const int NLIN = cdiv(N_NODES, 64);    // 782

    // ---- CSR build: no global atomics anywhere ----
    coarse_hist_kernel<<<NBP + T1B, B, 0, stream>>>(src, dst, histd, hists, emb, W1, T1);
    coarse_scan_kernel<<<2, B, 0, stream>>>(histd, hists, blkrel_d, blkrel_s, bbase_d, bbase_s);
    partition_kernel<<<NBP, B, 0, stream>>>(src, dst, blkrel_d, blkrel_s, bbase_d, bbase_s,
                                            dstp, srcp);
    fine_hist_kernel<<<2 * NBUCK, B, 0, stream>>>(dstp, srcp, bbase_d, bbase_s,
                                                  deg_in, deg_out_a);
    scan1_kernel<<<NB_SCAN, B, 0, stream>>>(deg_in, bsum);
    scan23_kernel<<<NB_SCAN, B, 0, stream>>>(deg_in, bsum, deg_out_a, dep_labels,
                                             row_off, out_norm, in_norm, node_info);
    fine_scatter_kernel<<<NBUCK, B, 0, stream>>>(dstp, bbase_d, row_off, node_info, edge_rec);

    // Layer 1 fused: linear edge_rec stream, T1 L1-resident -> h1s (fp16)
    gather1t_kernel<<<cdiv((long)N_NODES * (HID / 8), B), B, 0, stream>>>(
        edge_rec, T1, row_off, deg_in, in_norm, out_norm, b1, bufH);

    // Layer 2 aggregate (fp16 rows -> fp32 agg)  [clobbers CSR temporaries]
    gather4x2_kernel<<<cdiv((long)N_NODES * (HID / 8), B), B, 0, stream>>>(
        bufH, row_off, deg_in, edge_rec, in_norm, bufA);

    // Layers 2+3 fused transform: agg -> t (fp16 stride 64; h2 stays in LDS)
    linear23_kernel<<<NLIN, 256, 0, stream>>>(bufA, W2, b2, out_norm, W3, bufH);

    // Final gather + bias (fp16 t -> fp32 out)
    gather_out_kernel<<<cdiv((long)N_NODES * TC, B), B, 0, stream>>>(
        bufH, row_off, deg_in, edge_rec, in_norm, b3, out);
}

// Round 3
// 246.303 us; speedup vs baseline: 1.1810x; 1.0187x over previous
//
#include <hip/hip_runtime.h>
#include <hip/hip_fp16.h>

// GCN 3-layer, CSR-gather, low-rank L1 + fused L2/L3 transform.
//   CSR build GLOBAL-ATOMIC-FREE (two-level counting sort, LDS atomics only):
//     coarse_hist -> coarse_scan -> partition -> fine_hist -> scans -> fine_scatter
//   L1 fused: h1s(fp16) = relu(in_norm*sum w_e*T1[lbl_e] + b1)*out_norm (linear stream)
//   L2 agg:  agg(fp32) = in_norm * gather(h1s fp16, 192B rows)
//   L2+L3 fused GEMM: R2 rework — scalar ds_read_b32 issue count was the 47us
//     bottleneck (10 LDS instr / 24 FMA, 8 waves/CU). Now: k-unroll-4 with
//     float4 a-loads (aligned, 2-way-free banks) + float2/float4 w-loads
//     (conflict-free), W2 streamed in two 48-row halves so LDS = 51KB ->
//     3 blocks/CU. FMA floor ~10us.
//   out = in_norm*gather(t fp16) + b3      [fp32 accumulate everywhere]
#define N_NODES 50000
#define N_EDGES 800000
#define EMB     64
#define HID     96
#define NLAB    50
#define NB_SCAN ((N_NODES + 255) / 256)    // 196
#define TSTRIDE 64                         // t row stride (halfs): 128B line-aligned
#define TC      13                         // gather chunks over t (cols 0..51)
#define T1B     ((NLAB * HID + 255) / 256) // 19
#define NBP     256                        // partition blocks
#define EPB     ((N_EDGES + NBP - 1) / NBP)  // 3125 edges per block
#define NBUCK   196                        // node buckets of 256 (covers 50176)

__device__ __forceinline__ float2 h2f(unsigned u) {
    __half2 h = *reinterpret_cast<__half2*>(&u);
    return __half22float2(h);
}
__device__ __forceinline__ unsigned f2h(float a, float b) {
    __half2 h = __floats2half2_rn(a, b);
    return *reinterpret_cast<unsigned*>(&h);
}

// Per-block coarse histograms (dst>>8, src>>8) via LDS atomics. Tail blocks
// compute T1 = emb@W1.
__global__ void coarse_hist_kernel(const int* __restrict__ src, const int* __restrict__ dst,
                                   int* __restrict__ histd, int* __restrict__ hists,
                                   const float* __restrict__ emb, const float* __restrict__ W1,
                                   float* __restrict__ T1) {
    int b = blockIdx.x, t = threadIdx.x;
    if (b < NBP) {
        __shared__ int hd[256], hs[256];
        hd[t] = 0; hs[t] = 0;
        __syncthreads();
        int hi = min(b * EPB + EPB, N_EDGES);
        for (int i = b * EPB + t; i < hi; i += 256) {
            atomicAdd(&hd[((unsigned)dst[i]) >> 8], 1);
            atomicAdd(&hs[((unsigned)src[i]) >> 8], 1);
        }
        __syncthreads();
        histd[b * 256 + t] = hd[t];
        hists[b * 256 + t] = hs[t];
    } else {
        int i = (b - NBP) * 256 + t;
        if (i < NLAB * HID) {
            int l = i / HID, j = i - l * HID;
            float sum = 0.0f;
#pragma unroll
            for (int k = 0; k < EMB; ++k) sum += emb[l * EMB + k] * W1[k * HID + j];
            T1[i] = sum;
        }
    }
}

// Block 0: dst side; block 1: src side. Thread t owns bucket t.
__global__ void coarse_scan_kernel(const int* __restrict__ histd, const int* __restrict__ hists,
                                   int* __restrict__ blkrel_d, int* __restrict__ blkrel_s,
                                   int* __restrict__ bbase_d, int* __restrict__ bbase_s) {
    __shared__ int sh[256];
    int t = threadIdx.x;
    const int* hist = blockIdx.x ? hists : histd;
    int* blkrel     = blockIdx.x ? blkrel_s : blkrel_d;
    int* bbase      = blockIdx.x ? bbase_s : bbase_d;
    int run = 0;
#pragma unroll 4
    for (int b = 0; b < NBP; ++b) {
        blkrel[b * 256 + t] = run;
        run += hist[b * 256 + t];
    }
    sh[t] = run;
    __syncthreads();
    for (int off = 1; off < 256; off <<= 1) {
        int v = sh[t];
        if (t >= off) v += sh[t - off];
        __syncthreads();
        sh[t] = v;
        __syncthreads();
    }
    bbase[t] = sh[t] - run;   // exclusive bucket base
}

// Scatter edges into bucket-partitioned arrays via LDS cursors (no global RMW).
__global__ void partition_kernel(const int* __restrict__ src, const int* __restrict__ dst,
                                 const int* __restrict__ blkrel_d, const int* __restrict__ blkrel_s,
                                 const int* __restrict__ bbase_d, const int* __restrict__ bbase_s,
                                 int* __restrict__ dstp, int* __restrict__ srcp) {
    __shared__ int curd[256], curs[256];
    int b = blockIdx.x, t = threadIdx.x;
    curd[t] = bbase_d[t] + blkrel_d[b * 256 + t];
    curs[t] = bbase_s[t] + blkrel_s[b * 256 + t];
    __syncthreads();
    int hi = min(b * EPB + EPB, N_EDGES);
    for (int i = b * EPB + t; i < hi; i += 256) {
        int d = dst[i], s = src[i];
        int pd = atomicAdd(&curd[((unsigned)d) >> 8], 1);
        dstp[pd] = s | ((d & 0xFF) << 16);
        int ps = atomicAdd(&curs[((unsigned)s) >> 8], 1);
        srcp[ps] = s & 0xFF;
    }
}

// Per-bucket fine histogram -> degree arrays (plain stores, no atomics).
__global__ void fine_hist_kernel(const int* __restrict__ dstp, const int* __restrict__ srcp,
                                 const int* __restrict__ bbase_d, const int* __restrict__ bbase_s,
                                 int* __restrict__ deg_in, int* __restrict__ deg_out) {
    __shared__ int cnt[256];
    int b = blockIdx.x, t = threadIdx.x;
    cnt[t] = 0;
    __syncthreads();
    if (b < NBUCK) {
        int lo = bbase_d[b], hi = bbase_d[b + 1];
        for (int i = lo + t; i < hi; i += 256)
            atomicAdd(&cnt[(dstp[i] >> 16) & 0xFF], 1);
        __syncthreads();
        int node = b * 256 + t;
        if (node < N_NODES) deg_in[node] = cnt[t];
    } else {
        int bb = b - NBUCK;
        int lo = bbase_s[bb], hi = bbase_s[bb + 1];
        for (int i = lo + t; i < hi; i += 256)
            atomicAdd(&cnt[srcp[i]], 1);
        __syncthreads();
        int node = bb * 256 + t;
        if (node < N_NODES) deg_out[node] = cnt[t];
    }
}

// --- block sums of deg_in ---
__global__ void scan1_kernel(const int* __restrict__ deg, int* __restrict__ bsum) {
    __shared__ int s[256];
    int t = threadIdx.x, i = blockIdx.x * 256 + t;
    s[t] = (i < N_NODES) ? deg[i] : 0;
    for (int off = 128; off > 0; off >>= 1) {
        __syncthreads();
        if (t < off) s[t] += s[t + off];
    }
    if (t == 0) bsum[blockIdx.x] = s[0];
}

// Merged scan2+scan3.
__global__ void scan23_kernel(const int* __restrict__ deg_in, const int* __restrict__ bsum,
                              const int* __restrict__ deg_out, const int* __restrict__ labels,
                              int* __restrict__ row_off,
                              float* __restrict__ out_norm, float* __restrict__ in_norm,
                              int2* __restrict__ node_info) {
    __shared__ int pb[256];
    __shared__ int s[256];
    int t = threadIdx.x, i = blockIdx.x * 256 + t;
    pb[t] = (t < (int)blockIdx.x) ? bsum[t] : 0;
    int own = (i < N_NODES) ? deg_in[i] : 0;
    s[t] = own;
    __syncthreads();
    for (int off = 128; off > 0; off >>= 1) {
        if (t < off) pb[t] += pb[t + off];
        __syncthreads();
    }
    int base = pb[0];
    for (int off = 1; off < 256; off <<= 1) {
        int v = s[t];
        if (t >= off) v += s[t - off];
        __syncthreads();
        s[t] = v;
        __syncthreads();
    }
    if (i < N_NODES) {
        row_off[i] = base + s[t] - own;
        float on = rsqrtf(fmaxf((float)deg_out[i], 1.0f));
        out_norm[i] = on;
        in_norm[i]  = rsqrtf(fmaxf((float)own, 1.0f));
        node_info[i] = make_int2(labels[i] << 16, __float_as_int(on));
    }
}

// One block per dst-bucket: LDS per-node rank cursors -> final edge_rec write.
__global__ void fine_scatter_kernel(const int* __restrict__ dstp, const int* __restrict__ bbase_d,
                                    const int* __restrict__ row_off,
                                    const int2* __restrict__ node_info,
                                    int2* __restrict__ edge_rec) {
    __shared__ int cur[256];
    __shared__ int ro[256];
    int b = blockIdx.x, t = threadIdx.x;
    int node = b * 256 + t;
    ro[t] = (node < N_NODES) ? row_off[node] : 0;
    cur[t] = 0;
    __syncthreads();
    int lo = bbase_d[b], hi = bbase_d[b + 1];
    for (int i = lo + t; i < hi; i += 256) {
        int rec = dstp[i];
        int s = rec & 0xFFFF;
        int nl = (rec >> 16) & 0xFF;
        int r = atomicAdd(&cur[nl], 1);
        int2 ni = node_info[s];
        edge_rec[ro[nl] + r] = make_int2(s | ni.x, ni.y);
    }
}

// Fused layer 1: 2 float4 chunks per thread, unroll-4 edges; edge_rec read linearly.
__global__ void gather1t_kernel(const int2* __restrict__ edge_rec, const float* __restrict__ T1,
                                const int* __restrict__ row_off, const int* __restrict__ deg,
                                const float* __restrict__ in_norm,
                                const float* __restrict__ out_norm, const float* __restrict__ b1,
                                __half* __restrict__ h1s) {
    constexpr int C = HID / 8;   // 12 chunk-pairs per node
    int i = blockIdx.x * blockDim.x + threadIdx.x;
    if (i >= N_NODES * C) return;
    int n = i / C;
    int c = i - n * C;
    const float* t1a = T1 + c * 4;
    const float* t1b = T1 + (c + C) * 4;
    int k = row_off[n];
    int e = k + deg[n];
    float ax = 0.f, ay = 0.f, az = 0.f, aw = 0.f;
    float bx = 0.f, by = 0.f, bz = 0.f, bw = 0.f;
    for (; k + 3 < e; k += 4) {
        int2 i0 = edge_rec[k];
        int2 i1 = edge_rec[k + 1];
        int2 i2 = edge_rec[k + 2];
        int2 i3 = edge_rec[k + 3];
        int r0 = ((unsigned)i0.x >> 16) * HID, r1 = ((unsigned)i1.x >> 16) * HID;
        int r2 = ((unsigned)i2.x >> 16) * HID, r3 = ((unsigned)i3.x >> 16) * HID;
        float4 aA = *(const float4*)(t1a + r0); float4 bA = *(const float4*)(t1b + r0);
        float4 aB = *(const float4*)(t1a + r1); float4 bB = *(const float4*)(t1b + r1);
        float4 aC = *(const float4*)(t1a + r2); float4 bC = *(const float4*)(t1b + r2);
        float4 aD = *(const float4*)(t1a + r3); float4 bD = *(const float4*)(t1b + r3);
        float w0 = __int_as_float(i0.y), w1 = __int_as_float(i1.y);
        float w2 = __int_as_float(i2.y), w3 = __int_as_float(i3.y);
        ax += aA.x * w0 + aB.x * w1 + aC.x * w2 + aD.x * w3;
        ay += aA.y * w0 + aB.y * w1 + aC.y * w2 + aD.y * w3;
        az += aA.z * w0 + aB.z * w1 + aC.z * w2 + aD.z * w3;
        aw += aA.w * w0 + aB.w * w1 + aC.w * w2 + aD.w * w3;
        bx += bA.x * w0 + bB.x * w1 + bC.x * w2 + bD.x * w3;
        by += bA.y * w0 + bB.y * w1 + bC.y * w2 + bD.y * w3;
        bz += bA.z * w0 + bB.z * w1 + bC.z * w2 + bD.z * w3;
        bw += bA.w * w0 + bB.w * w1 + bC.w * w2 + bD.w * w3;
    }
    for (; k < e; ++k) {
        int2 i0 = edge_rec[k];
        int r0 = ((unsigned)i0.x >> 16) * HID;
        float4 aA = *(const float4*)(t1a + r0); float4 bA = *(const float4*)(t1b + r0);
        float w0 = __int_as_float(i0.y);
        ax += aA.x * w0; ay += aA.y * w0; az += aA.z * w0; aw += aA.w * w0;
        bx += bA.x * w0; by += bA.y * w0; bz += bA.z * w0; bw += bA.w * w0;
    }
    float nn = in_norm[n];
    float on = out_norm[n];
    float4 b1a = *(const float4*)(b1 + c * 4);
    float4 b1b = *(const float4*)(b1 + (c + C) * 4);
    uint2 rA, rB;
    rA.x = f2h(fmaxf(ax * nn + b1a.x, 0.f) * on, fmaxf(ay * nn + b1a.y, 0.f) * on);
    rA.y = f2h(fmaxf(az * nn + b1a.z, 0.f) * on, fmaxf(aw * nn + b1a.w, 0.f) * on);
    rB.x = f2h(fmaxf(bx * nn + b1b.x, 0.f) * on, fmaxf(by * nn + b1b.y, 0.f) * on);
    rB.y = f2h(fmaxf(bz * nn + b1b.z, 0.f) * on, fmaxf(bw * nn + b1b.w, 0.f) * on);
    __half* op = h1s + (size_t)n * HID;
    *(uint2*)(op + c * 4) = rA;
    *(uint2*)(op + (c + C) * 4) = rB;
}

// Layer-2 aggregate from FP16 rows (192B): src = edge_rec[k].x & 0xFFFF.
__global__ void gather4x2_kernel(const __half* __restrict__ hs, const int* __restrict__ row_off,
                                 const int* __restrict__ deg, const int2* __restrict__ erec,
                                 const float* __restrict__ in_norm, float* __restrict__ out) {
    constexpr int C = HID / 8;   // 12
    int i = blockIdx.x * blockDim.x + threadIdx.x;
    if (i >= N_NODES * C) return;
    int n = i / C;
    int c = i - n * C;
    const __half* p0 = hs + c * 4;
    const __half* p1 = hs + (c + C) * 4;
    int k = row_off[n];
    int e = k + deg[n];
    float ax = 0.f, ay = 0.f, az = 0.f, aw = 0.f;
    float bx = 0.f, by = 0.f, bz = 0.f, bw = 0.f;
    for (; k + 3 < e; k += 4) {
        size_t r0 = (size_t)(erec[k].x & 0xFFFF) * HID;
        size_t r1 = (size_t)(erec[k + 1].x & 0xFFFF) * HID;
        size_t r2 = (size_t)(erec[k + 2].x & 0xFFFF) * HID;
        size_t r3 = (size_t)(erec[k + 3].x & 0xFFFF) * HID;
        uint2 aA = *(const uint2*)(p0 + r0); uint2 bA = *(const uint2*)(p1 + r0);
        uint2 aB = *(const uint2*)(p0 + r1); uint2 bB = *(const uint2*)(p1 + r1);
        uint2 aC = *(const uint2*)(p0 + r2); uint2 bC = *(const uint2*)(p1 + r2);
        uint2 aD = *(const uint2*)(p0 + r3); uint2 bD = *(const uint2*)(p1 + r3);
        float2 f;
        f = h2f(aA.x); ax += f.x; ay += f.y;  f = h2f(aA.y); az += f.x; aw += f.y;
        f = h2f(aB.x); ax += f.x; ay += f.y;  f = h2f(aB.y); az += f.x; aw += f.y;
        f = h2f(aC.x); ax += f.x; ay += f.y;  f = h2f(aC.y); az += f.x; aw += f.y;
        f = h2f(aD.x); ax += f.x; ay += f.y;  f = h2f(aD.y); az += f.x; aw += f.y;
        f = h2f(bA.x); bx += f.x; by += f.y;  f = h2f(bA.y); bz += f.x; bw += f.y;
        f = h2f(bB.x); bx += f.x; by += f.y;  f = h2f(bB.y); bz += f.x; bw += f.y;
        f = h2f(bC.x); bx += f.x; by += f.y;  f = h2f(bC.y); bz += f.x; bw += f.y;
        f = h2f(bD.x); bx += f.x; by += f.y;  f = h2f(bD.y); bz += f.x; bw += f.y;
    }
    for (; k < e; ++k) {
        size_t r0 = (size_t)(erec[k].x & 0xFFFF) * HID;
        uint2 aA = *(const uint2*)(p0 + r0); uint2 bA = *(const uint2*)(p1 + r0);
        float2 f;
        f = h2f(aA.x); ax += f.x; ay += f.y;  f = h2f(aA.y); az += f.x; aw += f.y;
        f = h2f(bA.x); bx += f.x; by += f.y;  f = h2f(bA.y); bz += f.x; bw += f.y;
    }
    float nn = in_norm[n];
    float4 rA, rB;
    rA.x = ax * nn; rA.y = ay * nn; rA.z = az * nn; rA.w = aw * nn;
    rB.x = bx * nn; rB.y = by * nn; rB.z = bz * nn; rB.w = bw * nn;
    float* op = out + (size_t)n * HID;
    *(float4*)(op + c * 4) = rA;
    *(float4*)(op + (c + C) * 4) = rB;
}

// Fused layers 2+3. R2: vectorized LDS reads + W2 streamed in two halves.
// LDS: in_s 25.6KB + W_s 24.6KB + bs -> ~51KB -> 3 blocks/CU.
__global__ __launch_bounds__(256) void linear23_kernel(
        const float* __restrict__ agg, const float* __restrict__ W2,
        const float* __restrict__ b2, const float* __restrict__ out_norm,
        const float* __restrict__ W3, __half* __restrict__ t) {
    __shared__ float in_s[64][100];      // 25.6 KB (stride 100: float4 k-loads stay aligned)
    __shared__ float W_s[96 * 64];       // 24.6 KB (phase1: [48][96] W2-half; phase2: [96][64] W3)
    __shared__ float bs[HID];
    const int tid = threadIdx.x;
    const int n0 = blockIdx.x * 64;

    for (int idx = tid; idx < 64 * (HID / 4); idx += 256) {
        int m = idx / (HID / 4), c = idx - m * (HID / 4);
        int n = n0 + m;
        float4 v = (n < N_NODES) ? *(const float4*)(agg + (size_t)n * HID + c * 4)
                                 : make_float4(0.f, 0.f, 0.f, 0.f);
        *(float4*)(&in_s[m][c * 4]) = v;
    }
    // W2 rows 0..47
    for (int idx = tid; idx < 48 * (HID / 4); idx += 256)
        *(float4*)(&W_s[idx * 4]) = *(const float4*)(W2 + idx * 4);
    if (tid < HID) bs[tid] = b2[tid];
    __syncthreads();

    const int tx = tid & 15, ty = tid >> 4;
    const int j0 = tx * 6, m0 = ty * 4;

    // GEMM1: 64x96 @ 96x96, k-unroll-4, vector LDS reads.
    float acc[4][6];
#pragma unroll
    for (int i = 0; i < 4; ++i)
#pragma unroll
        for (int jj = 0; jj < 6; ++jj) acc[i][jj] = 0.0f;

#pragma unroll 2
    for (int k = 0; k < 48; k += 4) {
        float a4[4][4];
#pragma unroll
        for (int i = 0; i < 4; ++i)
            *(float4*)(a4[i]) = *(const float4*)(&in_s[m0 + i][k]);
#pragma unroll
        for (int q = 0; q < 4; ++q) {
            float w[6];
            *(float2*)(w)     = *(const float2*)(&W_s[(k + q) * HID + j0]);
            *(float2*)(w + 2) = *(const float2*)(&W_s[(k + q) * HID + j0 + 2]);
            *(float2*)(w + 4) = *(const float2*)(&W_s[(k + q) * HID + j0 + 4]);
#pragma unroll
            for (int i = 0; i < 4; ++i)
#pragma unroll
                for (int jj = 0; jj < 6; ++jj) acc[i][jj] += a4[i][q] * w[jj];
        }
    }
    __syncthreads();
    // W2 rows 48..95
    for (int idx = tid; idx < 48 * (HID / 4); idx += 256)
        *(float4*)(&W_s[idx * 4]) = *(const float4*)(W2 + 48 * HID + idx * 4);
    __syncthreads();
#pragma unroll 2
    for (int k = 48; k < 96; k += 4) {
        float a4[4][4];
#pragma unroll
        for (int i = 0; i < 4; ++i)
            *(float4*)(a4[i]) = *(const float4*)(&in_s[m0 + i][k]);
#pragma unroll
        for (int q = 0; q < 4; ++q) {
            float w[6];
            *(float2*)(w)     = *(const float2*)(&W_s[(k - 48 + q) * HID + j0]);
            *(float2*)(w + 2) = *(const float2*)(&W_s[(k - 48 + q) * HID + j0 + 2]);
            *(float2*)(w + 4) = *(const float2*)(&W_s[(k - 48 + q) * HID + j0 + 4]);
#pragma unroll
            for (int i = 0; i < 4; ++i)
#pragma unroll
                for (int jj = 0; jj < 6; ++jj) acc[i][jj] += a4[i][q] * w[jj];
        }
    }
    __syncthreads();

    // h2 tile -> in_s (in place); W3 (zero-padded to 64 cols) -> W_s
#pragma unroll
    for (int i = 0; i < 4; ++i) {
        int n = n0 + m0 + i;
        float on = (n < N_NODES) ? out_norm[n] : 0.0f;
#pragma unroll
        for (int jj = 0; jj < 6; ++jj)
            in_s[m0 + i][j0 + jj] = fmaxf(acc[i][jj] + bs[j0 + jj], 0.0f) * on;
    }
    for (int idx = tid; idx < HID * 64; idx += 256) {
        int k = idx >> 6, j = idx & 63;
        W_s[idx] = (j < NLAB) ? W3[k * NLAB + j] : 0.0f;
    }
    __syncthreads();

    // GEMM2: 64x96 @ 96x64 (cols >= 50 zero), k-unroll-4, vector LDS reads.
    const int j20 = tx * 4;
    float acc2[4][4];
#pragma unroll
    for (int i = 0; i < 4; ++i)
#pragma unroll
        for (int jj = 0; jj < 4; ++jj) acc2[i][jj] = 0.0f;
#pragma unroll 2
    for (int k = 0; k < 96; k += 4) {
        float a4[4][4];
#pragma unroll
        for (int i = 0; i < 4; ++i)
            *(float4*)(a4[i]) = *(const float4*)(&in_s[m0 + i][k]);
#pragma unroll
        for (int q = 0; q < 4; ++q) {
            float w[4];
            *(float4*)(w) = *(const float4*)(&W_s[(k + q) * 64 + j20]);
#pragma unroll
            for (int i = 0; i < 4; ++i)
#pragma unroll
                for (int jj = 0; jj < 4; ++jj) acc2[i][jj] += a4[i][q] * w[jj];
        }
    }
    if (j20 < 4 * TC) {   // tx <= 12: cols 0..51 (52..63 never read)
#pragma unroll
        for (int i = 0; i < 4; ++i) {
            int n = n0 + m0 + i;
            if (n >= N_NODES) break;
            uint2 raw;
            raw.x = f2h(acc2[i][0], acc2[i][1]);
            raw.y = f2h(acc2[i][2], acc2[i][3]);
            *(uint2*)(t + (size_t)n * TSTRIDE + j20) = raw;
        }
    }
}

// Final gather over FP16 t (128B-aligned rows, 1 line each).
__global__ void gather_out_kernel(const __half* __restrict__ t, const int* __restrict__ row_off,
                                  const int* __restrict__ deg, const int2* __restrict__ erec,
                                  const float* __restrict__ in_norm, const float* __restrict__ bias,
                                  float* __restrict__ out) {
    int i = blockIdx.x * blockDim.x + threadIdx.x;
    if (i >= N_NODES * TC) return;
    int n = i / TC;
    int c = i - n * TC;
    const __half* p0 = t + c * 4;
    int k = row_off[n];
    int e = k + deg[n];
    float ax = 0.f, ay = 0.f, az = 0.f, aw = 0.f;
    for (; k + 3 < e; k += 4) {
        size_t r0 = (size_t)(erec[k].x & 0xFFFF) * TSTRIDE;
        size_t r1 = (size_t)(erec[k + 1].x & 0xFFFF) * TSTRIDE;
        size_t r2 = (size_t)(erec[k + 2].x & 0xFFFF) * TSTRIDE;
        size_t r3 = (size_t)(erec[k + 3].x & 0xFFFF) * TSTRIDE;
        uint2 v0 = *(const uint2*)(p0 + r0);
        uint2 v1 = *(const uint2*)(p0 + r1);
        uint2 v2 = *(const uint2*)(p0 + r2);
        uint2 v3 = *(const uint2*)(p0 + r3);
        float2 f;
        f = h2f(v0.x); ax += f.x; ay += f.y;  f = h2f(v0.y); az += f.x; aw += f.y;
        f = h2f(v1.x); ax += f.x; ay += f.y;  f = h2f(v1.y); az += f.x; aw += f.y;
        f = h2f(v2.x); ax += f.x; ay += f.y;  f = h2f(v2.y); az += f.x; aw += f.y;
        f = h2f(v3.x); ax += f.x; ay += f.y;  f = h2f(v3.y); az += f.x; aw += f.y;
    }
    for (; k < e; ++k) {
        size_t r0 = (size_t)(erec[k].x & 0xFFFF) * TSTRIDE;
        uint2 v0 = *(const uint2*)(p0 + r0);
        float2 f;
        f = h2f(v0.x); ax += f.x; ay += f.y;  f = h2f(v0.y); az += f.x; aw += f.y;
    }
    float nn = in_norm[n];
    int j = c * 4;
    float* op = out + (size_t)n * NLAB + j;   // rows 8B-aligned only -> float2 stores
    float2 lo; lo.x = ax * nn + bias[j];     lo.y = ay * nn + bias[j + 1];
    *(float2*)op = lo;
    if (j + 2 < NLAB) {
        float2 hi; hi.x = az * nn + bias[j + 2]; hi.y = aw * nn + bias[j + 3];
        *(float2*)(op + 2) = hi;
    }
}

static inline int cdiv(long a, int b) { return (int)((a + b - 1) / b); }

extern "C" void kernel_launch(void* const* d_in, const int* in_sizes, int n_in,
                              void* d_out, int out_size, void* d_ws, size_t ws_size,
                              hipStream_t stream) {
    const int*   dep_labels = (const int*)d_in[0];
    const int*   src        = (const int*)d_in[1];
    const int*   dst        = (const int*)d_in[2];
    const float* emb        = (const float*)d_in[3];
    const float* W1 = (const float*)d_in[4]; const float* b1 = (const float*)d_in[5];
    const float* W2 = (const float*)d_in[6]; const float* b2 = (const float*)d_in[7];
    const float* W3 = (const float*)d_in[8]; const float* b3 = (const float*)d_in[9];
    float* out = (float*)d_out;

    // ---- workspace layout ----
    int* wsp           = (int*)d_ws;
    int* row_off       = wsp;                 wsp += N_NODES;
    int* deg_in        = wsp;                 wsp += N_NODES;
    int* deg_out_a     = wsp;                 wsp += N_NODES;
    int* bsum          = wsp;                 wsp += 256;
    float* out_norm    = (float*)wsp;         wsp += N_NODES;
    float* in_norm     = (float*)wsp;         wsp += N_NODES;
    int2* node_info    = (int2*)wsp;          wsp += 2 * N_NODES;
    float* T1          = (float*)wsp;         wsp += NLAB * HID + 16;  // pad
    int2* edge_rec     = (int2*)wsp;          wsp += 2 * N_EDGES;      // 6.4 MB
    float* bufA        = (float*)wsp;         wsp += (size_t)N_NODES * HID;   // agg (fp32)
    __half* bufH       = (__half*)wsp;        // h1s (fp16), then t (fp16, stride 64)
    // CSR-build temporaries alias into bufA (dead before gather4x2 writes it):
    int* histd    = (int*)bufA;               // [NBP][256]
    int* hists    = histd + NBP * 256;        // [NBP][256]
    int* blkrel_d = hists + NBP * 256;        // [NBP][256]
    int* blkrel_s = blkrel_d + NBP * 256;     // [NBP][256]
    int* bbase_d  = blkrel_s + NBP * 256;     // [256]
    int* bbase_s  = bbase_d + 256;            // [256]
    int* dstp     = bbase_s + 256;            // [N_EDGES]
    int* srcp     = dstp + N_EDGES;           // [N_EDGES]

    const int B = 256;
    const int NLIN = cdiv(N_NODES, 64);    // 782

    // ---- CSR build: no global atomics anywhere ----
    coarse_hist_kernel<<<NBP + T1B, B, 0, stream>>>(src, dst, histd, hists, emb, W1, T1);
    coarse_scan_kernel<<<2, B, 0, stream>>>(histd, hists, blkrel_d, blkrel_s, bbase_d, bbase_s);
    partition_kernel<<<NBP, B, 0, stream>>>(src, dst, blkrel_d, blkrel_s, bbase_d, bbase_s,
                                            dstp, srcp);
    fine_hist_kernel<<<2 * NBUCK, B, 0, stream>>>(dstp, srcp, bbase_d, bbase_s,
                                                  deg_in, deg_out_a);
    scan1_kernel<<<NB_SCAN, B, 0, stream>>>(deg_in, bsum);
    scan23_kernel<<<NB_SCAN, B, 0, stream>>>(deg_in, bsum, deg_out_a, dep_labels,
                                             row_off, out_norm, in_norm, node_info);
    fine_scatter_kernel<<<NBUCK, B, 0, stream>>>(dstp, bbase_d, row_off, node_info, edge_rec);

    // Layer 1 fused: linear edge_rec stream, T1 L1-resident -> h1s (fp16)
    gather1t_kernel<<<cdiv((long)N_NODES * (HID / 8), B), B, 0, stream>>>(
        edge_rec, T1, row_off, deg_in, in_norm, out_norm, b1, bufH);

    // Layer 2 aggregate (fp16 rows -> fp32 agg)  [clobbers CSR temporaries]
    gather4x2_kernel<<<cdiv((long)N_NODES * (HID / 8), B), B, 0, stream>>>(
        bufH, row_off, deg_in, edge_rec, in_norm, bufA);

    // Layers 2+3 fused transform: agg -> t (fp16 stride 64; h2 stays in LDS)
    linear23_kernel<<<NLIN, 256, 0, stream>>>(bufA, W2, b2, out_norm, W3, bufH);

    // Final gather + bias (fp16 t -> fp32 out)
    gather_out_kernel<<<cdiv((long)N_NODES * TC, B), B, 0, stream>>>(
        bufH, row_off, deg_in, edge_rec, in_norm, b3, out);
}

// Round 4
// 237.945 us; speedup vs baseline: 1.2225x; 1.0351x over previous
//
#include <hip/hip_runtime.h>
#include <hip/hip_fp16.h>

// GCN 3-layer, CSR-gather, low-rank L1 + fused L2/L3 transform.
//   CSR build GLOBAL-ATOMIC-FREE (two-level counting sort, LDS atomics only):
//     coarse_hist -> coarse_scan -> partition -> fine_hist -> scans -> fine_scatter
//   L1 fused: h1s(fp16) = relu(in_norm*sum w_e*T1[lbl_e] + b1)*out_norm (linear stream)
//   L2 agg:  agg(fp32) = in_norm * gather(h1s fp16, 192B rows)
//   L2+L3 fused GEMM: R3 rework — R2 (vector LDS reads, +occupancy) was NULL;
//     waves are >90% stalled on ds_read->FMA latency (VGPR=68: compiler built
//     no pipeline). Now: explicit register double-buffering, load-use distance
//     = one 96-FMA block; full W2 in LDS (63KB, 2 blk/CU — occupancy proved
//     non-binding), no mid-loop W2 reload.
//   out = in_norm*gather(t fp16) + b3      [fp32 accumulate everywhere]
#define N_NODES 50000
#define N_EDGES 800000
#define EMB     64
#define HID     96
#define NLAB    50
#define NB_SCAN ((N_NODES + 255) / 256)    // 196
#define TSTRIDE 64                         // t row stride (halfs): 128B line-aligned
#define TC      13                         // gather chunks over t (cols 0..51)
#define T1B     ((NLAB * HID + 255) / 256) // 19
#define NBP     256                        // partition blocks
#define EPB     ((N_EDGES + NBP - 1) / NBP)  // 3125 edges per block
#define NBUCK   196                        // node buckets of 256 (covers 50176)

__device__ __forceinline__ float2 h2f(unsigned u) {
    __half2 h = *reinterpret_cast<__half2*>(&u);
    return __half22float2(h);
}
__device__ __forceinline__ unsigned f2h(float a, float b) {
    __half2 h = __floats2half2_rn(a, b);
    return *reinterpret_cast<unsigned*>(&h);
}

// Per-block coarse histograms (dst>>8, src>>8) via LDS atomics. Tail blocks
// compute T1 = emb@W1.
__global__ void coarse_hist_kernel(const int* __restrict__ src, const int* __restrict__ dst,
                                   int* __restrict__ histd, int* __restrict__ hists,
                                   const float* __restrict__ emb, const float* __restrict__ W1,
                                   float* __restrict__ T1) {
    int b = blockIdx.x, t = threadIdx.x;
    if (b < NBP) {
        __shared__ int hd[256], hs[256];
        hd[t] = 0; hs[t] = 0;
        __syncthreads();
        int hi = min(b * EPB + EPB, N_EDGES);
        for (int i = b * EPB + t; i < hi; i += 256) {
            atomicAdd(&hd[((unsigned)dst[i]) >> 8], 1);
            atomicAdd(&hs[((unsigned)src[i]) >> 8], 1);
        }
        __syncthreads();
        histd[b * 256 + t] = hd[t];
        hists[b * 256 + t] = hs[t];
    } else {
        int i = (b - NBP) * 256 + t;
        if (i < NLAB * HID) {
            int l = i / HID, j = i - l * HID;
            float sum = 0.0f;
#pragma unroll
            for (int k = 0; k < EMB; ++k) sum += emb[l * EMB + k] * W1[k * HID + j];
            T1[i] = sum;
        }
    }
}

// Block 0: dst side; block 1: src side. Thread t owns bucket t.
__global__ void coarse_scan_kernel(const int* __restrict__ histd, const int* __restrict__ hists,
                                   int* __restrict__ blkrel_d, int* __restrict__ blkrel_s,
                                   int* __restrict__ bbase_d, int* __restrict__ bbase_s) {
    __shared__ int sh[256];
    int t = threadIdx.x;
    const int* hist = blockIdx.x ? hists : histd;
    int* blkrel     = blockIdx.x ? blkrel_s : blkrel_d;
    int* bbase      = blockIdx.x ? bbase_s : bbase_d;
    int run = 0;
#pragma unroll 16
    for (int b = 0; b < NBP; ++b) {
        blkrel[b * 256 + t] = run;
        run += hist[b * 256 + t];
    }
    sh[t] = run;
    __syncthreads();
    for (int off = 1; off < 256; off <<= 1) {
        int v = sh[t];
        if (t >= off) v += sh[t - off];
        __syncthreads();
        sh[t] = v;
        __syncthreads();
    }
    bbase[t] = sh[t] - run;   // exclusive bucket base
}

// Scatter edges into bucket-partitioned arrays via LDS cursors (no global RMW).
__global__ void partition_kernel(const int* __restrict__ src, const int* __restrict__ dst,
                                 const int* __restrict__ blkrel_d, const int* __restrict__ blkrel_s,
                                 const int* __restrict__ bbase_d, const int* __restrict__ bbase_s,
                                 int* __restrict__ dstp, int* __restrict__ srcp) {
    __shared__ int curd[256], curs[256];
    int b = blockIdx.x, t = threadIdx.x;
    curd[t] = bbase_d[t] + blkrel_d[b * 256 + t];
    curs[t] = bbase_s[t] + blkrel_s[b * 256 + t];
    __syncthreads();
    int hi = min(b * EPB + EPB, N_EDGES);
    for (int i = b * EPB + t; i < hi; i += 256) {
        int d = dst[i], s = src[i];
        int pd = atomicAdd(&curd[((unsigned)d) >> 8], 1);
        dstp[pd] = s | ((d & 0xFF) << 16);
        int ps = atomicAdd(&curs[((unsigned)s) >> 8], 1);
        srcp[ps] = s & 0xFF;
    }
}

// Per-bucket fine histogram -> degree arrays (plain stores, no atomics).
__global__ void fine_hist_kernel(const int* __restrict__ dstp, const int* __restrict__ srcp,
                                 const int* __restrict__ bbase_d, const int* __restrict__ bbase_s,
                                 int* __restrict__ deg_in, int* __restrict__ deg_out) {
    __shared__ int cnt[256];
    int b = blockIdx.x, t = threadIdx.x;
    cnt[t] = 0;
    __syncthreads();
    if (b < NBUCK) {
        int lo = bbase_d[b], hi = bbase_d[b + 1];
        for (int i = lo + t; i < hi; i += 256)
            atomicAdd(&cnt[(dstp[i] >> 16) & 0xFF], 1);
        __syncthreads();
        int node = b * 256 + t;
        if (node < N_NODES) deg_in[node] = cnt[t];
    } else {
        int bb = b - NBUCK;
        int lo = bbase_s[bb], hi = bbase_s[bb + 1];
        for (int i = lo + t; i < hi; i += 256)
            atomicAdd(&cnt[srcp[i]], 1);
        __syncthreads();
        int node = bb * 256 + t;
        if (node < N_NODES) deg_out[node] = cnt[t];
    }
}

// --- block sums of deg_in ---
__global__ void scan1_kernel(const int* __restrict__ deg, int* __restrict__ bsum) {
    __shared__ int s[256];
    int t = threadIdx.x, i = blockIdx.x * 256 + t;
    s[t] = (i < N_NODES) ? deg[i] : 0;
    for (int off = 128; off > 0; off >>= 1) {
        __syncthreads();
        if (t < off) s[t] += s[t + off];
    }
    if (t == 0) bsum[blockIdx.x] = s[0];
}

// Merged scan2+scan3.
__global__ void scan23_kernel(const int* __restrict__ deg_in, const int* __restrict__ bsum,
                              const int* __restrict__ deg_out, const int* __restrict__ labels,
                              int* __restrict__ row_off,
                              float* __restrict__ out_norm, float* __restrict__ in_norm,
                              int2* __restrict__ node_info) {
    __shared__ int pb[256];
    __shared__ int s[256];
    int t = threadIdx.x, i = blockIdx.x * 256 + t;
    pb[t] = (t < (int)blockIdx.x) ? bsum[t] : 0;
    int own = (i < N_NODES) ? deg_in[i] : 0;
    s[t] = own;
    __syncthreads();
    for (int off = 128; off > 0; off >>= 1) {
        if (t < off) pb[t] += pb[t + off];
        __syncthreads();
    }
    int base = pb[0];
    for (int off = 1; off < 256; off <<= 1) {
        int v = s[t];
        if (t >= off) v += s[t - off];
        __syncthreads();
        s[t] = v;
        __syncthreads();
    }
    if (i < N_NODES) {
        row_off[i] = base + s[t] - own;
        float on = rsqrtf(fmaxf((float)deg_out[i], 1.0f));
        out_norm[i] = on;
        in_norm[i]  = rsqrtf(fmaxf((float)own, 1.0f));
        node_info[i] = make_int2(labels[i] << 16, __float_as_int(on));
    }
}

// One block per dst-bucket: LDS per-node rank cursors -> final edge_rec write.
__global__ void fine_scatter_kernel(const int* __restrict__ dstp, const int* __restrict__ bbase_d,
                                    const int* __restrict__ row_off,
                                    const int2* __restrict__ node_info,
                                    int2* __restrict__ edge_rec) {
    __shared__ int cur[256];
    __shared__ int ro[256];
    int b = blockIdx.x, t = threadIdx.x;
    int node = b * 256 + t;
    ro[t] = (node < N_NODES) ? row_off[node] : 0;
    cur[t] = 0;
    __syncthreads();
    int lo = bbase_d[b], hi = bbase_d[b + 1];
    for (int i = lo + t; i < hi; i += 256) {
        int rec = dstp[i];
        int s = rec & 0xFFFF;
        int nl = (rec >> 16) & 0xFF;
        int r = atomicAdd(&cur[nl], 1);
        int2 ni = node_info[s];
        edge_rec[ro[nl] + r] = make_int2(s | ni.x, ni.y);
    }
}

// Fused layer 1: 2 float4 chunks per thread, unroll-4 edges; edge_rec read linearly.
__global__ void gather1t_kernel(const int2* __restrict__ edge_rec, const float* __restrict__ T1,
                                const int* __restrict__ row_off, const int* __restrict__ deg,
                                const float* __restrict__ in_norm,
                                const float* __restrict__ out_norm, const float* __restrict__ b1,
                                __half* __restrict__ h1s) {
    constexpr int C = HID / 8;   // 12 chunk-pairs per node
    int i = blockIdx.x * blockDim.x + threadIdx.x;
    if (i >= N_NODES * C) return;
    int n = i / C;
    int c = i - n * C;
    const float* t1a = T1 + c * 4;
    const float* t1b = T1 + (c + C) * 4;
    int k = row_off[n];
    int e = k + deg[n];
    float ax = 0.f, ay = 0.f, az = 0.f, aw = 0.f;
    float bx = 0.f, by = 0.f, bz = 0.f, bw = 0.f;
    for (; k + 3 < e; k += 4) {
        int2 i0 = edge_rec[k];
        int2 i1 = edge_rec[k + 1];
        int2 i2 = edge_rec[k + 2];
        int2 i3 = edge_rec[k + 3];
        int r0 = ((unsigned)i0.x >> 16) * HID, r1 = ((unsigned)i1.x >> 16) * HID;
        int r2 = ((unsigned)i2.x >> 16) * HID, r3 = ((unsigned)i3.x >> 16) * HID;
        float4 aA = *(const float4*)(t1a + r0); float4 bA = *(const float4*)(t1b + r0);
        float4 aB = *(const float4*)(t1a + r1); float4 bB = *(const float4*)(t1b + r1);
        float4 aC = *(const float4*)(t1a + r2); float4 bC = *(const float4*)(t1b + r2);
        float4 aD = *(const float4*)(t1a + r3); float4 bD = *(const float4*)(t1b + r3);
        float w0 = __int_as_float(i0.y), w1 = __int_as_float(i1.y);
        float w2 = __int_as_float(i2.y), w3 = __int_as_float(i3.y);
        ax += aA.x * w0 + aB.x * w1 + aC.x * w2 + aD.x * w3;
        ay += aA.y * w0 + aB.y * w1 + aC.y * w2 + aD.y * w3;
        az += aA.z * w0 + aB.z * w1 + aC.z * w2 + aD.z * w3;
        aw += aA.w * w0 + aB.w * w1 + aC.w * w2 + aD.w * w3;
        bx += bA.x * w0 + bB.x * w1 + bC.x * w2 + bD.x * w3;
        by += bA.y * w0 + bB.y * w1 + bC.y * w2 + bD.y * w3;
        bz += bA.z * w0 + bB.z * w1 + bC.z * w2 + bD.z * w3;
        bw += bA.w * w0 + bB.w * w1 + bC.w * w2 + bD.w * w3;
    }
    for (; k < e; ++k) {
        int2 i0 = edge_rec[k];
        int r0 = ((unsigned)i0.x >> 16) * HID;
        float4 aA = *(const float4*)(t1a + r0); float4 bA = *(const float4*)(t1b + r0);
        float w0 = __int_as_float(i0.y);
        ax += aA.x * w0; ay += aA.y * w0; az += aA.z * w0; aw += aA.w * w0;
        bx += bA.x * w0; by += bA.y * w0; bz += bA.z * w0; bw += bA.w * w0;
    }
    float nn = in_norm[n];
    float on = out_norm[n];
    float4 b1a = *(const float4*)(b1 + c * 4);
    float4 b1b = *(const float4*)(b1 + (c + C) * 4);
    uint2 rA, rB;
    rA.x = f2h(fmaxf(ax * nn + b1a.x, 0.f) * on, fmaxf(ay * nn + b1a.y, 0.f) * on);
    rA.y = f2h(fmaxf(az * nn + b1a.z, 0.f) * on, fmaxf(aw * nn + b1a.w, 0.f) * on);
    rB.x = f2h(fmaxf(bx * nn + b1b.x, 0.f) * on, fmaxf(by * nn + b1b.y, 0.f) * on);
    rB.y = f2h(fmaxf(bz * nn + b1b.z, 0.f) * on, fmaxf(bw * nn + b1b.w, 0.f) * on);
    __half* op = h1s + (size_t)n * HID;
    *(uint2*)(op + c * 4) = rA;
    *(uint2*)(op + (c + C) * 4) = rB;
}

// Layer-2 aggregate from FP16 rows (192B): src = edge_rec[k].x & 0xFFFF.
__global__ void gather4x2_kernel(const __half* __restrict__ hs, const int* __restrict__ row_off,
                                 const int* __restrict__ deg, const int2* __restrict__ erec,
                                 const float* __restrict__ in_norm, float* __restrict__ out) {
    constexpr int C = HID / 8;   // 12
    int i = blockIdx.x * blockDim.x + threadIdx.x;
    if (i >= N_NODES * C) return;
    int n = i / C;
    int c = i - n * C;
    const __half* p0 = hs + c * 4;
    const __half* p1 = hs + (c + C) * 4;
    int k = row_off[n];
    int e = k + deg[n];
    float ax = 0.f, ay = 0.f, az = 0.f, aw = 0.f;
    float bx = 0.f, by = 0.f, bz = 0.f, bw = 0.f;
    for (; k + 3 < e; k += 4) {
        size_t r0 = (size_t)(erec[k].x & 0xFFFF) * HID;
        size_t r1 = (size_t)(erec[k + 1].x & 0xFFFF) * HID;
        size_t r2 = (size_t)(erec[k + 2].x & 0xFFFF) * HID;
        size_t r3 = (size_t)(erec[k + 3].x & 0xFFFF) * HID;
        uint2 aA = *(const uint2*)(p0 + r0); uint2 bA = *(const uint2*)(p1 + r0);
        uint2 aB = *(const uint2*)(p0 + r1); uint2 bB = *(const uint2*)(p1 + r1);
        uint2 aC = *(const uint2*)(p0 + r2); uint2 bC = *(const uint2*)(p1 + r2);
        uint2 aD = *(const uint2*)(p0 + r3); uint2 bD = *(const uint2*)(p1 + r3);
        float2 f;
        f = h2f(aA.x); ax += f.x; ay += f.y;  f = h2f(aA.y); az += f.x; aw += f.y;
        f = h2f(aB.x); ax += f.x; ay += f.y;  f = h2f(aB.y); az += f.x; aw += f.y;
        f = h2f(aC.x); ax += f.x; ay += f.y;  f = h2f(aC.y); az += f.x; aw += f.y;
        f = h2f(aD.x); ax += f.x; ay += f.y;  f = h2f(aD.y); az += f.x; aw += f.y;
        f = h2f(bA.x); bx += f.x; by += f.y;  f = h2f(bA.y); bz += f.x; bw += f.y;
        f = h2f(bB.x); bx += f.x; by += f.y;  f = h2f(bB.y); bz += f.x; bw += f.y;
        f = h2f(bC.x); bx += f.x; by += f.y;  f = h2f(bC.y); bz += f.x; bw += f.y;
        f = h2f(bD.x); bx += f.x; by += f.y;  f = h2f(bD.y); bz += f.x; bw += f.y;
    }
    for (; k < e; ++k) {
        size_t r0 = (size_t)(erec[k].x & 0xFFFF) * HID;
        uint2 aA = *(const uint2*)(p0 + r0); uint2 bA = *(const uint2*)(p1 + r0);
        float2 f;
        f = h2f(aA.x); ax += f.x; ay += f.y;  f = h2f(aA.y); az += f.x; aw += f.y;
        f = h2f(bA.x); bx += f.x; by += f.y;  f = h2f(bA.y); bz += f.x; bw += f.y;
    }
    float nn = in_norm[n];
    float4 rA, rB;
    rA.x = ax * nn; rA.y = ay * nn; rA.z = az * nn; rA.w = aw * nn;
    rB.x = bx * nn; rB.y = by * nn; rB.z = bz * nn; rB.w = bw * nn;
    float* op = out + (size_t)n * HID;
    *(float4*)(op + c * 4) = rA;
    *(float4*)(op + (c + C) * 4) = rB;
}

// ---- linear23 helpers: register double-buffered GEMM stages ----
__device__ __forceinline__ void fma6(float av, const float2* w, float* ac) {
    ac[0] += av * w[0].x; ac[1] += av * w[0].y; ac[2] += av * w[1].x;
    ac[3] += av * w[1].y; ac[4] += av * w[2].x; ac[5] += av * w[2].y;
}
__device__ __forceinline__ void ld_stage1(const float (*in_s)[100], const float* W_s,
                                          int m0, int j0, int K, float4* a, float2* w) {
#pragma unroll
    for (int i = 0; i < 4; ++i) a[i] = *(const float4*)(&in_s[m0 + i][K]);
#pragma unroll
    for (int q = 0; q < 4; ++q) {
        w[q * 3 + 0] = *(const float2*)(&W_s[(K + q) * HID + j0]);
        w[q * 3 + 1] = *(const float2*)(&W_s[(K + q) * HID + j0 + 2]);
        w[q * 3 + 2] = *(const float2*)(&W_s[(K + q) * HID + j0 + 4]);
    }
}
__device__ __forceinline__ void fma_stage1(const float4* a, const float2* w, float ac[4][6]) {
#pragma unroll
    for (int i = 0; i < 4; ++i) {
        fma6(a[i].x, w + 0, ac[i]);
        fma6(a[i].y, w + 3, ac[i]);
        fma6(a[i].z, w + 6, ac[i]);
        fma6(a[i].w, w + 9, ac[i]);
    }
}
__device__ __forceinline__ void fma4(float av, float4 w, float* ac) {
    ac[0] += av * w.x; ac[1] += av * w.y; ac[2] += av * w.z; ac[3] += av * w.w;
}
__device__ __forceinline__ void ld_stage2(const float (*in_s)[100], const float* W_s,
                                          int m0, int j20, int K, float4* a, float4* w) {
#pragma unroll
    for (int i = 0; i < 4; ++i) a[i] = *(const float4*)(&in_s[m0 + i][K]);
#pragma unroll
    for (int q = 0; q < 4; ++q) w[q] = *(const float4*)(&W_s[(K + q) * 64 + j20]);
}
__device__ __forceinline__ void fma_stage2(const float4* a, const float4* w, float ac[4][4]) {
#pragma unroll
    for (int i = 0; i < 4; ++i) {
        fma4(a[i].x, w[0], ac[i]);
        fma4(a[i].y, w[1], ac[i]);
        fma4(a[i].z, w[2], ac[i]);
        fma4(a[i].w, w[3], ac[i]);
    }
}

// Fused layers 2+3. R3: explicit register double-buffering (load-use distance
// = one 96-FMA block); full W2 in LDS (63KB, 2 blocks/CU).
__global__ __launch_bounds__(256) void linear23_kernel(
        const float* __restrict__ agg, const float* __restrict__ W2,
        const float* __restrict__ b2, const float* __restrict__ out_norm,
        const float* __restrict__ W3, __half* __restrict__ t) {
    __shared__ float in_s[64][100];      // 25.6 KB (stride 100: float4 k-loads stay aligned)
    __shared__ float W_s[HID * HID];     // 36.9 KB (phase1: [96][96] W2; phase2: [96][64] W3)
    __shared__ float bs[HID];
    const int tid = threadIdx.x;
    const int n0 = blockIdx.x * 64;

    for (int idx = tid; idx < 64 * (HID / 4); idx += 256) {
        int m = idx / (HID / 4), c = idx - m * (HID / 4);
        int n = n0 + m;
        float4 v = (n < N_NODES) ? *(const float4*)(agg + (size_t)n * HID + c * 4)
                                 : make_float4(0.f, 0.f, 0.f, 0.f);
        *(float4*)(&in_s[m][c * 4]) = v;
    }
    for (int idx = tid; idx < HID * (HID / 4); idx += 256)
        *(float4*)(&W_s[idx * 4]) = *(const float4*)(W2 + idx * 4);
    if (tid < HID) bs[tid] = b2[tid];
    __syncthreads();

    const int tx = tid & 15, ty = tid >> 4;
    const int j0 = tx * 6, m0 = ty * 4;

    // GEMM1: 64x96 @ 96x96, register double-buffered over 4-k stages.
    float acc[4][6];
#pragma unroll
    for (int i = 0; i < 4; ++i)
#pragma unroll
        for (int jj = 0; jj < 6; ++jj) acc[i][jj] = 0.0f;

    float4 aA[4], aB[4];
    float2 wA[12], wB[12];
    ld_stage1(in_s, W_s, m0, j0, 0, aA, wA);
#pragma unroll 2
    for (int k = 0; k < 88; k += 8) {
        ld_stage1(in_s, W_s, m0, j0, k + 4, aB, wB);
        fma_stage1(aA, wA, acc);
        ld_stage1(in_s, W_s, m0, j0, k + 8, aA, wA);
        fma_stage1(aB, wB, acc);
    }
    ld_stage1(in_s, W_s, m0, j0, 92, aB, wB);
    fma_stage1(aA, wA, acc);   // k = 88
    fma_stage1(aB, wB, acc);   // k = 92
    __syncthreads();

    // h2 tile -> in_s (in place); W3 (zero-padded to 64 cols) -> W_s
#pragma unroll
    for (int i = 0; i < 4; ++i) {
        int n = n0 + m0 + i;
        float on = (n < N_NODES) ? out_norm[n] : 0.0f;
#pragma unroll
        for (int jj = 0; jj < 6; ++jj)
            in_s[m0 + i][j0 + jj] = fmaxf(acc[i][jj] + bs[j0 + jj], 0.0f) * on;
    }
    for (int idx = tid; idx < HID * 64; idx += 256) {
        int k = idx >> 6, j = idx & 63;
        W_s[idx] = (j < NLAB) ? W3[k * NLAB + j] : 0.0f;
    }
    __syncthreads();

    // GEMM2: 64x96 @ 96x64 (cols >= 50 zero), register double-buffered.
    const int j20 = tx * 4;
    float acc2[4][4];
#pragma unroll
    for (int i = 0; i < 4; ++i)
#pragma unroll
        for (int jj = 0; jj < 4; ++jj) acc2[i][jj] = 0.0f;

    float4 w2A[4], w2B[4];
    ld_stage2(in_s, W_s, m0, j20, 0, aA, w2A);
#pragma unroll 2
    for (int k = 0; k < 88; k += 8) {
        ld_stage2(in_s, W_s, m0, j20, k + 4, aB, w2B);
        fma_stage2(aA, w2A, acc2);
        ld_stage2(in_s, W_s, m0, j20, k + 8, aA, w2A);
        fma_stage2(aB, w2B, acc2);
    }
    ld_stage2(in_s, W_s, m0, j20, 92, aB, w2B);
    fma_stage2(aA, w2A, acc2);   // k = 88
    fma_stage2(aB, w2B, acc2);   // k = 92

    if (j20 < 4 * TC) {   // tx <= 12: cols 0..51 (52..63 never read)
#pragma unroll
        for (int i = 0; i < 4; ++i) {
            int n = n0 + m0 + i;
            if (n >= N_NODES) break;
            uint2 raw;
            raw.x = f2h(acc2[i][0], acc2[i][1]);
            raw.y = f2h(acc2[i][2], acc2[i][3]);
            *(uint2*)(t + (size_t)n * TSTRIDE + j20) = raw;
        }
    }
}

// Final gather over FP16 t (128B-aligned rows, 1 line each).
__global__ void gather_out_kernel(const __half* __restrict__ t, const int* __restrict__ row_off,
                                  const int* __restrict__ deg, const int2* __restrict__ erec,
                                  const float* __restrict__ in_norm, const float* __restrict__ bias,
                                  float* __restrict__ out) {
    int i = blockIdx.x * blockDim.x + threadIdx.x;
    if (i >= N_NODES * TC) return;
    int n = i / TC;
    int c = i - n * TC;
    const __half* p0 = t + c * 4;
    int k = row_off[n];
    int e = k + deg[n];
    float ax = 0.f, ay = 0.f, az = 0.f, aw = 0.f;
    for (; k + 3 < e; k += 4) {
        size_t r0 = (size_t)(erec[k].x & 0xFFFF) * TSTRIDE;
        size_t r1 = (size_t)(erec[k + 1].x & 0xFFFF) * TSTRIDE;
        size_t r2 = (size_t)(erec[k + 2].x & 0xFFFF) * TSTRIDE;
        size_t r3 = (size_t)(erec[k + 3].x & 0xFFFF) * TSTRIDE;
        uint2 v0 = *(const uint2*)(p0 + r0);
        uint2 v1 = *(const uint2*)(p0 + r1);
        uint2 v2 = *(const uint2*)(p0 + r2);
        uint2 v3 = *(const uint2*)(p0 + r3);
        float2 f;
        f = h2f(v0.x); ax += f.x; ay += f.y;  f = h2f(v0.y); az += f.x; aw += f.y;
        f = h2f(v1.x); ax += f.x; ay += f.y;  f = h2f(v1.y); az += f.x; aw += f.y;
        f = h2f(v2.x); ax += f.x; ay += f.y;  f = h2f(v2.y); az += f.x; aw += f.y;
        f = h2f(v3.x); ax += f.x; ay += f.y;  f = h2f(v3.y); az += f.x; aw += f.y;
    }
    for (; k < e; ++k) {
        size_t r0 = (size_t)(erec[k].x & 0xFFFF) * TSTRIDE;
        uint2 v0 = *(const uint2*)(p0 + r0);
        float2 f;
        f = h2f(v0.x); ax += f.x; ay += f.y;  f = h2f(v0.y); az += f.x; aw += f.y;
    }
    float nn = in_norm[n];
    int j = c * 4;
    float* op = out + (size_t)n * NLAB + j;   // rows 8B-aligned only -> float2 stores
    float2 lo; lo.x = ax * nn + bias[j];     lo.y = ay * nn + bias[j + 1];
    *(float2*)op = lo;
    if (j + 2 < NLAB) {
        float2 hi; hi.x = az * nn + bias[j + 2]; hi.y = aw * nn + bias[j + 3];
        *(float2*)(op + 2) = hi;
    }
}

static inline int cdiv(long a, int b) { return (int)((a + b - 1) / b); }

extern "C" void kernel_launch(void* const* d_in, const int* in_sizes, int n_in,
                              void* d_out, int out_size, void* d_ws, size_t ws_size,
                              hipStream_t stream) {
    const int*   dep_labels = (const int*)d_in[0];
    const int*   src        = (const int*)d_in[1];
    const int*   dst        = (const int*)d_in[2];
    const float* emb        = (const float*)d_in[3];
    const float* W1 = (const float*)d_in[4]; const float* b1 = (const float*)d_in[5];
    const float* W2 = (const float*)d_in[6]; const float* b2 = (const float*)d_in[7];
    const float* W3 = (const float*)d_in[8]; const float* b3 = (const float*)d_in[9];
    float* out = (float*)d_out;

    // ---- workspace layout ----
    int* wsp           = (int*)d_ws;
    int* row_off       = wsp;                 wsp += N_NODES;
    int* deg_in        = wsp;                 wsp += N_NODES;
    int* deg_out_a     = wsp;                 wsp += N_NODES;
    int* bsum          = wsp;                 wsp += 256;
    float* out_norm    = (float*)wsp;         wsp += N_NODES;
    float* in_norm     = (float*)wsp;         wsp += N_NODES;
    int2* node_info    = (int2*)wsp;          wsp += 2 * N_NODES;
    float* T1          = (float*)wsp;         wsp += NLAB * HID + 16;  // pad
    int2* edge_rec     = (int2*)wsp;          wsp += 2 * N_EDGES;      // 6.4 MB
    float* bufA        = (float*)wsp;         wsp += (size_t)N_NODES * HID;   // agg (fp32)
    __half* bufH       = (__half*)wsp;        // h1s (fp16), then t (fp16, stride 64)
    // CSR-build temporaries alias into bufA (dead before gather4x2 writes it):
    int* histd    = (int*)bufA;               // [NBP][256]
    int* hists    = histd + NBP * 256;        // [NBP][256]
    int* blkrel_d = hists + NBP * 256;        // [NBP][256]
    int* blkrel_s = blkrel_d + NBP * 256;     // [NBP][256]
    int* bbase_d  = blkrel_s + NBP * 256;     // [256]
    int* bbase_s  = bbase_d + 256;            // [256]
    int* dstp     = bbase_s + 256;            // [N_EDGES]
    int* srcp     = dstp + N_EDGES;           // [N_EDGES]

    const int B = 256;
    const int NLIN = cdiv(N_NODES, 64);    // 782

    // ---- CSR build: no global atomics anywhere ----
    coarse_hist_kernel<<<NBP + T1B, B, 0, stream>>>(src, dst, histd, hists, emb, W1, T1);
    coarse_scan_kernel<<<2, B, 0, stream>>>(histd, hists, blkrel_d, blkrel_s, bbase_d, bbase_s);
    partition_kernel<<<NBP, B, 0, stream>>>(src, dst, blkrel_d, blkrel_s, bbase_d, bbase_s,
                                            dstp, srcp);
    fine_hist_kernel<<<2 * NBUCK, B, 0, stream>>>(dstp, srcp, bbase_d, bbase_s,
                                                  deg_in, deg_out_a);
    scan1_kernel<<<NB_SCAN, B, 0, stream>>>(deg_in, bsum);
    scan23_kernel<<<NB_SCAN, B, 0, stream>>>(deg_in, bsum, deg_out_a, dep_labels,
                                             row_off, out_norm, in_norm, node_info);
    fine_scatter_kernel<<<NBUCK, B, 0, stream>>>(dstp, bbase_d, row_off, node_info, edge_rec);

    // Layer 1 fused: linear edge_rec stream, T1 L1-resident -> h1s (fp16)
    gather1t_kernel<<<cdiv((long)N_NODES * (HID / 8), B), B, 0, stream>>>(
        edge_rec, T1, row_off, deg_in, in_norm, out_norm, b1, bufH);

    // Layer 2 aggregate (fp16 rows -> fp32 agg)  [clobbers CSR temporaries]
    gather4x2_kernel<<<cdiv((long)N_NODES * (HID / 8), B), B, 0, stream>>>(
        bufH, row_off, deg_in, edge_rec, in_norm, bufA);

    // Layers 2+3 fused transform: agg -> t (fp16 stride 64; h2 stays in LDS)
    linear23_kernel<<<NLIN, 256, 0, stream>>>(bufA, W2, b2, out_norm, W3, bufH);

    // Final gather + bias (fp16 t -> fp32 out)
    gather_out_kernel<<<cdiv((long)N_NODES * TC, B), B, 0, stream>>>(
        bufH, row_off, deg_in, edge_rec, in_norm, b3, out);
}

// Round 5
// 207.179 us; speedup vs baseline: 1.4040x; 1.1485x over previous
//
#include <hip/hip_runtime.h>
#include <hip/hip_fp16.h>

// GCN 3-layer, CSR-gather, low-rank L1 + fused L2/L3 transform.
//   CSR build GLOBAL-ATOMIC-FREE (two-level counting sort, LDS atomics only).
//   L1 fused: h1s(fp16) = relu(in_norm*sum w_e*T1[lbl_e] + b1)*out_norm (linear stream)
//   L2 agg:  aggh(FP16) = in_norm * gather(h1s fp16, 192B rows)
//   L2+L3: R4 rework — fp32 VALU GEMM was stuck at 47us across 3 inner-loop
//     variants (VALUBusy 26% = pure FMA issue arithmetic; compiler defeats
//     source pipelining, VGPR=88 proved dbuf collapsed). Now MFMA
//     16x16x32_f16 (fp32 acc): A=aggh from global (row-major k-contig,
//     m91-verified frag layout), B=pre-transposed W2t/W3t fp16 in LDS
//     (stride 104), h2 via per-wave LDS fp16 (lgkmcnt only, no barrier).
//     392 blocks x 512thr; math ~0.2us machine-wide -> staging-bound.
//   out = in_norm*gather(t fp16) + b3
#define N_NODES 50000
#define N_EDGES 800000
#define EMB     64
#define HID     96
#define NLAB    50
#define NB_SCAN ((N_NODES + 255) / 256)    // 196
#define TSTRIDE 64                         // t row stride (halfs): 128B line-aligned
#define TC      13                         // gather chunks over t (cols 0..51)
#define T1B     ((NLAB * HID + 255) / 256) // 19
#define NBP     256                        // partition blocks
#define EPB     ((N_EDGES + NBP - 1) / NBP)  // 3125 edges per block
#define NBUCK   196                        // node buckets of 256 (covers 50176)
#define WSTRIDE 104                        // W2t/W3t/h2 LDS row stride (halfs)
#define WPREP_N (160 * WSTRIDE)            // 96 W2t rows + 64 W3t rows
#define WPREPB  ((WPREP_N + 255) / 256)    // 65
#define NMFMA   ((N_NODES + 127) / 128)    // 392 blocks of 128 nodes

typedef _Float16 f16x8 __attribute__((ext_vector_type(8)));
typedef float f32x4 __attribute__((ext_vector_type(4)));

__device__ __forceinline__ float2 h2f(unsigned u) {
    __half2 h = *reinterpret_cast<__half2*>(&u);
    return __half22float2(h);
}
__device__ __forceinline__ unsigned f2h(float a, float b) {
    __half2 h = __floats2half2_rn(a, b);
    return *reinterpret_cast<unsigned*>(&h);
}

// Per-block coarse histograms (dst>>8, src>>8) via LDS atomics. Tail blocks:
// T1 = emb@W1, then W2t/W3t fp16 transpose-prep.
__global__ void coarse_hist_kernel(const int* __restrict__ src, const int* __restrict__ dst,
                                   int* __restrict__ histd, int* __restrict__ hists,
                                   const float* __restrict__ emb, const float* __restrict__ W1,
                                   float* __restrict__ T1,
                                   const float* __restrict__ W2, const float* __restrict__ W3,
                                   __half* __restrict__ wprep) {
    int b = blockIdx.x, t = threadIdx.x;
    if (b < NBP) {
        __shared__ int hd[256], hs[256];
        hd[t] = 0; hs[t] = 0;
        __syncthreads();
        int hi = min(b * EPB + EPB, N_EDGES);
        for (int i = b * EPB + t; i < hi; i += 256) {
            atomicAdd(&hd[((unsigned)dst[i]) >> 8], 1);
            atomicAdd(&hs[((unsigned)src[i]) >> 8], 1);
        }
        __syncthreads();
        histd[b * 256 + t] = hd[t];
        hists[b * 256 + t] = hs[t];
    } else if (b < NBP + T1B) {
        int i = (b - NBP) * 256 + t;
        if (i < NLAB * HID) {
            int l = i / HID, j = i - l * HID;
            float sum = 0.0f;
#pragma unroll
            for (int k = 0; k < EMB; ++k) sum += emb[l * EMB + k] * W1[k * HID + j];
            T1[i] = sum;
        }
    } else {
        // wprep[0..96): W2t rows (j over HID); wprep[96..160): W3t rows (j over 64)
        int i = (b - NBP - T1B) * 256 + t;
        if (i < WPREP_N) {
            int j = i / WSTRIDE, kk = i - j * WSTRIDE;
            float v = 0.0f;
            if (kk < HID) {
                if (j < HID) v = W2[kk * HID + j];
                else { int jj = j - HID; if (jj < NLAB) v = W3[kk * NLAB + jj]; }
            }
            wprep[i] = __float2half(v);
        }
    }
}

// Block 0: dst side; block 1: src side. Thread t owns bucket t.
__global__ void coarse_scan_kernel(const int* __restrict__ histd, const int* __restrict__ hists,
                                   int* __restrict__ blkrel_d, int* __restrict__ blkrel_s,
                                   int* __restrict__ bbase_d, int* __restrict__ bbase_s) {
    __shared__ int sh[256];
    int t = threadIdx.x;
    const int* hist = blockIdx.x ? hists : histd;
    int* blkrel     = blockIdx.x ? blkrel_s : blkrel_d;
    int* bbase      = blockIdx.x ? bbase_s : bbase_d;
    int run = 0;
#pragma unroll 16
    for (int b = 0; b < NBP; ++b) {
        blkrel[b * 256 + t] = run;
        run += hist[b * 256 + t];
    }
    sh[t] = run;
    __syncthreads();
    for (int off = 1; off < 256; off <<= 1) {
        int v = sh[t];
        if (t >= off) v += sh[t - off];
        __syncthreads();
        sh[t] = v;
        __syncthreads();
    }
    bbase[t] = sh[t] - run;   // exclusive bucket base
}

// Scatter edges into bucket-partitioned arrays via LDS cursors (no global RMW).
__global__ void partition_kernel(const int* __restrict__ src, const int* __restrict__ dst,
                                 const int* __restrict__ blkrel_d, const int* __restrict__ blkrel_s,
                                 const int* __restrict__ bbase_d, const int* __restrict__ bbase_s,
                                 int* __restrict__ dstp, int* __restrict__ srcp) {
    __shared__ int curd[256], curs[256];
    int b = blockIdx.x, t = threadIdx.x;
    curd[t] = bbase_d[t] + blkrel_d[b * 256 + t];
    curs[t] = bbase_s[t] + blkrel_s[b * 256 + t];
    __syncthreads();
    int hi = min(b * EPB + EPB, N_EDGES);
    for (int i = b * EPB + t; i < hi; i += 256) {
        int d = dst[i], s = src[i];
        int pd = atomicAdd(&curd[((unsigned)d) >> 8], 1);
        dstp[pd] = s | ((d & 0xFF) << 16);
        int ps = atomicAdd(&curs[((unsigned)s) >> 8], 1);
        srcp[ps] = s & 0xFF;
    }
}

// Per-bucket fine histogram -> degree arrays (plain stores, no atomics).
__global__ void fine_hist_kernel(const int* __restrict__ dstp, const int* __restrict__ srcp,
                                 const int* __restrict__ bbase_d, const int* __restrict__ bbase_s,
                                 int* __restrict__ deg_in, int* __restrict__ deg_out) {
    __shared__ int cnt[256];
    int b = blockIdx.x, t = threadIdx.x;
    cnt[t] = 0;
    __syncthreads();
    if (b < NBUCK) {
        int lo = bbase_d[b], hi = bbase_d[b + 1];
        for (int i = lo + t; i < hi; i += 256)
            atomicAdd(&cnt[(dstp[i] >> 16) & 0xFF], 1);
        __syncthreads();
        int node = b * 256 + t;
        if (node < N_NODES) deg_in[node] = cnt[t];
    } else {
        int bb = b - NBUCK;
        int lo = bbase_s[bb], hi = bbase_s[bb + 1];
        for (int i = lo + t; i < hi; i += 256)
            atomicAdd(&cnt[srcp[i]], 1);
        __syncthreads();
        int node = bb * 256 + t;
        if (node < N_NODES) deg_out[node] = cnt[t];
    }
}

// --- block sums of deg_in ---
__global__ void scan1_kernel(const int* __restrict__ deg, int* __restrict__ bsum) {
    __shared__ int s[256];
    int t = threadIdx.x, i = blockIdx.x * 256 + t;
    s[t] = (i < N_NODES) ? deg[i] : 0;
    for (int off = 128; off > 0; off >>= 1) {
        __syncthreads();
        if (t < off) s[t] += s[t + off];
    }
    if (t == 0) bsum[blockIdx.x] = s[0];
}

// Merged scan2+scan3.
__global__ void scan23_kernel(const int* __restrict__ deg_in, const int* __restrict__ bsum,
                              const int* __restrict__ deg_out, const int* __restrict__ labels,
                              int* __restrict__ row_off,
                              float* __restrict__ out_norm, float* __restrict__ in_norm,
                              int2* __restrict__ node_info) {
    __shared__ int pb[256];
    __shared__ int s[256];
    int t = threadIdx.x, i = blockIdx.x * 256 + t;
    pb[t] = (t < (int)blockIdx.x) ? bsum[t] : 0;
    int own = (i < N_NODES) ? deg_in[i] : 0;
    s[t] = own;
    __syncthreads();
    for (int off = 128; off > 0; off >>= 1) {
        if (t < off) pb[t] += pb[t + off];
        __syncthreads();
    }
    int base = pb[0];
    for (int off = 1; off < 256; off <<= 1) {
        int v = s[t];
        if (t >= off) v += s[t - off];
        __syncthreads();
        s[t] = v;
        __syncthreads();
    }
    if (i < N_NODES) {
        row_off[i] = base + s[t] - own;
        float on = rsqrtf(fmaxf((float)deg_out[i], 1.0f));
        out_norm[i] = on;
        in_norm[i]  = rsqrtf(fmaxf((float)own, 1.0f));
        node_info[i] = make_int2(labels[i] << 16, __float_as_int(on));
    }
}

// One block per dst-bucket: LDS per-node rank cursors -> final edge_rec write.
__global__ void fine_scatter_kernel(const int* __restrict__ dstp, const int* __restrict__ bbase_d,
                                    const int* __restrict__ row_off,
                                    const int2* __restrict__ node_info,
                                    int2* __restrict__ edge_rec) {
    __shared__ int cur[256];
    __shared__ int ro[256];
    int b = blockIdx.x, t = threadIdx.x;
    int node = b * 256 + t;
    ro[t] = (node < N_NODES) ? row_off[node] : 0;
    cur[t] = 0;
    __syncthreads();
    int lo = bbase_d[b], hi = bbase_d[b + 1];
    for (int i = lo + t; i < hi; i += 256) {
        int rec = dstp[i];
        int s = rec & 0xFFFF;
        int nl = (rec >> 16) & 0xFF;
        int r = atomicAdd(&cur[nl], 1);
        int2 ni = node_info[s];
        edge_rec[ro[nl] + r] = make_int2(s | ni.x, ni.y);
    }
}

// Fused layer 1: 2 float4 chunks per thread, unroll-4 edges; edge_rec read linearly.
__global__ void gather1t_kernel(const int2* __restrict__ edge_rec, const float* __restrict__ T1,
                                const int* __restrict__ row_off, const int* __restrict__ deg,
                                const float* __restrict__ in_norm,
                                const float* __restrict__ out_norm, const float* __restrict__ b1,
                                __half* __restrict__ h1s) {
    constexpr int C = HID / 8;   // 12 chunk-pairs per node
    int i = blockIdx.x * blockDim.x + threadIdx.x;
    if (i >= N_NODES * C) return;
    int n = i / C;
    int c = i - n * C;
    const float* t1a = T1 + c * 4;
    const float* t1b = T1 + (c + C) * 4;
    int k = row_off[n];
    int e = k + deg[n];
    float ax = 0.f, ay = 0.f, az = 0.f, aw = 0.f;
    float bx = 0.f, by = 0.f, bz = 0.f, bw = 0.f;
    for (; k + 3 < e; k += 4) {
        int2 i0 = edge_rec[k];
        int2 i1 = edge_rec[k + 1];
        int2 i2 = edge_rec[k + 2];
        int2 i3 = edge_rec[k + 3];
        int r0 = ((unsigned)i0.x >> 16) * HID, r1 = ((unsigned)i1.x >> 16) * HID;
        int r2 = ((unsigned)i2.x >> 16) * HID, r3 = ((unsigned)i3.x >> 16) * HID;
        float4 aA = *(const float4*)(t1a + r0); float4 bA = *(const float4*)(t1b + r0);
        float4 aB = *(const float4*)(t1a + r1); float4 bB = *(const float4*)(t1b + r1);
        float4 aC = *(const float4*)(t1a + r2); float4 bC = *(const float4*)(t1b + r2);
        float4 aD = *(const float4*)(t1a + r3); float4 bD = *(const float4*)(t1b + r3);
        float w0 = __int_as_float(i0.y), w1 = __int_as_float(i1.y);
        float w2 = __int_as_float(i2.y), w3 = __int_as_float(i3.y);
        ax += aA.x * w0 + aB.x * w1 + aC.x * w2 + aD.x * w3;
        ay += aA.y * w0 + aB.y * w1 + aC.y * w2 + aD.y * w3;
        az += aA.z * w0 + aB.z * w1 + aC.z * w2 + aD.z * w3;
        aw += aA.w * w0 + aB.w * w1 + aC.w * w2 + aD.w * w3;
        bx += bA.x * w0 + bB.x * w1 + bC.x * w2 + bD.x * w3;
        by += bA.y * w0 + bB.y * w1 + bC.y * w2 + bD.y * w3;
        bz += bA.z * w0 + bB.z * w1 + bC.z * w2 + bD.z * w3;
        bw += bA.w * w0 + bB.w * w1 + bC.w * w2 + bD.w * w3;
    }
    for (; k < e; ++k) {
        int2 i0 = edge_rec[k];
        int r0 = ((unsigned)i0.x >> 16) * HID;
        float4 aA = *(const float4*)(t1a + r0); float4 bA = *(const float4*)(t1b + r0);
        float w0 = __int_as_float(i0.y);
        ax += aA.x * w0; ay += aA.y * w0; az += aA.z * w0; aw += aA.w * w0;
        bx += bA.x * w0; by += bA.y * w0; bz += bA.z * w0; bw += bA.w * w0;
    }
    float nn = in_norm[n];
    float on = out_norm[n];
    float4 b1a = *(const float4*)(b1 + c * 4);
    float4 b1b = *(const float4*)(b1 + (c + C) * 4);
    uint2 rA, rB;
    rA.x = f2h(fmaxf(ax * nn + b1a.x, 0.f) * on, fmaxf(ay * nn + b1a.y, 0.f) * on);
    rA.y = f2h(fmaxf(az * nn + b1a.z, 0.f) * on, fmaxf(aw * nn + b1a.w, 0.f) * on);
    rB.x = f2h(fmaxf(bx * nn + b1b.x, 0.f) * on, fmaxf(by * nn + b1b.y, 0.f) * on);
    rB.y = f2h(fmaxf(bz * nn + b1b.z, 0.f) * on, fmaxf(bw * nn + b1b.w, 0.f) * on);
    __half* op = h1s + (size_t)n * HID;
    *(uint2*)(op + c * 4) = rA;
    *(uint2*)(op + (c + C) * 4) = rB;
}

// Layer-2 aggregate from FP16 rows -> FP16 agg (halves write traffic; feeds MFMA).
__global__ void gather4x2_kernel(const __half* __restrict__ hs, const int* __restrict__ row_off,
                                 const int* __restrict__ deg, const int2* __restrict__ erec,
                                 const float* __restrict__ in_norm, __half* __restrict__ aggh) {
    constexpr int C = HID / 8;   // 12
    int i = blockIdx.x * blockDim.x + threadIdx.x;
    if (i >= N_NODES * C) return;
    int n = i / C;
    int c = i - n * C;
    const __half* p0 = hs + c * 4;
    const __half* p1 = hs + (c + C) * 4;
    int k = row_off[n];
    int e = k + deg[n];
    float ax = 0.f, ay = 0.f, az = 0.f, aw = 0.f;
    float bx = 0.f, by = 0.f, bz = 0.f, bw = 0.f;
    for (; k + 3 < e; k += 4) {
        size_t r0 = (size_t)(erec[k].x & 0xFFFF) * HID;
        size_t r1 = (size_t)(erec[k + 1].x & 0xFFFF) * HID;
        size_t r2 = (size_t)(erec[k + 2].x & 0xFFFF) * HID;
        size_t r3 = (size_t)(erec[k + 3].x & 0xFFFF) * HID;
        uint2 aA = *(const uint2*)(p0 + r0); uint2 bA = *(const uint2*)(p1 + r0);
        uint2 aB = *(const uint2*)(p0 + r1); uint2 bB = *(const uint2*)(p1 + r1);
        uint2 aC = *(const uint2*)(p0 + r2); uint2 bC = *(const uint2*)(p1 + r2);
        uint2 aD = *(const uint2*)(p0 + r3); uint2 bD = *(const uint2*)(p1 + r3);
        float2 f;
        f = h2f(aA.x); ax += f.x; ay += f.y;  f = h2f(aA.y); az += f.x; aw += f.y;
        f = h2f(aB.x); ax += f.x; ay += f.y;  f = h2f(aB.y); az += f.x; aw += f.y;
        f = h2f(aC.x); ax += f.x; ay += f.y;  f = h2f(aC.y); az += f.x; aw += f.y;
        f = h2f(aD.x); ax += f.x; ay += f.y;  f = h2f(aD.y); az += f.x; aw += f.y;
        f = h2f(bA.x); bx += f.x; by += f.y;  f = h2f(bA.y); bz += f.x; bw += f.y;
        f = h2f(bB.x); bx += f.x; by += f.y;  f = h2f(bB.y); bz += f.x; bw += f.y;
        f = h2f(bC.x); bx += f.x; by += f.y;  f = h2f(bC.y); bz += f.x; bw += f.y;
        f = h2f(bD.x); bx += f.x; by += f.y;  f = h2f(bD.y); bz += f.x; bw += f.y;
    }
    for (; k < e; ++k) {
        size_t r0 = (size_t)(erec[k].x & 0xFFFF) * HID;
        uint2 aA = *(const uint2*)(p0 + r0); uint2 bA = *(const uint2*)(p1 + r0);
        float2 f;
        f = h2f(aA.x); ax += f.x; ay += f.y;  f = h2f(aA.y); az += f.x; aw += f.y;
        f = h2f(bA.x); bx += f.x; by += f.y;  f = h2f(bA.y); bz += f.x; bw += f.y;
    }
    float nn = in_norm[n];
    uint2 rA, rB;
    rA.x = f2h(ax * nn, ay * nn); rA.y = f2h(az * nn, aw * nn);
    rB.x = f2h(bx * nn, by * nn); rB.y = f2h(bz * nn, bw * nn);
    __half* op = aggh + (size_t)n * HID;
    *(uint2*)(op + c * 4) = rA;
    *(uint2*)(op + (c + C) * 4) = rB;
}

// Fused layers 2+3 via MFMA 16x16x32_f16 (fp32 acc). 128 nodes/block, 8 waves
// x 16-node M-tiles. A-frag: lane holds row=lane&15, k=(lane>>4)*8+i (m91
// convention); D: col=lane&15, row=(lane>>4)*4+reg (m89-verified).
__global__ __launch_bounds__(512) void linear23_mfma_kernel(
        const __half* __restrict__ aggh, const __half* __restrict__ wprep,
        const float* __restrict__ b2, const float* __restrict__ out_norm,
        __half* __restrict__ t) {
    __shared__ _Float16 Wl[WPREP_N];         // W2t [96][104] then W3t [64][104]: 32.5 KB
    __shared__ _Float16 h2l[8][16][WSTRIDE]; // per-wave h2 tiles: 26 KB
    const int tid = threadIdx.x;
    {   // stage W2t+W3t (33280 B, linear uint4 copy)
        const uint4* sp = (const uint4*)wprep;
        uint4* dp = (uint4*)Wl;
        for (int i = tid; i < WPREP_N / 8; i += 512) dp[i] = sp[i];
    }
    __syncthreads();
    const int w = tid >> 6, l = tid & 63;
    const int lr = l & 15, lg = l >> 4;
    const int n0 = blockIdx.x * 128 + w * 16;

    // ---- GEMM1: h2 = relu(aggh @ W2 + b2) * out_norm ----
    f16x8 a[3];
    {
        int n = n0 + lr; if (n > N_NODES - 1) n = N_NODES - 1;
        const __half* ap = aggh + (size_t)n * HID + lg * 8;
#pragma unroll
        for (int kb = 0; kb < 3; ++kb) a[kb] = *(const f16x8*)(ap + kb * 32);
    }
    f32x4 acc[6];
#pragma unroll
    for (int nt = 0; nt < 6; ++nt) {
        acc[nt] = (f32x4){0.f, 0.f, 0.f, 0.f};
#pragma unroll
        for (int kb = 0; kb < 3; ++kb) {
            f16x8 bfr = *(const f16x8*)(&Wl[(nt * 16 + lr) * WSTRIDE + kb * 32 + lg * 8]);
            acc[nt] = __builtin_amdgcn_mfma_f32_16x16x32_f16(a[kb], bfr, acc[nt], 0, 0, 0);
        }
    }
    float on4[4];
#pragma unroll
    for (int r = 0; r < 4; ++r) {
        int n = n0 + lg * 4 + r; if (n > N_NODES - 1) n = N_NODES - 1;
        on4[r] = out_norm[n];
    }
#pragma unroll
    for (int nt = 0; nt < 6; ++nt) {
        int col = nt * 16 + lr;
        float bb = b2[col];
#pragma unroll
        for (int r = 0; r < 4; ++r) {
            float v = fmaxf(acc[nt][r] + bb, 0.f) * on4[r];
            h2l[w][lg * 4 + r][col] = (_Float16)v;
        }
    }
    // same-wave LDS write->read ordering (no cross-wave sharing: no barrier)
    asm volatile("s_waitcnt lgkmcnt(0)" ::: "memory");

    // ---- GEMM2: t = h2 @ W3 (cols 0..51), store fp16 stride 64 ----
    f16x8 a2[3];
#pragma unroll
    for (int kb = 0; kb < 3; ++kb)
        a2[kb] = *(const f16x8*)(&h2l[w][lr][kb * 32 + lg * 8]);
#pragma unroll
    for (int nt = 0; nt < 4; ++nt) {
        f32x4 acc2 = (f32x4){0.f, 0.f, 0.f, 0.f};
#pragma unroll
        for (int kb = 0; kb < 3; ++kb) {
            f16x8 bfr = *(const f16x8*)(&Wl[(HID + nt * 16 + lr) * WSTRIDE + kb * 32 + lg * 8]);
            acc2 = __builtin_amdgcn_mfma_f32_16x16x32_f16(a2[kb], bfr, acc2, 0, 0, 0);
        }
        int col = nt * 16 + lr;
        if (col < 4 * TC) {
#pragma unroll
            for (int r = 0; r < 4; ++r) {
                int n = n0 + lg * 4 + r;
                if (n < N_NODES) t[(size_t)n * TSTRIDE + col] = __float2half(acc2[r]);
            }
        }
    }
}

// Final gather over FP16 t (128B-aligned rows, 1 line each).
__global__ void gather_out_kernel(const __half* __restrict__ t, const int* __restrict__ row_off,
                                  const int* __restrict__ deg, const int2* __restrict__ erec,
                                  const float* __restrict__ in_norm, const float* __restrict__ bias,
                                  float* __restrict__ out) {
    int i = blockIdx.x * blockDim.x + threadIdx.x;
    if (i >= N_NODES * TC) return;
    int n = i / TC;
    int c = i - n * TC;
    const __half* p0 = t + c * 4;
    int k = row_off[n];
    int e = k + deg[n];
    float ax = 0.f, ay = 0.f, az = 0.f, aw = 0.f;
    for (; k + 3 < e; k += 4) {
        size_t r0 = (size_t)(erec[k].x & 0xFFFF) * TSTRIDE;
        size_t r1 = (size_t)(erec[k + 1].x & 0xFFFF) * TSTRIDE;
        size_t r2 = (size_t)(erec[k + 2].x & 0xFFFF) * TSTRIDE;
        size_t r3 = (size_t)(erec[k + 3].x & 0xFFFF) * TSTRIDE;
        uint2 v0 = *(const uint2*)(p0 + r0);
        uint2 v1 = *(const uint2*)(p0 + r1);
        uint2 v2 = *(const uint2*)(p0 + r2);
        uint2 v3 = *(const uint2*)(p0 + r3);
        float2 f;
        f = h2f(v0.x); ax += f.x; ay += f.y;  f = h2f(v0.y); az += f.x; aw += f.y;
        f = h2f(v1.x); ax += f.x; ay += f.y;  f = h2f(v1.y); az += f.x; aw += f.y;
        f = h2f(v2.x); ax += f.x; ay += f.y;  f = h2f(v2.y); az += f.x; aw += f.y;
        f = h2f(v3.x); ax += f.x; ay += f.y;  f = h2f(v3.y); az += f.x; aw += f.y;
    }
    for (; k < e; ++k) {
        size_t r0 = (size_t)(erec[k].x & 0xFFFF) * TSTRIDE;
        uint2 v0 = *(const uint2*)(p0 + r0);
        float2 f;
        f = h2f(v0.x); ax += f.x; ay += f.y;  f = h2f(v0.y); az += f.x; aw += f.y;
    }
    float nn = in_norm[n];
    int j = c * 4;
    float* op = out + (size_t)n * NLAB + j;   // rows 8B-aligned only -> float2 stores
    float2 lo; lo.x = ax * nn + bias[j];     lo.y = ay * nn + bias[j + 1];
    *(float2*)op = lo;
    if (j + 2 < NLAB) {
        float2 hi; hi.x = az * nn + bias[j + 2]; hi.y = aw * nn + bias[j + 3];
        *(float2*)(op + 2) = hi;
    }
}

static inline int cdiv(long a, int b) { return (int)((a + b - 1) / b); }

extern "C" void kernel_launch(void* const* d_in, const int* in_sizes, int n_in,
                              void* d_out, int out_size, void* d_ws, size_t ws_size,
                              hipStream_t stream) {
    const int*   dep_labels = (const int*)d_in[0];
    const int*   src        = (const int*)d_in[1];
    const int*   dst        = (const int*)d_in[2];
    const float* emb        = (const float*)d_in[3];
    const float* W1 = (const float*)d_in[4]; const float* b1 = (const float*)d_in[5];
    const float* W2 = (const float*)d_in[6]; const float* b2 = (const float*)d_in[7];
    const float* W3 = (const float*)d_in[8]; const float* b3 = (const float*)d_in[9];
    float* out = (float*)d_out;

    // ---- workspace layout (all regions multiple-of-4 ints -> 16B aligned) ----
    int* wsp           = (int*)d_ws;
    int* row_off       = wsp;                 wsp += N_NODES;
    int* deg_in        = wsp;                 wsp += N_NODES;
    int* deg_out_a     = wsp;                 wsp += N_NODES;
    int* bsum          = wsp;                 wsp += 256;
    float* out_norm    = (float*)wsp;         wsp += N_NODES;
    float* in_norm     = (float*)wsp;         wsp += N_NODES;
    int2* node_info    = (int2*)wsp;          wsp += 2 * N_NODES;
    float* T1          = (float*)wsp;         wsp += NLAB * HID + 16;  // 4816
    __half* wprep      = (__half*)wsp;        wsp += WPREP_N / 2;      // 16640 halfs
    int2* edge_rec     = (int2*)wsp;          wsp += 2 * N_EDGES;      // 6.4 MB
    int* bufA          = wsp;                 wsp += (size_t)N_NODES * HID;   // 19.2 MB
    __half* bufH       = (__half*)wsp;        // h1s (fp16), then t (fp16, stride 64)
    __half* aggh       = (__half*)bufA;       // fp16 agg (9.6 MB, first half of bufA)
    // CSR-build temporaries alias into bufA (dead before gather4x2 writes aggh):
    int* histd    = bufA;                     // [NBP][256]
    int* hists    = histd + NBP * 256;
    int* blkrel_d = hists + NBP * 256;
    int* blkrel_s = blkrel_d + NBP * 256;
    int* bbase_d  = blkrel_s + NBP * 256;     // [256]
    int* bbase_s  = bbase_d + 256;            // [256]
    int* dstp     = bbase_s + 256;            // [N_EDGES]
    int* srcp     = dstp + N_EDGES;           // [N_EDGES]

    const int B = 256;

    // ---- CSR build: no global atomics anywhere ----
    coarse_hist_kernel<<<NBP + T1B + WPREPB, B, 0, stream>>>(src, dst, histd, hists,
                                                             emb, W1, T1, W2, W3, wprep);
    coarse_scan_kernel<<<2, B, 0, stream>>>(histd, hists, blkrel_d, blkrel_s, bbase_d, bbase_s);
    partition_kernel<<<NBP, B, 0, stream>>>(src, dst, blkrel_d, blkrel_s, bbase_d, bbase_s,
                                            dstp, srcp);
    fine_hist_kernel<<<2 * NBUCK, B, 0, stream>>>(dstp, srcp, bbase_d, bbase_s,
                                                  deg_in, deg_out_a);
    scan1_kernel<<<NB_SCAN, B, 0, stream>>>(deg_in, bsum);
    scan23_kernel<<<NB_SCAN, B, 0, stream>>>(deg_in, bsum, deg_out_a, dep_labels,
                                             row_off, out_norm, in_norm, node_info);
    fine_scatter_kernel<<<NBUCK, B, 0, stream>>>(dstp, bbase_d, row_off, node_info, edge_rec);

    // Layer 1 fused: linear edge_rec stream, T1 L1-resident -> h1s (fp16)
    gather1t_kernel<<<cdiv((long)N_NODES * (HID / 8), B), B, 0, stream>>>(
        edge_rec, T1, row_off, deg_in, in_norm, out_norm, b1, bufH);

    // Layer 2 aggregate (fp16 rows -> fp16 aggh)  [clobbers CSR temporaries]
    gather4x2_kernel<<<cdiv((long)N_NODES * (HID / 8), B), B, 0, stream>>>(
        bufH, row_off, deg_in, edge_rec, in_norm, aggh);

    // Layers 2+3 fused transform via MFMA: aggh -> t (fp16 stride 64)
    linear23_mfma_kernel<<<NMFMA, 512, 0, stream>>>(aggh, wprep, b2, out_norm, bufH);

    // Final gather + bias (fp16 t -> fp32 out)
    gather_out_kernel<<<cdiv((long)N_NODES * TC, B), B, 0, stream>>>(
        bufH, row_off, deg_in, edge_rec, in_norm, b3, out);
}

// Round 6
// 204.405 us; speedup vs baseline: 1.4231x; 1.0136x over previous
//
#include <hip/hip_runtime.h>
#include <hip/hip_fp16.h>

// GCN 3-layer, CSR-gather, low-rank L1 + fused L2/L3 transform.
//   CSR build GLOBAL-ATOMIC-FREE (two-level counting sort, LDS atomics only).
//   R5: gather4x2 + linear23 fused (agg -> LDS fp16, MFMA reads LDS, h2
//     in-place per-wave) -> aggh 19.2MB round-trip removed; srcp packed to
//     bytes; scan1 merged into fine_hist (dst-buckets emit bsum directly).
//   L1 fused: h1s(fp16) = relu(in_norm*sum w_e*T1[lbl_e] + b1)*out_norm (linear stream)
//   L2+L3: MFMA 16x16x32_f16 (fp32 acc), W2t/W3t fp16 LDS stride 104,
//     t = h2@W3 stored FP16 row stride 64 halfs.
//   out = in_norm*gather(t fp16) + b3
#define N_NODES 50000
#define N_EDGES 800000
#define EMB     64
#define HID     96
#define NLAB    50
#define NB_SCAN ((N_NODES + 255) / 256)    // 196
#define TSTRIDE 64                         // t row stride (halfs): 128B line-aligned
#define TC      13                         // gather chunks over t (cols 0..51)
#define T1B     ((NLAB * HID + 255) / 256) // 19
#define NBP     256                        // partition blocks
#define EPB     ((N_EDGES + NBP - 1) / NBP)  // 3125 edges per block
#define NBUCK   196                        // node buckets of 256 (covers 50176)
#define WSTRIDE 104                        // W2t/W3t/A LDS row stride (halfs)
#define WPREP_N (160 * WSTRIDE)            // 96 W2t rows + 64 W3t rows
#define WPREPB  ((WPREP_N + 255) / 256)    // 65
#define NMFMA   ((N_NODES + 127) / 128)    // 392 blocks of 128 nodes

typedef _Float16 f16x8 __attribute__((ext_vector_type(8)));
typedef float f32x4 __attribute__((ext_vector_type(4)));

__device__ __forceinline__ float2 h2f(unsigned u) {
    __half2 h = *reinterpret_cast<__half2*>(&u);
    return __half22float2(h);
}
__device__ __forceinline__ unsigned f2h(float a, float b) {
    __half2 h = __floats2half2_rn(a, b);
    return *reinterpret_cast<unsigned*>(&h);
}

// Per-block coarse histograms (dst>>8, src>>8) via LDS atomics. Tail blocks:
// T1 = emb@W1, then W2t/W3t fp16 transpose-prep.
__global__ void coarse_hist_kernel(const int* __restrict__ src, const int* __restrict__ dst,
                                   int* __restrict__ histd, int* __restrict__ hists,
                                   const float* __restrict__ emb, const float* __restrict__ W1,
                                   float* __restrict__ T1,
                                   const float* __restrict__ W2, const float* __restrict__ W3,
                                   __half* __restrict__ wprep) {
    int b = blockIdx.x, t = threadIdx.x;
    if (b < NBP) {
        __shared__ int hd[256], hs[256];
        hd[t] = 0; hs[t] = 0;
        __syncthreads();
        int hi = min(b * EPB + EPB, N_EDGES);
        for (int i = b * EPB + t; i < hi; i += 256) {
            atomicAdd(&hd[((unsigned)dst[i]) >> 8], 1);
            atomicAdd(&hs[((unsigned)src[i]) >> 8], 1);
        }
        __syncthreads();
        histd[b * 256 + t] = hd[t];
        hists[b * 256 + t] = hs[t];
    } else if (b < NBP + T1B) {
        int i = (b - NBP) * 256 + t;
        if (i < NLAB * HID) {
            int l = i / HID, j = i - l * HID;
            float sum = 0.0f;
#pragma unroll
            for (int k = 0; k < EMB; ++k) sum += emb[l * EMB + k] * W1[k * HID + j];
            T1[i] = sum;
        }
    } else {
        // wprep[0..96): W2t rows (j over HID); wprep[96..160): W3t rows (j over 64)
        int i = (b - NBP - T1B) * 256 + t;
        if (i < WPREP_N) {
            int j = i / WSTRIDE, kk = i - j * WSTRIDE;
            float v = 0.0f;
            if (kk < HID) {
                if (j < HID) v = W2[kk * HID + j];
                else { int jj = j - HID; if (jj < NLAB) v = W3[kk * NLAB + jj]; }
            }
            wprep[i] = __float2half(v);
        }
    }
}

// Block 0: dst side; block 1: src side. Thread t owns bucket t.
__global__ void coarse_scan_kernel(const int* __restrict__ histd, const int* __restrict__ hists,
                                   int* __restrict__ blkrel_d, int* __restrict__ blkrel_s,
                                   int* __restrict__ bbase_d, int* __restrict__ bbase_s) {
    __shared__ int sh[256];
    int t = threadIdx.x;
    const int* hist = blockIdx.x ? hists : histd;
    int* blkrel     = blockIdx.x ? blkrel_s : blkrel_d;
    int* bbase      = blockIdx.x ? bbase_s : bbase_d;
    int run = 0;
#pragma unroll 16
    for (int b = 0; b < NBP; ++b) {
        blkrel[b * 256 + t] = run;
        run += hist[b * 256 + t];
    }
    sh[t] = run;
    __syncthreads();
    for (int off = 1; off < 256; off <<= 1) {
        int v = sh[t];
        if (t >= off) v += sh[t - off];
        __syncthreads();
        sh[t] = v;
        __syncthreads();
    }
    bbase[t] = sh[t] - run;   // exclusive bucket base
}

// Scatter edges into bucket-partitioned arrays via LDS cursors (no global RMW).
// dstp rec = src | (dst&255)<<16 ; srcp rec = (byte) src&255.
__global__ void partition_kernel(const int* __restrict__ src, const int* __restrict__ dst,
                                 const int* __restrict__ blkrel_d, const int* __restrict__ blkrel_s,
                                 const int* __restrict__ bbase_d, const int* __restrict__ bbase_s,
                                 int* __restrict__ dstp, unsigned char* __restrict__ srcp) {
    __shared__ int curd[256], curs[256];
    int b = blockIdx.x, t = threadIdx.x;
    curd[t] = bbase_d[t] + blkrel_d[b * 256 + t];
    curs[t] = bbase_s[t] + blkrel_s[b * 256 + t];
    __syncthreads();
    int hi = min(b * EPB + EPB, N_EDGES);
    for (int i = b * EPB + t; i < hi; i += 256) {
        int d = dst[i], s = src[i];
        int pd = atomicAdd(&curd[((unsigned)d) >> 8], 1);
        dstp[pd] = s | ((d & 0xFF) << 16);
        int ps = atomicAdd(&curs[((unsigned)s) >> 8], 1);
        srcp[ps] = (unsigned char)(s & 0xFF);
    }
}

// Per-bucket fine histogram -> degree arrays (plain stores, no atomics).
// Dst-buckets also tree-reduce their counts -> bsum[b] (scan1 merged here).
__global__ void fine_hist_kernel(const int* __restrict__ dstp, const unsigned char* __restrict__ srcp,
                                 const int* __restrict__ bbase_d, const int* __restrict__ bbase_s,
                                 int* __restrict__ deg_in, int* __restrict__ deg_out,
                                 int* __restrict__ bsum) {
    __shared__ int cnt[256];
    int b = blockIdx.x, t = threadIdx.x;
    cnt[t] = 0;
    __syncthreads();
    if (b < NBUCK) {
        int lo = bbase_d[b], hi = bbase_d[b + 1];
        for (int i = lo + t; i < hi; i += 256)
            atomicAdd(&cnt[(dstp[i] >> 16) & 0xFF], 1);
        __syncthreads();
        int node = b * 256 + t;
        if (node < N_NODES) deg_in[node] = cnt[t];
        // tree-reduce cnt -> bsum[b]
        for (int off = 128; off > 0; off >>= 1) {
            __syncthreads();
            if (t < off) cnt[t] += cnt[t + off];
        }
        if (t == 0) bsum[b] = cnt[0];
    } else {
        int bb = b - NBUCK;
        int lo = bbase_s[bb], hi = bbase_s[bb + 1];
        for (int i = lo + t; i < hi; i += 256)
            atomicAdd(&cnt[srcp[i]], 1);
        __syncthreads();
        int node = bb * 256 + t;
        if (node < N_NODES) deg_out[node] = cnt[t];
    }
}

// Merged scan2+scan3.
__global__ void scan23_kernel(const int* __restrict__ deg_in, const int* __restrict__ bsum,
                              const int* __restrict__ deg_out, const int* __restrict__ labels,
                              int* __restrict__ row_off,
                              float* __restrict__ out_norm, float* __restrict__ in_norm,
                              int2* __restrict__ node_info) {
    __shared__ int pb[256];
    __shared__ int s[256];
    int t = threadIdx.x, i = blockIdx.x * 256 + t;
    pb[t] = (t < (int)blockIdx.x) ? bsum[t] : 0;
    int own = (i < N_NODES) ? deg_in[i] : 0;
    s[t] = own;
    __syncthreads();
    for (int off = 128; off > 0; off >>= 1) {
        if (t < off) pb[t] += pb[t + off];
        __syncthreads();
    }
    int base = pb[0];
    for (int off = 1; off < 256; off <<= 1) {
        int v = s[t];
        if (t >= off) v += s[t - off];
        __syncthreads();
        s[t] = v;
        __syncthreads();
    }
    if (i < N_NODES) {
        row_off[i] = base + s[t] - own;
        float on = rsqrtf(fmaxf((float)deg_out[i], 1.0f));
        out_norm[i] = on;
        in_norm[i]  = rsqrtf(fmaxf((float)own, 1.0f));
        node_info[i] = make_int2(labels[i] << 16, __float_as_int(on));
    }
}

// One block per dst-bucket: LDS per-node rank cursors -> final edge_rec write.
__global__ void fine_scatter_kernel(const int* __restrict__ dstp, const int* __restrict__ bbase_d,
                                    const int* __restrict__ row_off,
                                    const int2* __restrict__ node_info,
                                    int2* __restrict__ edge_rec) {
    __shared__ int cur[256];
    __shared__ int ro[256];
    int b = blockIdx.x, t = threadIdx.x;
    int node = b * 256 + t;
    ro[t] = (node < N_NODES) ? row_off[node] : 0;
    cur[t] = 0;
    __syncthreads();
    int lo = bbase_d[b], hi = bbase_d[b + 1];
    for (int i = lo + t; i < hi; i += 256) {
        int rec = dstp[i];
        int s = rec & 0xFFFF;
        int nl = (rec >> 16) & 0xFF;
        int r = atomicAdd(&cur[nl], 1);
        int2 ni = node_info[s];
        edge_rec[ro[nl] + r] = make_int2(s | ni.x, ni.y);
    }
}

// Fused layer 1: 2 float4 chunks per thread, unroll-4 edges; edge_rec read linearly.
__global__ void gather1t_kernel(const int2* __restrict__ edge_rec, const float* __restrict__ T1,
                                const int* __restrict__ row_off, const int* __restrict__ deg,
                                const float* __restrict__ in_norm,
                                const float* __restrict__ out_norm, const float* __restrict__ b1,
                                __half* __restrict__ h1s) {
    constexpr int C = HID / 8;   // 12 chunk-pairs per node
    int i = blockIdx.x * blockDim.x + threadIdx.x;
    if (i >= N_NODES * C) return;
    int n = i / C;
    int c = i - n * C;
    const float* t1a = T1 + c * 4;
    const float* t1b = T1 + (c + C) * 4;
    int k = row_off[n];
    int e = k + deg[n];
    float ax = 0.f, ay = 0.f, az = 0.f, aw = 0.f;
    float bx = 0.f, by = 0.f, bz = 0.f, bw = 0.f;
    for (; k + 3 < e; k += 4) {
        int2 i0 = edge_rec[k];
        int2 i1 = edge_rec[k + 1];
        int2 i2 = edge_rec[k + 2];
        int2 i3 = edge_rec[k + 3];
        int r0 = ((unsigned)i0.x >> 16) * HID, r1 = ((unsigned)i1.x >> 16) * HID;
        int r2 = ((unsigned)i2.x >> 16) * HID, r3 = ((unsigned)i3.x >> 16) * HID;
        float4 aA = *(const float4*)(t1a + r0); float4 bA = *(const float4*)(t1b + r0);
        float4 aB = *(const float4*)(t1a + r1); float4 bB = *(const float4*)(t1b + r1);
        float4 aC = *(const float4*)(t1a + r2); float4 bC = *(const float4*)(t1b + r2);
        float4 aD = *(const float4*)(t1a + r3); float4 bD = *(const float4*)(t1b + r3);
        float w0 = __int_as_float(i0.y), w1 = __int_as_float(i1.y);
        float w2 = __int_as_float(i2.y), w3 = __int_as_float(i3.y);
        ax += aA.x * w0 + aB.x * w1 + aC.x * w2 + aD.x * w3;
        ay += aA.y * w0 + aB.y * w1 + aC.y * w2 + aD.y * w3;
        az += aA.z * w0 + aB.z * w1 + aC.z * w2 + aD.z * w3;
        aw += aA.w * w0 + aB.w * w1 + aC.w * w2 + aD.w * w3;
        bx += bA.x * w0 + bB.x * w1 + bC.x * w2 + bD.x * w3;
        by += bA.y * w0 + bB.y * w1 + bC.y * w2 + bD.y * w3;
        bz += bA.z * w0 + bB.z * w1 + bC.z * w2 + bD.z * w3;
        bw += bA.w * w0 + bB.w * w1 + bC.w * w2 + bD.w * w3;
    }
    for (; k < e; ++k) {
        int2 i0 = edge_rec[k];
        int r0 = ((unsigned)i0.x >> 16) * HID;
        float4 aA = *(const float4*)(t1a + r0); float4 bA = *(const float4*)(t1b + r0);
        float w0 = __int_as_float(i0.y);
        ax += aA.x * w0; ay += aA.y * w0; az += aA.z * w0; aw += aA.w * w0;
        bx += bA.x * w0; by += bA.y * w0; bz += bA.z * w0; bw += bA.w * w0;
    }
    float nn = in_norm[n];
    float on = out_norm[n];
    float4 b1a = *(const float4*)(b1 + c * 4);
    float4 b1b = *(const float4*)(b1 + (c + C) * 4);
    uint2 rA, rB;
    rA.x = f2h(fmaxf(ax * nn + b1a.x, 0.f) * on, fmaxf(ay * nn + b1a.y, 0.f) * on);
    rA.y = f2h(fmaxf(az * nn + b1a.z, 0.f) * on, fmaxf(aw * nn + b1a.w, 0.f) * on);
    rB.x = f2h(fmaxf(bx * nn + b1b.x, 0.f) * on, fmaxf(by * nn + b1b.y, 0.f) * on);
    rB.y = f2h(fmaxf(bz * nn + b1b.z, 0.f) * on, fmaxf(bw * nn + b1b.w, 0.f) * on);
    __half* op = h1s + (size_t)n * HID;
    *(uint2*)(op + c * 4) = rA;
    *(uint2*)(op + (c + C) * 4) = rB;
}

// R5 fused: layer-2 aggregation (gather h1s fp16 rows -> LDS fp16 A) + MFMA
// layers 2+3. 128 nodes/block, 512 threads. h2 overwrites A in-place (each
// wave owns its 16 rows exclusively). A-frag: row=lane&15, k=(lane>>4)*8+i;
// D: col=lane&15, row=(lane>>4)*4+reg (m89/m91-verified).
__global__ __launch_bounds__(512) void agg_linear23_kernel(
        const __half* __restrict__ hs, const int* __restrict__ row_off,
        const int* __restrict__ deg, const int2* __restrict__ erec,
        const float* __restrict__ in_norm, const __half* __restrict__ wprep,
        const float* __restrict__ b2, const float* __restrict__ out_norm,
        __half* __restrict__ t) {
    __shared__ _Float16 Wl[WPREP_N];          // 33.3 KB: W2t [96][104] + W3t [64][104]
    __shared__ _Float16 A[128][WSTRIDE];      // 26.6 KB: agg fp16, then h2 in-place
    const int tid = threadIdx.x;
    {   // stage W2t+W3t (linear uint4 copy)
        const uint4* sp = (const uint4*)wprep;
        uint4* dp = (uint4*)Wl;
        for (int i = tid; i < WPREP_N / 8; i += 512) dp[i] = sp[i];
    }
    const int n0b = blockIdx.x * 128;

    // ---- phase 1: aggregate 128 nodes x 12 chunk-pairs into A ----
    for (int task = tid; task < 128 * 12; task += 512) {
        int m = task / 12;
        int c = task - m * 12;
        int n = n0b + m;
        uint2 rA = make_uint2(0u, 0u), rB = make_uint2(0u, 0u);
        if (n < N_NODES) {
            const __half* p0 = hs + c * 4;
            const __half* p1 = hs + (c + 12) * 4;
            int k = row_off[n];
            int e = k + deg[n];
            float ax = 0.f, ay = 0.f, az = 0.f, aw = 0.f;
            float bx = 0.f, by = 0.f, bz = 0.f, bw = 0.f;
            for (; k + 3 < e; k += 4) {
                size_t r0 = (size_t)(erec[k].x & 0xFFFF) * HID;
                size_t r1 = (size_t)(erec[k + 1].x & 0xFFFF) * HID;
                size_t r2 = (size_t)(erec[k + 2].x & 0xFFFF) * HID;
                size_t r3 = (size_t)(erec[k + 3].x & 0xFFFF) * HID;
                uint2 aA = *(const uint2*)(p0 + r0); uint2 bA = *(const uint2*)(p1 + r0);
                uint2 aB = *(const uint2*)(p0 + r1); uint2 bB = *(const uint2*)(p1 + r1);
                uint2 aC = *(const uint2*)(p0 + r2); uint2 bC = *(const uint2*)(p1 + r2);
                uint2 aD = *(const uint2*)(p0 + r3); uint2 bD = *(const uint2*)(p1 + r3);
                float2 f;
                f = h2f(aA.x); ax += f.x; ay += f.y;  f = h2f(aA.y); az += f.x; aw += f.y;
                f = h2f(aB.x); ax += f.x; ay += f.y;  f = h2f(aB.y); az += f.x; aw += f.y;
                f = h2f(aC.x); ax += f.x; ay += f.y;  f = h2f(aC.y); az += f.x; aw += f.y;
                f = h2f(aD.x); ax += f.x; ay += f.y;  f = h2f(aD.y); az += f.x; aw += f.y;
                f = h2f(bA.x); bx += f.x; by += f.y;  f = h2f(bA.y); bz += f.x; bw += f.y;
                f = h2f(bB.x); bx += f.x; by += f.y;  f = h2f(bB.y); bz += f.x; bw += f.y;
                f = h2f(bC.x); bx += f.x; by += f.y;  f = h2f(bC.y); bz += f.x; bw += f.y;
                f = h2f(bD.x); bx += f.x; by += f.y;  f = h2f(bD.y); bz += f.x; bw += f.y;
            }
            for (; k < e; ++k) {
                size_t r0 = (size_t)(erec[k].x & 0xFFFF) * HID;
                uint2 aA = *(const uint2*)(p0 + r0); uint2 bA = *(const uint2*)(p1 + r0);
                float2 f;
                f = h2f(aA.x); ax += f.x; ay += f.y;  f = h2f(aA.y); az += f.x; aw += f.y;
                f = h2f(bA.x); bx += f.x; by += f.y;  f = h2f(bA.y); bz += f.x; bw += f.y;
            }
            float nn = in_norm[n];
            rA.x = f2h(ax * nn, ay * nn); rA.y = f2h(az * nn, aw * nn);
            rB.x = f2h(bx * nn, by * nn); rB.y = f2h(bz * nn, bw * nn);
        }
        *(uint2*)(&A[m][c * 4]) = rA;
        *(uint2*)(&A[m][(c + 12) * 4]) = rB;
    }
    __syncthreads();

    // ---- phase 2: MFMA GEMM1 + GEMM2 ----
    const int w = tid >> 6, l = tid & 63;
    const int lr = l & 15, lg = l >> 4;
    const int m0 = w * 16;            // this wave's A-row base
    const int n0 = n0b + m0;

    f16x8 a[3];
#pragma unroll
    for (int kb = 0; kb < 3; ++kb)
        a[kb] = *(const f16x8*)(&A[m0 + lr][kb * 32 + lg * 8]);
    f32x4 acc[6];
#pragma unroll
    for (int nt = 0; nt < 6; ++nt) {
        acc[nt] = (f32x4){0.f, 0.f, 0.f, 0.f};
#pragma unroll
        for (int kb = 0; kb < 3; ++kb) {
            f16x8 bfr = *(const f16x8*)(&Wl[(nt * 16 + lr) * WSTRIDE + kb * 32 + lg * 8]);
            acc[nt] = __builtin_amdgcn_mfma_f32_16x16x32_f16(a[kb], bfr, acc[nt], 0, 0, 0);
        }
    }
    float on4[4];
#pragma unroll
    for (int r = 0; r < 4; ++r) {
        int n = n0 + lg * 4 + r; if (n > N_NODES - 1) n = N_NODES - 1;
        on4[r] = out_norm[n];
    }
    // ensure this wave's A-frag reads completed before in-place h2 overwrite
    asm volatile("s_waitcnt lgkmcnt(0)" ::: "memory");
#pragma unroll
    for (int nt = 0; nt < 6; ++nt) {
        int col = nt * 16 + lr;
        float bb = b2[col];
#pragma unroll
        for (int r = 0; r < 4; ++r) {
            float v = fmaxf(acc[nt][r] + bb, 0.f) * on4[r];
            A[m0 + lg * 4 + r][col] = (_Float16)v;
        }
    }
    // same-wave LDS write->read ordering (rows exclusive per wave: no barrier)
    asm volatile("s_waitcnt lgkmcnt(0)" ::: "memory");

    f16x8 a2[3];
#pragma unroll
    for (int kb = 0; kb < 3; ++kb)
        a2[kb] = *(const f16x8*)(&A[m0 + lr][kb * 32 + lg * 8]);
#pragma unroll
    for (int nt = 0; nt < 4; ++nt) {
        f32x4 acc2 = (f32x4){0.f, 0.f, 0.f, 0.f};
#pragma unroll
        for (int kb = 0; kb < 3; ++kb) {
            f16x8 bfr = *(const f16x8*)(&Wl[(HID + nt * 16 + lr) * WSTRIDE + kb * 32 + lg * 8]);
            acc2 = __builtin_amdgcn_mfma_f32_16x16x32_f16(a2[kb], bfr, acc2, 0, 0, 0);
        }
        int col = nt * 16 + lr;
        if (col < 4 * TC) {
#pragma unroll
            for (int r = 0; r < 4; ++r) {
                int n = n0 + lg * 4 + r;
                if (n < N_NODES) t[(size_t)n * TSTRIDE + col] = __float2half(acc2[r]);
            }
        }
    }
}

// Final gather over FP16 t (128B-aligned rows, 1 line each).
__global__ void gather_out_kernel(const __half* __restrict__ t, const int* __restrict__ row_off,
                                  const int* __restrict__ deg, const int2* __restrict__ erec,
                                  const float* __restrict__ in_norm, const float* __restrict__ bias,
                                  float* __restrict__ out) {
    int i = blockIdx.x * blockDim.x + threadIdx.x;
    if (i >= N_NODES * TC) return;
    int n = i / TC;
    int c = i - n * TC;
    const __half* p0 = t + c * 4;
    int k = row_off[n];
    int e = k + deg[n];
    float ax = 0.f, ay = 0.f, az = 0.f, aw = 0.f;
    for (; k + 3 < e; k += 4) {
        size_t r0 = (size_t)(erec[k].x & 0xFFFF) * TSTRIDE;
        size_t r1 = (size_t)(erec[k + 1].x & 0xFFFF) * TSTRIDE;
        size_t r2 = (size_t)(erec[k + 2].x & 0xFFFF) * TSTRIDE;
        size_t r3 = (size_t)(erec[k + 3].x & 0xFFFF) * TSTRIDE;
        uint2 v0 = *(const uint2*)(p0 + r0);
        uint2 v1 = *(const uint2*)(p0 + r1);
        uint2 v2 = *(const uint2*)(p0 + r2);
        uint2 v3 = *(const uint2*)(p0 + r3);
        float2 f;
        f = h2f(v0.x); ax += f.x; ay += f.y;  f = h2f(v0.y); az += f.x; aw += f.y;
        f = h2f(v1.x); ax += f.x; ay += f.y;  f = h2f(v1.y); az += f.x; aw += f.y;
        f = h2f(v2.x); ax += f.x; ay += f.y;  f = h2f(v2.y); az += f.x; aw += f.y;
        f = h2f(v3.x); ax += f.x; ay += f.y;  f = h2f(v3.y); az += f.x; aw += f.y;
    }
    for (; k < e; ++k) {
        size_t r0 = (size_t)(erec[k].x & 0xFFFF) * TSTRIDE;
        uint2 v0 = *(const uint2*)(p0 + r0);
        float2 f;
        f = h2f(v0.x); ax += f.x; ay += f.y;  f = h2f(v0.y); az += f.x; aw += f.y;
    }
    float nn = in_norm[n];
    int j = c * 4;
    float* op = out + (size_t)n * NLAB + j;   // rows 8B-aligned only -> float2 stores
    float2 lo; lo.x = ax * nn + bias[j];     lo.y = ay * nn + bias[j + 1];
    *(float2*)op = lo;
    if (j + 2 < NLAB) {
        float2 hi; hi.x = az * nn + bias[j + 2]; hi.y = aw * nn + bias[j + 3];
        *(float2*)(op + 2) = hi;
    }
}

static inline int cdiv(long a, int b) { return (int)((a + b - 1) / b); }

extern "C" void kernel_launch(void* const* d_in, const int* in_sizes, int n_in,
                              void* d_out, int out_size, void* d_ws, size_t ws_size,
                              hipStream_t stream) {
    const int*   dep_labels = (const int*)d_in[0];
    const int*   src        = (const int*)d_in[1];
    const int*   dst        = (const int*)d_in[2];
    const float* emb        = (const float*)d_in[3];
    const float* W1 = (const float*)d_in[4]; const float* b1 = (const float*)d_in[5];
    const float* W2 = (const float*)d_in[6]; const float* b2 = (const float*)d_in[7];
    const float* W3 = (const float*)d_in[8]; const float* b3 = (const float*)d_in[9];
    float* out = (float*)d_out;

    // ---- workspace layout (regions 16B aligned) ----
    int* wsp           = (int*)d_ws;
    int* row_off       = wsp;                 wsp += N_NODES;
    int* deg_in        = wsp;                 wsp += N_NODES;
    int* deg_out_a     = wsp;                 wsp += N_NODES;
    int* bsum          = wsp;                 wsp += 256;
    float* out_norm    = (float*)wsp;         wsp += N_NODES;
    float* in_norm     = (float*)wsp;         wsp += N_NODES;
    int2* node_info    = (int2*)wsp;          wsp += 2 * N_NODES;
    float* T1          = (float*)wsp;         wsp += NLAB * HID + 16;
    __half* wprep      = (__half*)wsp;        wsp += WPREP_N / 2;
    int2* edge_rec     = (int2*)wsp;          wsp += 2 * N_EDGES;      // 6.4 MB
    int* bufA          = wsp;                 wsp += (size_t)N_NODES * HID;
    __half* bufH       = (__half*)wsp;        // h1s (fp16), then t (fp16, stride 64)
    // CSR-build temporaries alias into bufA (dead after fine_scatter):
    int* histd    = bufA;                     // [NBP][256]
    int* hists    = histd + NBP * 256;
    int* blkrel_d = hists + NBP * 256;
    int* blkrel_s = blkrel_d + NBP * 256;
    int* bbase_d  = blkrel_s + NBP * 256;     // [256]
    int* bbase_s  = bbase_d + 256;            // [256]
    int* dstp     = bbase_s + 256;            // [N_EDGES]
    unsigned char* srcp = (unsigned char*)(dstp + N_EDGES);  // [N_EDGES] bytes

    const int B = 256;

    // ---- CSR build: no global atomics anywhere ----
    coarse_hist_kernel<<<NBP + T1B + WPREPB, B, 0, stream>>>(src, dst, histd, hists,
                                                             emb, W1, T1, W2, W3, wprep);
    coarse_scan_kernel<<<2, B, 0, stream>>>(histd, hists, blkrel_d, blkrel_s, bbase_d, bbase_s);
    partition_kernel<<<NBP, B, 0, stream>>>(src, dst, blkrel_d, blkrel_s, bbase_d, bbase_s,
                                            dstp, srcp);
    fine_hist_kernel<<<2 * NBUCK, B, 0, stream>>>(dstp, srcp, bbase_d, bbase_s,
                                                  deg_in, deg_out_a, bsum);
    scan23_kernel<<<NB_SCAN, B, 0, stream>>>(deg_in, bsum, deg_out_a, dep_labels,
                                             row_off, out_norm, in_norm, node_info);
    fine_scatter_kernel<<<NBUCK, B, 0, stream>>>(dstp, bbase_d, row_off, node_info, edge_rec);

    // Layer 1 fused: linear edge_rec stream, T1 L1-resident -> h1s (fp16)
    gather1t_kernel<<<cdiv((long)N_NODES * (HID / 8), B), B, 0, stream>>>(
        edge_rec, T1, row_off, deg_in, in_norm, out_norm, b1, bufH);

    // Layer 2 aggregate + layers 2+3 MFMA transform, fused: h1s -> t
    agg_linear23_kernel<<<NMFMA, 512, 0, stream>>>(
        bufH, row_off, deg_in, edge_rec, in_norm, wprep, b2, out_norm, bufH);

    // Final gather + bias (fp16 t -> fp32 out)
    gather_out_kernel<<<cdiv((long)N_NODES * TC, B), B, 0, stream>>>(
        bufH, row_off, deg_in, edge_rec, in_norm, b3, out);
}

// Round 8
// 200.647 us; speedup vs baseline: 1.4497x; 1.0187x over previous
//
#include <hip/hip_runtime.h>
#include <hip/hip_fp16.h>

// GCN 3-layer, CSR-gather, low-rank L1 + fused L2/L3 transform.
//   CSR build GLOBAL-ATOMIC-FREE (two-level counting sort, LDS atomics only).
//   R6/R7: RACE FIX — t now lives in bufA (disjoint from h1s in bufH; R5
//     aliased both in bufH -> cross-block clobber, absmax 0.0054 nondet).
//     node_info/out_norm moved into fine_hist src-side; scan23+fine_scatter
//     merged (scan block b == bucket b; row_off stays in LDS for the scatter).
//     (R7 = R6 resubmitted verbatim: round-6 bench was an infra failure.)
//   L1 fused: h1s(fp16) = relu(in_norm*sum w_e*T1[lbl_e] + b1)*out_norm (linear stream)
//   L2+L3 fused (R5): agg -> LDS fp16 A, MFMA 16x16x32_f16 (fp32 acc),
//     W2t/W3t fp16 LDS stride 104, h2 in-place per-wave, t fp16 stride 64.
//   out = in_norm*gather(t fp16) + b3
#define N_NODES 50000
#define N_EDGES 800000
#define EMB     64
#define HID     96
#define NLAB    50
#define NB_SCAN ((N_NODES + 255) / 256)    // 196
#define TSTRIDE 64                         // t row stride (halfs): 128B line-aligned
#define TC      13                         // gather chunks over t (cols 0..51)
#define T1B     ((NLAB * HID + 255) / 256) // 19
#define NBP     256                        // partition blocks
#define EPB     ((N_EDGES + NBP - 1) / NBP)  // 3125 edges per block
#define NBUCK   196                        // node buckets of 256 (covers 50176)
#define WSTRIDE 104                        // W2t/W3t/A LDS row stride (halfs)
#define WPREP_N (160 * WSTRIDE)            // 96 W2t rows + 64 W3t rows
#define WPREPB  ((WPREP_N + 255) / 256)    // 65
#define NMFMA   ((N_NODES + 127) / 128)    // 392 blocks of 128 nodes

typedef _Float16 f16x8 __attribute__((ext_vector_type(8)));
typedef float f32x4 __attribute__((ext_vector_type(4)));

__device__ __forceinline__ float2 h2f(unsigned u) {
    __half2 h = *reinterpret_cast<__half2*>(&u);
    return __half22float2(h);
}
__device__ __forceinline__ unsigned f2h(float a, float b) {
    __half2 h = __floats2half2_rn(a, b);
    return *reinterpret_cast<unsigned*>(&h);
}

// Per-block coarse histograms (dst>>8, src>>8) via LDS atomics. Tail blocks:
// T1 = emb@W1, then W2t/W3t fp16 transpose-prep.
__global__ void coarse_hist_kernel(const int* __restrict__ src, const int* __restrict__ dst,
                                   int* __restrict__ histd, int* __restrict__ hists,
                                   const float* __restrict__ emb, const float* __restrict__ W1,
                                   float* __restrict__ T1,
                                   const float* __restrict__ W2, const float* __restrict__ W3,
                                   __half* __restrict__ wprep) {
    int b = blockIdx.x, t = threadIdx.x;
    if (b < NBP) {
        __shared__ int hd[256], hs[256];
        hd[t] = 0; hs[t] = 0;
        __syncthreads();
        int hi = min(b * EPB + EPB, N_EDGES);
        for (int i = b * EPB + t; i < hi; i += 256) {
            atomicAdd(&hd[((unsigned)dst[i]) >> 8], 1);
            atomicAdd(&hs[((unsigned)src[i]) >> 8], 1);
        }
        __syncthreads();
        histd[b * 256 + t] = hd[t];
        hists[b * 256 + t] = hs[t];
    } else if (b < NBP + T1B) {
        int i = (b - NBP) * 256 + t;
        if (i < NLAB * HID) {
            int l = i / HID, j = i - l * HID;
            float sum = 0.0f;
#pragma unroll
            for (int k = 0; k < EMB; ++k) sum += emb[l * EMB + k] * W1[k * HID + j];
            T1[i] = sum;
        }
    } else {
        // wprep[0..96): W2t rows (j over HID); wprep[96..160): W3t rows (j over 64)
        int i = (b - NBP - T1B) * 256 + t;
        if (i < WPREP_N) {
            int j = i / WSTRIDE, kk = i - j * WSTRIDE;
            float v = 0.0f;
            if (kk < HID) {
                if (j < HID) v = W2[kk * HID + j];
                else { int jj = j - HID; if (jj < NLAB) v = W3[kk * NLAB + jj]; }
            }
            wprep[i] = __float2half(v);
        }
    }
}

// Block 0: dst side; block 1: src side. Thread t owns bucket t.
__global__ void coarse_scan_kernel(const int* __restrict__ histd, const int* __restrict__ hists,
                                   int* __restrict__ blkrel_d, int* __restrict__ blkrel_s,
                                   int* __restrict__ bbase_d, int* __restrict__ bbase_s) {
    __shared__ int sh[256];
    int t = threadIdx.x;
    const int* hist = blockIdx.x ? hists : histd;
    int* blkrel     = blockIdx.x ? blkrel_s : blkrel_d;
    int* bbase      = blockIdx.x ? bbase_s : bbase_d;
    int run = 0;
#pragma unroll 16
    for (int b = 0; b < NBP; ++b) {
        blkrel[b * 256 + t] = run;
        run += hist[b * 256 + t];
    }
    sh[t] = run;
    __syncthreads();
    for (int off = 1; off < 256; off <<= 1) {
        int v = sh[t];
        if (t >= off) v += sh[t - off];
        __syncthreads();
        sh[t] = v;
        __syncthreads();
    }
    bbase[t] = sh[t] - run;   // exclusive bucket base
}

// Scatter edges into bucket-partitioned arrays via LDS cursors (no global RMW).
// dstp rec = src | (dst&255)<<16 ; srcp rec = (byte) src&255.
__global__ void partition_kernel(const int* __restrict__ src, const int* __restrict__ dst,
                                 const int* __restrict__ blkrel_d, const int* __restrict__ blkrel_s,
                                 const int* __restrict__ bbase_d, const int* __restrict__ bbase_s,
                                 int* __restrict__ dstp, unsigned char* __restrict__ srcp) {
    __shared__ int curd[256], curs[256];
    int b = blockIdx.x, t = threadIdx.x;
    curd[t] = bbase_d[t] + blkrel_d[b * 256 + t];
    curs[t] = bbase_s[t] + blkrel_s[b * 256 + t];
    __syncthreads();
    int hi = min(b * EPB + EPB, N_EDGES);
    for (int i = b * EPB + t; i < hi; i += 256) {
        int d = dst[i], s = src[i];
        int pd = atomicAdd(&curd[((unsigned)d) >> 8], 1);
        dstp[pd] = s | ((d & 0xFF) << 16);
        int ps = atomicAdd(&curs[((unsigned)s) >> 8], 1);
        srcp[ps] = (unsigned char)(s & 0xFF);
    }
}

// Per-bucket fine histogram -> degree arrays (plain stores, no atomics).
// Dst-buckets tree-reduce counts -> bsum. Src-buckets also emit out_norm and
// node_info (label<<16, out_norm bits) so the merged scan+scatter kernel can
// consume node_info without a cross-block dependency.
__global__ void fine_hist_kernel(const int* __restrict__ dstp, const unsigned char* __restrict__ srcp,
                                 const int* __restrict__ bbase_d, const int* __restrict__ bbase_s,
                                 const int* __restrict__ labels,
                                 int* __restrict__ deg_in, int* __restrict__ deg_out,
                                 float* __restrict__ out_norm, int2* __restrict__ node_info,
                                 int* __restrict__ bsum) {
    __shared__ int cnt[256];
    int b = blockIdx.x, t = threadIdx.x;
    cnt[t] = 0;
    __syncthreads();
    if (b < NBUCK) {
        int lo = bbase_d[b], hi = bbase_d[b + 1];
        for (int i = lo + t; i < hi; i += 256)
            atomicAdd(&cnt[(dstp[i] >> 16) & 0xFF], 1);
        __syncthreads();
        int node = b * 256 + t;
        if (node < N_NODES) deg_in[node] = cnt[t];
        // tree-reduce cnt -> bsum[b]
        for (int off = 128; off > 0; off >>= 1) {
            __syncthreads();
            if (t < off) cnt[t] += cnt[t + off];
        }
        if (t == 0) bsum[b] = cnt[0];
    } else {
        int bb = b - NBUCK;
        int lo = bbase_s[bb], hi = bbase_s[bb + 1];
        for (int i = lo + t; i < hi; i += 256)
            atomicAdd(&cnt[srcp[i]], 1);
        __syncthreads();
        int node = bb * 256 + t;
        if (node < N_NODES) {
            int d = cnt[t];
            deg_out[node] = d;
            float on = rsqrtf(fmaxf((float)d, 1.0f));
            out_norm[node] = on;
            node_info[node] = make_int2(labels[node] << 16, __float_as_int(on));
        }
    }
}

// Merged scan + scatter: block b scans chunk b (== bucket b) -> row_off,
// in_norm; then scatters bucket b's edges into edge_rec using LDS row_off.
// rec = {src|label<<16, out_norm} (node_info ready from fine_hist).
__global__ void scan_scatter_kernel(const int* __restrict__ deg_in, const int* __restrict__ bsum,
                                    const int* __restrict__ dstp, const int* __restrict__ bbase_d,
                                    const int2* __restrict__ node_info,
                                    int* __restrict__ row_off, float* __restrict__ in_norm,
                                    int2* __restrict__ edge_rec) {
    __shared__ int pb[256];
    __shared__ int s[256];
    __shared__ int ro[256];
    __shared__ int cur[256];
    int t = threadIdx.x, b = blockIdx.x, i = b * 256 + t;
    pb[t] = (t < b) ? bsum[t] : 0;
    int own = (i < N_NODES) ? deg_in[i] : 0;
    s[t] = own;
    cur[t] = 0;
    __syncthreads();
    for (int off = 128; off > 0; off >>= 1) {
        if (t < off) pb[t] += pb[t + off];
        __syncthreads();
    }
    int base = pb[0];
    for (int off = 1; off < 256; off <<= 1) {
        int v = s[t];
        if (t >= off) v += s[t - off];
        __syncthreads();
        s[t] = v;
        __syncthreads();
    }
    int r0 = base + s[t] - own;
    ro[t] = r0;
    if (i < N_NODES) {
        row_off[i] = r0;
        in_norm[i] = rsqrtf(fmaxf((float)own, 1.0f));
    }
    __syncthreads();
    int lo = bbase_d[b], hi = bbase_d[b + 1];
    for (int k = lo + t; k < hi; k += 256) {
        int rec = dstp[k];
        int sn = rec & 0xFFFF;
        int nl = (rec >> 16) & 0xFF;
        int r = atomicAdd(&cur[nl], 1);
        int2 ni = node_info[sn];
        edge_rec[ro[nl] + r] = make_int2(sn | ni.x, ni.y);
    }
}

// Fused layer 1: 2 float4 chunks per thread, unroll-4 edges; edge_rec read linearly.
__global__ void gather1t_kernel(const int2* __restrict__ edge_rec, const float* __restrict__ T1,
                                const int* __restrict__ row_off, const int* __restrict__ deg,
                                const float* __restrict__ in_norm,
                                const float* __restrict__ out_norm, const float* __restrict__ b1,
                                __half* __restrict__ h1s) {
    constexpr int C = HID / 8;   // 12 chunk-pairs per node
    int i = blockIdx.x * blockDim.x + threadIdx.x;
    if (i >= N_NODES * C) return;
    int n = i / C;
    int c = i - n * C;
    const float* t1a = T1 + c * 4;
    const float* t1b = T1 + (c + C) * 4;
    int k = row_off[n];
    int e = k + deg[n];
    float ax = 0.f, ay = 0.f, az = 0.f, aw = 0.f;
    float bx = 0.f, by = 0.f, bz = 0.f, bw = 0.f;
    for (; k + 3 < e; k += 4) {
        int2 i0 = edge_rec[k];
        int2 i1 = edge_rec[k + 1];
        int2 i2 = edge_rec[k + 2];
        int2 i3 = edge_rec[k + 3];
        int r0 = ((unsigned)i0.x >> 16) * HID, r1 = ((unsigned)i1.x >> 16) * HID;
        int r2 = ((unsigned)i2.x >> 16) * HID, r3 = ((unsigned)i3.x >> 16) * HID;
        float4 aA = *(const float4*)(t1a + r0); float4 bA = *(const float4*)(t1b + r0);
        float4 aB = *(const float4*)(t1a + r1); float4 bB = *(const float4*)(t1b + r1);
        float4 aC = *(const float4*)(t1a + r2); float4 bC = *(const float4*)(t1b + r2);
        float4 aD = *(const float4*)(t1a + r3); float4 bD = *(const float4*)(t1b + r3);
        float w0 = __int_as_float(i0.y), w1 = __int_as_float(i1.y);
        float w2 = __int_as_float(i2.y), w3 = __int_as_float(i3.y);
        ax += aA.x * w0 + aB.x * w1 + aC.x * w2 + aD.x * w3;
        ay += aA.y * w0 + aB.y * w1 + aC.y * w2 + aD.y * w3;
        az += aA.z * w0 + aB.z * w1 + aC.z * w2 + aD.z * w3;
        aw += aA.w * w0 + aB.w * w1 + aC.w * w2 + aD.w * w3;
        bx += bA.x * w0 + bB.x * w1 + bC.x * w2 + bD.x * w3;
        by += bA.y * w0 + bB.y * w1 + bC.y * w2 + bD.y * w3;
        bz += bA.z * w0 + bB.z * w1 + bC.z * w2 + bD.z * w3;
        bw += bA.w * w0 + bB.w * w1 + bC.w * w2 + bD.w * w3;
    }
    for (; k < e; ++k) {
        int2 i0 = edge_rec[k];
        int r0 = ((unsigned)i0.x >> 16) * HID;
        float4 aA = *(const float4*)(t1a + r0); float4 bA = *(const float4*)(t1b + r0);
        float w0 = __int_as_float(i0.y);
        ax += aA.x * w0; ay += aA.y * w0; az += aA.z * w0; aw += aA.w * w0;
        bx += bA.x * w0; by += bA.y * w0; bz += bA.z * w0; bw += bA.w * w0;
    }
    float nn = in_norm[n];
    float on = out_norm[n];
    float4 b1a = *(const float4*)(b1 + c * 4);
    float4 b1b = *(const float4*)(b1 + (c + C) * 4);
    uint2 rA, rB;
    rA.x = f2h(fmaxf(ax * nn + b1a.x, 0.f) * on, fmaxf(ay * nn + b1a.y, 0.f) * on);
    rA.y = f2h(fmaxf(az * nn + b1a.z, 0.f) * on, fmaxf(aw * nn + b1a.w, 0.f) * on);
    rB.x = f2h(fmaxf(bx * nn + b1b.x, 0.f) * on, fmaxf(by * nn + b1b.y, 0.f) * on);
    rB.y = f2h(fmaxf(bz * nn + b1b.z, 0.f) * on, fmaxf(bw * nn + b1b.w, 0.f) * on);
    __half* op = h1s + (size_t)n * HID;
    *(uint2*)(op + c * 4) = rA;
    *(uint2*)(op + (c + C) * 4) = rB;
}

// Fused: layer-2 aggregation (gather h1s fp16 rows -> LDS fp16 A) + MFMA
// layers 2+3. 128 nodes/block, 512 threads. h2 overwrites A in-place (each
// wave owns its 16 rows exclusively). A-frag: row=lane&15, k=(lane>>4)*8+i;
// D: col=lane&15, row=(lane>>4)*4+reg (m89/m91-verified).
// NOTE: t must be DISJOINT from hs (R6 race fix: t lives in bufA).
__global__ __launch_bounds__(512) void agg_linear23_kernel(
        const __half* __restrict__ hs, const int* __restrict__ row_off,
        const int* __restrict__ deg, const int2* __restrict__ erec,
        const float* __restrict__ in_norm, const __half* __restrict__ wprep,
        const float* __restrict__ b2, const float* __restrict__ out_norm,
        __half* __restrict__ t) {
    __shared__ _Float16 Wl[WPREP_N];          // 33.3 KB: W2t [96][104] + W3t [64][104]
    __shared__ _Float16 A[128][WSTRIDE];      // 26.6 KB: agg fp16, then h2 in-place
    const int tid = threadIdx.x;
    {   // stage W2t+W3t (linear uint4 copy)
        const uint4* sp = (const uint4*)wprep;
        uint4* dp = (uint4*)Wl;
        for (int i = tid; i < WPREP_N / 8; i += 512) dp[i] = sp[i];
    }
    const int n0b = blockIdx.x * 128;

    // ---- phase 1: aggregate 128 nodes x 12 chunk-pairs into A ----
    for (int task = tid; task < 128 * 12; task += 512) {
        int m = task / 12;
        int c = task - m * 12;
        int n = n0b + m;
        uint2 rA = make_uint2(0u, 0u), rB = make_uint2(0u, 0u);
        if (n < N_NODES) {
            const __half* p0 = hs + c * 4;
            const __half* p1 = hs + (c + 12) * 4;
            int k = row_off[n];
            int e = k + deg[n];
            float ax = 0.f, ay = 0.f, az = 0.f, aw = 0.f;
            float bx = 0.f, by = 0.f, bz = 0.f, bw = 0.f;
            for (; k + 3 < e; k += 4) {
                size_t r0 = (size_t)(erec[k].x & 0xFFFF) * HID;
                size_t r1 = (size_t)(erec[k + 1].x & 0xFFFF) * HID;
                size_t r2 = (size_t)(erec[k + 2].x & 0xFFFF) * HID;
                size_t r3 = (size_t)(erec[k + 3].x & 0xFFFF) * HID;
                uint2 aA = *(const uint2*)(p0 + r0); uint2 bA = *(const uint2*)(p1 + r0);
                uint2 aB = *(const uint2*)(p0 + r1); uint2 bB = *(const uint2*)(p1 + r1);
                uint2 aC = *(const uint2*)(p0 + r2); uint2 bC = *(const uint2*)(p1 + r2);
                uint2 aD = *(const uint2*)(p0 + r3); uint2 bD = *(const uint2*)(p1 + r3);
                float2 f;
                f = h2f(aA.x); ax += f.x; ay += f.y;  f = h2f(aA.y); az += f.x; aw += f.y;
                f = h2f(aB.x); ax += f.x; ay += f.y;  f = h2f(aB.y); az += f.x; aw += f.y;
                f = h2f(aC.x); ax += f.x; ay += f.y;  f = h2f(aC.y); az += f.x; aw += f.y;
                f = h2f(aD.x); ax += f.x; ay += f.y;  f = h2f(aD.y); az += f.x; aw += f.y;
                f = h2f(bA.x); bx += f.x; by += f.y;  f = h2f(bA.y); bz += f.x; bw += f.y;
                f = h2f(bB.x); bx += f.x; by += f.y;  f = h2f(bB.y); bz += f.x; bw += f.y;
                f = h2f(bC.x); bx += f.x; by += f.y;  f = h2f(bC.y); bz += f.x; bw += f.y;
                f = h2f(bD.x); bx += f.x; by += f.y;  f = h2f(bD.y); bz += f.x; bw += f.y;
            }
            for (; k < e; ++k) {
                size_t r0 = (size_t)(erec[k].x & 0xFFFF) * HID;
                uint2 aA = *(const uint2*)(p0 + r0); uint2 bA = *(const uint2*)(p1 + r0);
                float2 f;
                f = h2f(aA.x); ax += f.x; ay += f.y;  f = h2f(aA.y); az += f.x; aw += f.y;
                f = h2f(bA.x); bx += f.x; by += f.y;  f = h2f(bA.y); bz += f.x; bw += f.y;
            }
            float nn = in_norm[n];
            rA.x = f2h(ax * nn, ay * nn); rA.y = f2h(az * nn, aw * nn);
            rB.x = f2h(bx * nn, by * nn); rB.y = f2h(bz * nn, bw * nn);
        }
        *(uint2*)(&A[m][c * 4]) = rA;
        *(uint2*)(&A[m][(c + 12) * 4]) = rB;
    }
    __syncthreads();

    // ---- phase 2: MFMA GEMM1 + GEMM2 ----
    const int w = tid >> 6, l = tid & 63;
    const int lr = l & 15, lg = l >> 4;
    const int m0 = w * 16;            // this wave's A-row base
    const int n0 = n0b + m0;

    f16x8 a[3];
#pragma unroll
    for (int kb = 0; kb < 3; ++kb)
        a[kb] = *(const f16x8*)(&A[m0 + lr][kb * 32 + lg * 8]);
    f32x4 acc[6];
#pragma unroll
    for (int nt = 0; nt < 6; ++nt) {
        acc[nt] = (f32x4){0.f, 0.f, 0.f, 0.f};
#pragma unroll
        for (int kb = 0; kb < 3; ++kb) {
            f16x8 bfr = *(const f16x8*)(&Wl[(nt * 16 + lr) * WSTRIDE + kb * 32 + lg * 8]);
            acc[nt] = __builtin_amdgcn_mfma_f32_16x16x32_f16(a[kb], bfr, acc[nt], 0, 0, 0);
        }
    }
    float on4[4];
#pragma unroll
    for (int r = 0; r < 4; ++r) {
        int n = n0 + lg * 4 + r; if (n > N_NODES - 1) n = N_NODES - 1;
        on4[r] = out_norm[n];
    }
    // ensure this wave's A-frag reads completed before in-place h2 overwrite
    asm volatile("s_waitcnt lgkmcnt(0)" ::: "memory");
#pragma unroll
    for (int nt = 0; nt < 6; ++nt) {
        int col = nt * 16 + lr;
        float bb = b2[col];
#pragma unroll
        for (int r = 0; r < 4; ++r) {
            float v = fmaxf(acc[nt][r] + bb, 0.f) * on4[r];
            A[m0 + lg * 4 + r][col] = (_Float16)v;
        }
    }
    // same-wave LDS write->read ordering (rows exclusive per wave: no barrier)
    asm volatile("s_waitcnt lgkmcnt(0)" ::: "memory");

    f16x8 a2[3];
#pragma unroll
    for (int kb = 0; kb < 3; ++kb)
        a2[kb] = *(const f16x8*)(&A[m0 + lr][kb * 32 + lg * 8]);
#pragma unroll
    for (int nt = 0; nt < 4; ++nt) {
        f32x4 acc2 = (f32x4){0.f, 0.f, 0.f, 0.f};
#pragma unroll
        for (int kb = 0; kb < 3; ++kb) {
            f16x8 bfr = *(const f16x8*)(&Wl[(HID + nt * 16 + lr) * WSTRIDE + kb * 32 + lg * 8]);
            acc2 = __builtin_amdgcn_mfma_f32_16x16x32_f16(a2[kb], bfr, acc2, 0, 0, 0);
        }
        int col = nt * 16 + lr;
        if (col < 4 * TC) {
#pragma unroll
            for (int r = 0; r < 4; ++r) {
                int n = n0 + lg * 4 + r;
                if (n < N_NODES) t[(size_t)n * TSTRIDE + col] = __float2half(acc2[r]);
            }
        }
    }
}

// Final gather over FP16 t (128B-aligned rows, 1 line each).
__global__ void gather_out_kernel(const __half* __restrict__ t, const int* __restrict__ row_off,
                                  const int* __restrict__ deg, const int2* __restrict__ erec,
                                  const float* __restrict__ in_norm, const float* __restrict__ bias,
                                  float* __restrict__ out) {
    int i = blockIdx.x * blockDim.x + threadIdx.x;
    if (i >= N_NODES * TC) return;
    int n = i / TC;
    int c = i - n * TC;
    const __half* p0 = t + c * 4;
    int k = row_off[n];
    int e = k + deg[n];
    float ax = 0.f, ay = 0.f, az = 0.f, aw = 0.f;
    for (; k + 3 < e; k += 4) {
        size_t r0 = (size_t)(erec[k].x & 0xFFFF) * TSTRIDE;
        size_t r1 = (size_t)(erec[k + 1].x & 0xFFFF) * TSTRIDE;
        size_t r2 = (size_t)(erec[k + 2].x & 0xFFFF) * TSTRIDE;
        size_t r3 = (size_t)(erec[k + 3].x & 0xFFFF) * TSTRIDE;
        uint2 v0 = *(const uint2*)(p0 + r0);
        uint2 v1 = *(const uint2*)(p0 + r1);
        uint2 v2 = *(const uint2*)(p0 + r2);
        uint2 v3 = *(const uint2*)(p0 + r3);
        float2 f;
        f = h2f(v0.x); ax += f.x; ay += f.y;  f = h2f(v0.y); az += f.x; aw += f.y;
        f = h2f(v1.x); ax += f.x; ay += f.y;  f = h2f(v1.y); az += f.x; aw += f.y;
        f = h2f(v2.x); ax += f.x; ay += f.y;  f = h2f(v2.y); az += f.x; aw += f.y;
        f = h2f(v3.x); ax += f.x; ay += f.y;  f = h2f(v3.y); az += f.x; aw += f.y;
    }
    for (; k < e; ++k) {
        size_t r0 = (size_t)(erec[k].x & 0xFFFF) * TSTRIDE;
        uint2 v0 = *(const uint2*)(p0 + r0);
        float2 f;
        f = h2f(v0.x); ax += f.x; ay += f.y;  f = h2f(v0.y); az += f.x; aw += f.y;
    }
    float nn = in_norm[n];
    int j = c * 4;
    float* op = out + (size_t)n * NLAB + j;   // rows 8B-aligned only -> float2 stores
    float2 lo; lo.x = ax * nn + bias[j];     lo.y = ay * nn + bias[j + 1];
    *(float2*)op = lo;
    if (j + 2 < NLAB) {
        float2 hi; hi.x = az * nn + bias[j + 2]; hi.y = aw * nn + bias[j + 3];
        *(float2*)(op + 2) = hi;
    }
}

static inline int cdiv(long a, int b) { return (int)((a + b - 1) / b); }

extern "C" void kernel_launch(void* const* d_in, const int* in_sizes, int n_in,
                              void* d_out, int out_size, void* d_ws, size_t ws_size,
                              hipStream_t stream) {
    const int*   dep_labels = (const int*)d_in[0];
    const int*   src        = (const int*)d_in[1];
    const int*   dst        = (const int*)d_in[2];
    const float* emb        = (const float*)d_in[3];
    const float* W1 = (const float*)d_in[4]; const float* b1 = (const float*)d_in[5];
    const float* W2 = (const float*)d_in[6]; const float* b2 = (const float*)d_in[7];
    const float* W3 = (const float*)d_in[8]; const float* b3 = (const float*)d_in[9];
    float* out = (float*)d_out;

    // ---- workspace layout (regions 16B aligned) ----
    int* wsp           = (int*)d_ws;
    int* row_off       = wsp;                 wsp += N_NODES;
    int* deg_in        = wsp;                 wsp += N_NODES;
    int* deg_out_a     = wsp;                 wsp += N_NODES;
    int* bsum          = wsp;                 wsp += 256;
    float* out_norm    = (float*)wsp;         wsp += N_NODES;
    float* in_norm     = (float*)wsp;         wsp += N_NODES;
    int2* node_info    = (int2*)wsp;          wsp += 2 * N_NODES;
    float* T1          = (float*)wsp;         wsp += NLAB * HID + 16;
    __half* wprep      = (__half*)wsp;        wsp += WPREP_N / 2;
    int2* edge_rec     = (int2*)wsp;          wsp += 2 * N_EDGES;      // 6.4 MB
    int* bufA          = wsp;                 wsp += (size_t)N_NODES * HID;   // 19.2 MB
    __half* bufH       = (__half*)wsp;        // h1s (fp16) ONLY (t moved out, R6)
    // t (fp16, stride 64, 6.4 MB) lives in bufA — disjoint from h1s in bufH.
    __half* tbuf       = (__half*)bufA;
    // CSR-build temporaries also alias into bufA (dead before agg_linear23):
    int* histd    = bufA;                     // [NBP][256]
    int* hists    = histd + NBP * 256;
    int* blkrel_d = hists + NBP * 256;
    int* blkrel_s = blkrel_d + NBP * 256;
    int* bbase_d  = blkrel_s + NBP * 256;     // [256]
    int* bbase_s  = bbase_d + 256;            // [256]
    int* dstp     = bbase_s + 256;            // [N_EDGES]
    unsigned char* srcp = (unsigned char*)(dstp + N_EDGES);  // [N_EDGES] bytes

    const int B = 256;

    // ---- CSR build: no global atomics anywhere ----
    coarse_hist_kernel<<<NBP + T1B + WPREPB, B, 0, stream>>>(src, dst, histd, hists,
                                                             emb, W1, T1, W2, W3, wprep);
    coarse_scan_kernel<<<2, B, 0, stream>>>(histd, hists, blkrel_d, blkrel_s, bbase_d, bbase_s);
    partition_kernel<<<NBP, B, 0, stream>>>(src, dst, blkrel_d, blkrel_s, bbase_d, bbase_s,
                                            dstp, srcp);
    fine_hist_kernel<<<2 * NBUCK, B, 0, stream>>>(dstp, srcp, bbase_d, bbase_s, dep_labels,
                                                  deg_in, deg_out_a, out_norm, node_info, bsum);
    scan_scatter_kernel<<<NBUCK, B, 0, stream>>>(deg_in, bsum, dstp, bbase_d, node_info,
                                                 row_off, in_norm, edge_rec);

    // Layer 1 fused: linear edge_rec stream, T1 L1-resident -> h1s (fp16)
    gather1t_kernel<<<cdiv((long)N_NODES * (HID / 8), B), B, 0, stream>>>(
        edge_rec, T1, row_off, deg_in, in_norm, out_norm, b1, bufH);

    // Layer 2 aggregate + layers 2+3 MFMA transform, fused: h1s -> t (in bufA)
    // [dstp/srcp CSR temps are dead; tbuf region disjoint from live h1s]
    agg_linear23_kernel<<<NMFMA, 512, 0, stream>>>(
        bufH, row_off, deg_in, edge_rec, in_norm, wprep, b2, out_norm, tbuf);

    // Final gather + bias (fp16 t -> fp32 out)
    gather_out_kernel<<<cdiv((long)N_NODES * TC, B), B, 0, stream>>>(
        tbuf, row_off, deg_in, edge_rec, in_norm, b3, out);
}

// Round 9
// 198.102 us; speedup vs baseline: 1.4684x; 1.0128x over previous
//
#include <hip/hip_runtime.h>
#include <hip/hip_fp16.h>

// GCN 3-layer, CSR-gather, low-rank L1 + fused L2/L3 transform.
//   CSR build GLOBAL-ATOMIC-FREE (two-level counting sort, LDS atomics only).
//   R8: LAYER-1 IS LOW-RANK OVER LABELS — gather1t eliminated.
//     agg1[n] = sum_l S[n][l]*T1[l], S[n][l] = sum out_norm[src] over in-edges
//     with label l. S built in LDS during scan_scatter (Sl[256][50], 51KB);
//     h1s = relu(in_norm*(S@T1t)+b1)*out_norm via MFMA (no LDS, T1t L1-hot).
//     edge_rec (int2) shrunk to esrc (ushort) for agg/gather_out.
//   L2+L3 fused: agg -> LDS fp16 A, MFMA 16x16x32_f16 (fp32 acc),
//     W2t/W3t fp16 LDS stride 104, h2 in-place per-wave, t fp16 stride 64
//     in bufA (disjoint from h1s — R6 race fix).
//   out = in_norm*gather(t fp16) + b3
#define N_NODES 50000
#define N_EDGES 800000
#define EMB     64
#define HID     96
#define NLAB    50
#define TSTRIDE 64                         // t row stride (halfs): 128B line-aligned
#define TC      13                         // gather chunks over t (cols 0..51)
#define NBP     256                        // partition blocks
#define EPB     ((N_EDGES + NBP - 1) / NBP)  // 3125 edges per block
#define NBUCK   196                        // node buckets of 256 (covers 50176)
#define WSTRIDE 104                        // W2t/W3t/A LDS row stride (halfs)
#define WPREP_N (160 * WSTRIDE)            // 96 W2t rows + 64 W3t rows
#define WPREPB  ((WPREP_N + 255) / 256)    // 65
#define T1TSTR  72                         // T1t row stride (halfs)
#define T1T_N   (HID * T1TSTR)             // 96 rows x 72
#define T1TB    ((T1T_N + 255) / 256)      // 27
#define SSTR    64                         // S row stride (floats), cols 50..63 zero
#define NMFMA   ((N_NODES + 127) / 128)    // 392 blocks of 128 nodes

typedef _Float16 f16x8 __attribute__((ext_vector_type(8)));
typedef float f32x4 __attribute__((ext_vector_type(4)));

__device__ __forceinline__ float2 h2f(unsigned u) {
    __half2 h = *reinterpret_cast<__half2*>(&u);
    return __half22float2(h);
}
__device__ __forceinline__ unsigned f2h(float a, float b) {
    __half2 h = __floats2half2_rn(a, b);
    return *reinterpret_cast<unsigned*>(&h);
}

// Per-block coarse histograms (dst>>8, src>>8) via LDS atomics. Tail blocks:
// T1t[j][l] = (emb@W1)^T fp16 (stride 72, l>=50 zero), then W2t/W3t prep.
__global__ void coarse_hist_kernel(const int* __restrict__ src, const int* __restrict__ dst,
                                   int* __restrict__ histd, int* __restrict__ hists,
                                   const float* __restrict__ emb, const float* __restrict__ W1,
                                   __half* __restrict__ T1t,
                                   const float* __restrict__ W2, const float* __restrict__ W3,
                                   __half* __restrict__ wprep) {
    int b = blockIdx.x, t = threadIdx.x;
    if (b < NBP) {
        __shared__ int hd[256], hs[256];
        hd[t] = 0; hs[t] = 0;
        __syncthreads();
        int hi = min(b * EPB + EPB, N_EDGES);
        for (int i = b * EPB + t; i < hi; i += 256) {
            atomicAdd(&hd[((unsigned)dst[i]) >> 8], 1);
            atomicAdd(&hs[((unsigned)src[i]) >> 8], 1);
        }
        __syncthreads();
        histd[b * 256 + t] = hd[t];
        hists[b * 256 + t] = hs[t];
    } else if (b < NBP + T1TB) {
        int i = (b - NBP) * 256 + t;
        if (i < T1T_N) {
            int j = i / T1TSTR, l = i - j * T1TSTR;
            float sum = 0.0f;
            if (l < NLAB) {
#pragma unroll
                for (int m = 0; m < EMB; ++m) sum += emb[l * EMB + m] * W1[m * HID + j];
            }
            T1t[i] = __float2half(sum);
        }
    } else {
        // wprep rows 0..95: W2t (j over HID); rows 96..159: W3t (j over 64)
        int i = (b - NBP - T1TB) * 256 + t;
        if (i < WPREP_N) {
            int j = i / WSTRIDE, kk = i - j * WSTRIDE;
            float v = 0.0f;
            if (kk < HID) {
                if (j < HID) v = W2[kk * HID + j];
                else { int jj = j - HID; if (jj < NLAB) v = W3[kk * NLAB + jj]; }
            }
            wprep[i] = __float2half(v);
        }
    }
}

// Block 0: dst side; block 1: src side. Thread t owns bucket t.
__global__ void coarse_scan_kernel(const int* __restrict__ histd, const int* __restrict__ hists,
                                   int* __restrict__ blkrel_d, int* __restrict__ blkrel_s,
                                   int* __restrict__ bbase_d, int* __restrict__ bbase_s) {
    __shared__ int sh[256];
    int t = threadIdx.x;
    const int* hist = blockIdx.x ? hists : histd;
    int* blkrel     = blockIdx.x ? blkrel_s : blkrel_d;
    int* bbase      = blockIdx.x ? bbase_s : bbase_d;
    int run = 0;
#pragma unroll 16
    for (int b = 0; b < NBP; ++b) {
        blkrel[b * 256 + t] = run;
        run += hist[b * 256 + t];
    }
    sh[t] = run;
    __syncthreads();
    for (int off = 1; off < 256; off <<= 1) {
        int v = sh[t];
        if (t >= off) v += sh[t - off];
        __syncthreads();
        sh[t] = v;
        __syncthreads();
    }
    bbase[t] = sh[t] - run;   // exclusive bucket base
}

// Scatter edges into bucket-partitioned arrays via LDS cursors (no global RMW).
// dstp rec = src | (dst&255)<<16 ; srcp rec = (byte) src&255.
__global__ void partition_kernel(const int* __restrict__ src, const int* __restrict__ dst,
                                 const int* __restrict__ blkrel_d, const int* __restrict__ blkrel_s,
                                 const int* __restrict__ bbase_d, const int* __restrict__ bbase_s,
                                 int* __restrict__ dstp, unsigned char* __restrict__ srcp) {
    __shared__ int curd[256], curs[256];
    int b = blockIdx.x, t = threadIdx.x;
    curd[t] = bbase_d[t] + blkrel_d[b * 256 + t];
    curs[t] = bbase_s[t] + blkrel_s[b * 256 + t];
    __syncthreads();
    int hi = min(b * EPB + EPB, N_EDGES);
    for (int i = b * EPB + t; i < hi; i += 256) {
        int d = dst[i], s = src[i];
        int pd = atomicAdd(&curd[((unsigned)d) >> 8], 1);
        dstp[pd] = s | ((d & 0xFF) << 16);
        int ps = atomicAdd(&curs[((unsigned)s) >> 8], 1);
        srcp[ps] = (unsigned char)(s & 0xFF);
    }
}

// Per-bucket fine histogram -> degree arrays (plain stores, no atomics).
// Dst-buckets tree-reduce counts -> bsum. Src-buckets emit out_norm and
// node_info (label<<16, out_norm bits).
__global__ void fine_hist_kernel(const int* __restrict__ dstp, const unsigned char* __restrict__ srcp,
                                 const int* __restrict__ bbase_d, const int* __restrict__ bbase_s,
                                 const int* __restrict__ labels,
                                 int* __restrict__ deg_in, int* __restrict__ deg_out,
                                 float* __restrict__ out_norm, int2* __restrict__ node_info,
                                 int* __restrict__ bsum) {
    __shared__ int cnt[256];
    int b = blockIdx.x, t = threadIdx.x;
    cnt[t] = 0;
    __syncthreads();
    if (b < NBUCK) {
        int lo = bbase_d[b], hi = bbase_d[b + 1];
        for (int i = lo + t; i < hi; i += 256)
            atomicAdd(&cnt[(dstp[i] >> 16) & 0xFF], 1);
        __syncthreads();
        int node = b * 256 + t;
        if (node < N_NODES) deg_in[node] = cnt[t];
        for (int off = 128; off > 0; off >>= 1) {
            __syncthreads();
            if (t < off) cnt[t] += cnt[t + off];
        }
        if (t == 0) bsum[b] = cnt[0];
    } else {
        int bb = b - NBUCK;
        int lo = bbase_s[bb], hi = bbase_s[bb + 1];
        for (int i = lo + t; i < hi; i += 256)
            atomicAdd(&cnt[srcp[i]], 1);
        __syncthreads();
        int node = bb * 256 + t;
        if (node < N_NODES) {
            int d = cnt[t];
            deg_out[node] = d;
            float on = rsqrtf(fmaxf((float)d, 1.0f));
            out_norm[node] = on;
            node_info[node] = make_int2(labels[node] << 16, __float_as_int(on));
        }
    }
}

// Merged scan + scatter + S-build: block b scans chunk b (== bucket b) ->
// row_off, in_norm; scatters bucket b's edges into esrc (ushort); and
// accumulates S[n][label] += out_norm[src] in LDS (layer-1 low-rank stats).
__global__ void scan_scatter_kernel(const int* __restrict__ deg_in, const int* __restrict__ bsum,
                                    const int* __restrict__ dstp, const int* __restrict__ bbase_d,
                                    const int2* __restrict__ node_info,
                                    int* __restrict__ row_off, float* __restrict__ in_norm,
                                    unsigned short* __restrict__ esrc, float* __restrict__ S) {
    __shared__ int pb[256];
    __shared__ int s[256];
    __shared__ int ro[256];
    __shared__ int cur[256];
    __shared__ float Sl[256][NLAB];          // 51.2 KB
    int t = threadIdx.x, b = blockIdx.x, i = b * 256 + t;
    for (int idx = t; idx < 256 * NLAB; idx += 256) ((float*)Sl)[idx] = 0.0f;
    pb[t] = (t < b) ? bsum[t] : 0;
    int own = (i < N_NODES) ? deg_in[i] : 0;
    s[t] = own;
    cur[t] = 0;
    __syncthreads();
    for (int off = 128; off > 0; off >>= 1) {
        if (t < off) pb[t] += pb[t + off];
        __syncthreads();
    }
    int base = pb[0];
    for (int off = 1; off < 256; off <<= 1) {
        int v = s[t];
        if (t >= off) v += s[t - off];
        __syncthreads();
        s[t] = v;
        __syncthreads();
    }
    int r0 = base + s[t] - own;
    ro[t] = r0;
    if (i < N_NODES) {
        row_off[i] = r0;
        in_norm[i] = rsqrtf(fmaxf((float)own, 1.0f));
    }
    __syncthreads();
    int lo = bbase_d[b], hi = bbase_d[b + 1];
    for (int k = lo + t; k < hi; k += 256) {
        int rec = dstp[k];
        int sn = rec & 0xFFFF;
        int nl = (rec >> 16) & 0xFF;
        int r = atomicAdd(&cur[nl], 1);
        esrc[ro[nl] + r] = (unsigned short)sn;
        int2 ni = node_info[sn];
        atomicAdd(&Sl[nl][((unsigned)ni.x) >> 16], __int_as_float(ni.y));
    }
    __syncthreads();
    // writeback S rows (stride 64, cols 50..63 zero)
    for (int idx = t; idx < 256 * SSTR; idx += 256) {
        int n = idx >> 6, c = idx & 63;
        int node = b * 256 + n;
        if (node < N_NODES)
            S[(size_t)node * SSTR + c] = (c < NLAB) ? Sl[n][c] : 0.0f;
    }
}

// Layer-1 via MFMA: h1s = relu(in_norm*(S@T1t) + b1)*out_norm. No LDS;
// T1t (13.8KB) is L1-resident. A-frag: row=lane&15, k=(lane>>4)*8+i;
// D: col=lane&15, row=(lane>>4)*4+reg (m89/m91-verified).
__global__ __launch_bounds__(512) void h1_mfma_kernel(
        const float* __restrict__ S, const __half* __restrict__ T1t,
        const float* __restrict__ b1, const float* __restrict__ in_norm,
        const float* __restrict__ out_norm, __half* __restrict__ h1s) {
    const int tid = threadIdx.x;
    const int w = tid >> 6, l = tid & 63;
    const int lr = l & 15, lg = l >> 4;
    const int n0 = blockIdx.x * 128 + w * 16;

    f16x8 a[2];
    {
        int n = n0 + lr; if (n > N_NODES - 1) n = N_NODES - 1;
        const float* sp = S + (size_t)n * SSTR + lg * 8;
#pragma unroll
        for (int kb = 0; kb < 2; ++kb) {
            float4 v0 = *(const float4*)(sp + kb * 32);
            float4 v1 = *(const float4*)(sp + kb * 32 + 4);
            a[kb] = (f16x8){(_Float16)v0.x, (_Float16)v0.y, (_Float16)v0.z, (_Float16)v0.w,
                            (_Float16)v1.x, (_Float16)v1.y, (_Float16)v1.z, (_Float16)v1.w};
        }
    }
    f32x4 acc[6];
#pragma unroll
    for (int nt = 0; nt < 6; ++nt) {
        acc[nt] = (f32x4){0.f, 0.f, 0.f, 0.f};
#pragma unroll
        for (int kb = 0; kb < 2; ++kb) {
            f16x8 bfr = *(const f16x8*)(T1t + (nt * 16 + lr) * T1TSTR + kb * 32 + lg * 8);
            acc[nt] = __builtin_amdgcn_mfma_f32_16x16x32_f16(a[kb], bfr, acc[nt], 0, 0, 0);
        }
    }
    float on4[4], in4[4];
#pragma unroll
    for (int r = 0; r < 4; ++r) {
        int n = n0 + lg * 4 + r; if (n > N_NODES - 1) n = N_NODES - 1;
        on4[r] = out_norm[n];
        in4[r] = in_norm[n];
    }
#pragma unroll
    for (int nt = 0; nt < 6; ++nt) {
        int col = nt * 16 + lr;
        float bb = b1[col];
#pragma unroll
        for (int r = 0; r < 4; ++r) {
            int n = n0 + lg * 4 + r;
            if (n < N_NODES) {
                float v = fmaxf(in4[r] * acc[nt][r] + bb, 0.f) * on4[r];
                h1s[(size_t)n * HID + col] = __float2half(v);
            }
        }
    }
}

// Fused: layer-2 aggregation (gather h1s fp16 rows -> LDS fp16 A) + MFMA
// layers 2+3. 128 nodes/block, 512 threads. h2 overwrites A in-place (each
// wave owns its 16 rows exclusively). t must be DISJOINT from hs (race fix).
__global__ __launch_bounds__(512) void agg_linear23_kernel(
        const __half* __restrict__ hs, const int* __restrict__ row_off,
        const int* __restrict__ deg, const unsigned short* __restrict__ esrc,
        const float* __restrict__ in_norm, const __half* __restrict__ wprep,
        const float* __restrict__ b2, const float* __restrict__ out_norm,
        __half* __restrict__ t) {
    __shared__ _Float16 Wl[WPREP_N];          // 33.3 KB: W2t [96][104] + W3t [64][104]
    __shared__ _Float16 A[128][WSTRIDE];      // 26.6 KB: agg fp16, then h2 in-place
    const int tid = threadIdx.x;
    {   // stage W2t+W3t (linear uint4 copy)
        const uint4* sp = (const uint4*)wprep;
        uint4* dp = (uint4*)Wl;
        for (int i = tid; i < WPREP_N / 8; i += 512) dp[i] = sp[i];
    }
    const int n0b = blockIdx.x * 128;

    // ---- phase 1: aggregate 128 nodes x 12 chunk-pairs into A ----
    for (int task = tid; task < 128 * 12; task += 512) {
        int m = task / 12;
        int c = task - m * 12;
        int n = n0b + m;
        uint2 rA = make_uint2(0u, 0u), rB = make_uint2(0u, 0u);
        if (n < N_NODES) {
            const __half* p0 = hs + c * 4;
            const __half* p1 = hs + (c + 12) * 4;
            int k = row_off[n];
            int e = k + deg[n];
            float ax = 0.f, ay = 0.f, az = 0.f, aw = 0.f;
            float bx = 0.f, by = 0.f, bz = 0.f, bw = 0.f;
            for (; k + 3 < e; k += 4) {
                size_t r0 = (size_t)esrc[k] * HID;
                size_t r1 = (size_t)esrc[k + 1] * HID;
                size_t r2 = (size_t)esrc[k + 2] * HID;
                size_t r3 = (size_t)esrc[k + 3] * HID;
                uint2 aA = *(const uint2*)(p0 + r0); uint2 bA = *(const uint2*)(p1 + r0);
                uint2 aB = *(const uint2*)(p0 + r1); uint2 bB = *(const uint2*)(p1 + r1);
                uint2 aC = *(const uint2*)(p0 + r2); uint2 bC = *(const uint2*)(p1 + r2);
                uint2 aD = *(const uint2*)(p0 + r3); uint2 bD = *(const uint2*)(p1 + r3);
                float2 f;
                f = h2f(aA.x); ax += f.x; ay += f.y;  f = h2f(aA.y); az += f.x; aw += f.y;
                f = h2f(aB.x); ax += f.x; ay += f.y;  f = h2f(aB.y); az += f.x; aw += f.y;
                f = h2f(aC.x); ax += f.x; ay += f.y;  f = h2f(aC.y); az += f.x; aw += f.y;
                f = h2f(aD.x); ax += f.x; ay += f.y;  f = h2f(aD.y); az += f.x; aw += f.y;
                f = h2f(bA.x); bx += f.x; by += f.y;  f = h2f(bA.y); bz += f.x; bw += f.y;
                f = h2f(bB.x); bx += f.x; by += f.y;  f = h2f(bB.y); bz += f.x; bw += f.y;
                f = h2f(bC.x); bx += f.x; by += f.y;  f = h2f(bC.y); bz += f.x; bw += f.y;
                f = h2f(bD.x); bx += f.x; by += f.y;  f = h2f(bD.y); bz += f.x; bw += f.y;
            }
            for (; k < e; ++k) {
                size_t r0 = (size_t)esrc[k] * HID;
                uint2 aA = *(const uint2*)(p0 + r0); uint2 bA = *(const uint2*)(p1 + r0);
                float2 f;
                f = h2f(aA.x); ax += f.x; ay += f.y;  f = h2f(aA.y); az += f.x; aw += f.y;
                f = h2f(bA.x); bx += f.x; by += f.y;  f = h2f(bA.y); bz += f.x; bw += f.y;
            }
            float nn = in_norm[n];
            rA.x = f2h(ax * nn, ay * nn); rA.y = f2h(az * nn, aw * nn);
            rB.x = f2h(bx * nn, by * nn); rB.y = f2h(bz * nn, bw * nn);
        }
        *(uint2*)(&A[m][c * 4]) = rA;
        *(uint2*)(&A[m][(c + 12) * 4]) = rB;
    }
    __syncthreads();

    // ---- phase 2: MFMA GEMM1 + GEMM2 ----
    const int w = tid >> 6, l = tid & 63;
    const int lr = l & 15, lg = l >> 4;
    const int m0 = w * 16;
    const int n0 = n0b + m0;

    f16x8 a[3];
#pragma unroll
    for (int kb = 0; kb < 3; ++kb)
        a[kb] = *(const f16x8*)(&A[m0 + lr][kb * 32 + lg * 8]);
    f32x4 acc[6];
#pragma unroll
    for (int nt = 0; nt < 6; ++nt) {
        acc[nt] = (f32x4){0.f, 0.f, 0.f, 0.f};
#pragma unroll
        for (int kb = 0; kb < 3; ++kb) {
            f16x8 bfr = *(const f16x8*)(&Wl[(nt * 16 + lr) * WSTRIDE + kb * 32 + lg * 8]);
            acc[nt] = __builtin_amdgcn_mfma_f32_16x16x32_f16(a[kb], bfr, acc[nt], 0, 0, 0);
        }
    }
    float on4[4];
#pragma unroll
    for (int r = 0; r < 4; ++r) {
        int n = n0 + lg * 4 + r; if (n > N_NODES - 1) n = N_NODES - 1;
        on4[r] = out_norm[n];
    }
    asm volatile("s_waitcnt lgkmcnt(0)" ::: "memory");
#pragma unroll
    for (int nt = 0; nt < 6; ++nt) {
        int col = nt * 16 + lr;
        float bb = b2[col];
#pragma unroll
        for (int r = 0; r < 4; ++r) {
            float v = fmaxf(acc[nt][r] + bb, 0.f) * on4[r];
            A[m0 + lg * 4 + r][col] = (_Float16)v;
        }
    }
    asm volatile("s_waitcnt lgkmcnt(0)" ::: "memory");

    f16x8 a2[3];
#pragma unroll
    for (int kb = 0; kb < 3; ++kb)
        a2[kb] = *(const f16x8*)(&A[m0 + lr][kb * 32 + lg * 8]);
#pragma unroll
    for (int nt = 0; nt < 4; ++nt) {
        f32x4 acc2 = (f32x4){0.f, 0.f, 0.f, 0.f};
#pragma unroll
        for (int kb = 0; kb < 3; ++kb) {
            f16x8 bfr = *(const f16x8*)(&Wl[(HID + nt * 16 + lr) * WSTRIDE + kb * 32 + lg * 8]);
            acc2 = __builtin_amdgcn_mfma_f32_16x16x32_f16(a2[kb], bfr, acc2, 0, 0, 0);
        }
        int col = nt * 16 + lr;
        if (col < 4 * TC) {
#pragma unroll
            for (int r = 0; r < 4; ++r) {
                int n = n0 + lg * 4 + r;
                if (n < N_NODES) t[(size_t)n * TSTRIDE + col] = __float2half(acc2[r]);
            }
        }
    }
}

// Final gather over FP16 t (128B-aligned rows, 1 line each).
__global__ void gather_out_kernel(const __half* __restrict__ t, const int* __restrict__ row_off,
                                  const int* __restrict__ deg, const unsigned short* __restrict__ esrc,
                                  const float* __restrict__ in_norm, const float* __restrict__ bias,
                                  float* __restrict__ out) {
    int i = blockIdx.x * blockDim.x + threadIdx.x;
    if (i >= N_NODES * TC) return;
    int n = i / TC;
    int c = i - n * TC;
    const __half* p0 = t + c * 4;
    int k = row_off[n];
    int e = k + deg[n];
    float ax = 0.f, ay = 0.f, az = 0.f, aw = 0.f;
    for (; k + 3 < e; k += 4) {
        size_t r0 = (size_t)esrc[k] * TSTRIDE;
        size_t r1 = (size_t)esrc[k + 1] * TSTRIDE;
        size_t r2 = (size_t)esrc[k + 2] * TSTRIDE;
        size_t r3 = (size_t)esrc[k + 3] * TSTRIDE;
        uint2 v0 = *(const uint2*)(p0 + r0);
        uint2 v1 = *(const uint2*)(p0 + r1);
        uint2 v2 = *(const uint2*)(p0 + r2);
        uint2 v3 = *(const uint2*)(p0 + r3);
        float2 f;
        f = h2f(v0.x); ax += f.x; ay += f.y;  f = h2f(v0.y); az += f.x; aw += f.y;
        f = h2f(v1.x); ax += f.x; ay += f.y;  f = h2f(v1.y); az += f.x; aw += f.y;
        f = h2f(v2.x); ax += f.x; ay += f.y;  f = h2f(v2.y); az += f.x; aw += f.y;
        f = h2f(v3.x); ax += f.x; ay += f.y;  f = h2f(v3.y); az += f.x; aw += f.y;
    }
    for (; k < e; ++k) {
        size_t r0 = (size_t)esrc[k] * TSTRIDE;
        uint2 v0 = *(const uint2*)(p0 + r0);
        float2 f;
        f = h2f(v0.x); ax += f.x; ay += f.y;  f = h2f(v0.y); az += f.x; aw += f.y;
    }
    float nn = in_norm[n];
    int j = c * 4;
    float* op = out + (size_t)n * NLAB + j;   // rows 8B-aligned only -> float2 stores
    float2 lo; lo.x = ax * nn + bias[j];     lo.y = ay * nn + bias[j + 1];
    *(float2*)op = lo;
    if (j + 2 < NLAB) {
        float2 hi; hi.x = az * nn + bias[j + 2]; hi.y = aw * nn + bias[j + 3];
        *(float2*)(op + 2) = hi;
    }
}

static inline int cdiv(long a, int b) { return (int)((a + b - 1) / b); }

extern "C" void kernel_launch(void* const* d_in, const int* in_sizes, int n_in,
                              void* d_out, int out_size, void* d_ws, size_t ws_size,
                              hipStream_t stream) {
    const int*   dep_labels = (const int*)d_in[0];
    const int*   src        = (const int*)d_in[1];
    const int*   dst        = (const int*)d_in[2];
    const float* emb        = (const float*)d_in[3];
    const float* W1 = (const float*)d_in[4]; const float* b1 = (const float*)d_in[5];
    const float* W2 = (const float*)d_in[6]; const float* b2 = (const float*)d_in[7];
    const float* W3 = (const float*)d_in[8]; const float* b3 = (const float*)d_in[9];
    float* out = (float*)d_out;

    // ---- workspace layout (regions 16B aligned) ----
    int* wsp           = (int*)d_ws;
    int* row_off       = wsp;                 wsp += N_NODES;
    int* deg_in        = wsp;                 wsp += N_NODES;
    int* deg_out_a     = wsp;                 wsp += N_NODES;
    int* bsum          = wsp;                 wsp += 256;
    float* out_norm    = (float*)wsp;         wsp += N_NODES;
    float* in_norm     = (float*)wsp;         wsp += N_NODES;
    int2* node_info    = (int2*)wsp;          wsp += 2 * N_NODES;
    __half* T1t        = (__half*)wsp;        wsp += T1T_N / 2 + 8;
    __half* wprep      = (__half*)wsp;        wsp += WPREP_N / 2;
    unsigned short* esrc = (unsigned short*)wsp; wsp += N_EDGES / 2;  // 1.6 MB
    int* bufA          = wsp;                 wsp += (size_t)N_NODES * HID;   // 19.2 MB
    __half* bufH       = (__half*)wsp;        // h1s (fp16) only
    // Inside bufA:
    //   tbuf: [0 .. 1.6M ints)  — t (fp16 stride 64), written k7, read k8.
    //   Sbuf: [1.6M .. 4.8M)    — S (fp32 stride 64), written k5, read k6.
    //   CSR temps overlap tbuf region only (all < 1.26M ints, dead after k5).
    __half* tbuf  = (__half*)bufA;
    float*  Sbuf  = (float*)(bufA + 1600000);
    int* histd    = bufA;                     // [NBP][256]
    int* hists    = histd + NBP * 256;
    int* blkrel_d = hists + NBP * 256;
    int* blkrel_s = blkrel_d + NBP * 256;
    int* bbase_d  = blkrel_s + NBP * 256;     // [256]
    int* bbase_s  = bbase_d + 256;            // [256]
    int* dstp     = bbase_s + 256;            // [N_EDGES] -> ends ~1.056M
    unsigned char* srcp = (unsigned char*)(dstp + N_EDGES);  // [N_EDGES] bytes -> ends ~1.256M

    const int B = 256;

    // ---- CSR build: no global atomics anywhere ----
    coarse_hist_kernel<<<NBP + T1TB + WPREPB, B, 0, stream>>>(src, dst, histd, hists,
                                                              emb, W1, T1t, W2, W3, wprep);
    coarse_scan_kernel<<<2, B, 0, stream>>>(histd, hists, blkrel_d, blkrel_s, bbase_d, bbase_s);
    partition_kernel<<<NBP, B, 0, stream>>>(src, dst, blkrel_d, blkrel_s, bbase_d, bbase_s,
                                            dstp, srcp);
    fine_hist_kernel<<<2 * NBUCK, B, 0, stream>>>(dstp, srcp, bbase_d, bbase_s, dep_labels,
                                                  deg_in, deg_out_a, out_norm, node_info, bsum);
    scan_scatter_kernel<<<NBUCK, B, 0, stream>>>(deg_in, bsum, dstp, bbase_d, node_info,
                                                 row_off, in_norm, esrc, Sbuf);

    // Layer 1 via MFMA: S @ T1t -> h1s (fp16)
    h1_mfma_kernel<<<NMFMA, 512, 0, stream>>>(Sbuf, T1t, b1, in_norm, out_norm, bufH);

    // Layer 2 aggregate + layers 2+3 MFMA transform, fused: h1s -> t (in bufA)
    agg_linear23_kernel<<<NMFMA, 512, 0, stream>>>(
        bufH, row_off, deg_in, esrc, in_norm, wprep, b2, out_norm, tbuf);

    // Final gather + bias (fp16 t -> fp32 out)
    gather_out_kernel<<<cdiv((long)N_NODES * TC, B), B, 0, stream>>>(
        tbuf, row_off, deg_in, esrc, in_norm, b3, out);
}